// Round 13
// baseline (69.521 us; speedup 1.0000x reference)
//
#include <hip/hip_runtime.h>
#include <cstdint>

#define BB 4
#define CDIM 128
#define HH 64
#define WW 64
#define RR 3
#define DD 7
#define DSQ 49

typedef __attribute__((ext_vector_type(8))) short short8v;   // 8 bf16 = 4 VGPR
typedef __attribute__((ext_vector_type(4))) float float4v;

__device__ __forceinline__ int reflect64(int p) {
    p = (p < 0) ? -p : p;
    return (p > 63) ? (126 - p) : p;
}
__device__ __forceinline__ float sigm(float x) { return 1.0f / (1.0f + __expf(-x)); }
__device__ __forceinline__ short f2bf(float f) {     // f32 -> bf16 RNE
    uint32_t u = __float_as_uint(f);
    u += 0x7FFF + ((u >> 16) & 1);
    return (short)(u >> 16);
}

// ---- range_proj: conv1x1 -> LN -> SiLU -> conv1x1 via bf16 MFMA.
// Output: bf16 TRANSPOSED [b][h][p][c].
template<bool SILU>
__global__ __launch_bounds__(1024) void proj_kernel(
    const float* __restrict__ x, const float* __restrict__ w1,
    const float* __restrict__ b1, const float* __restrict__ lnw,
    const float* __restrict__ lnb, const float* __restrict__ w2,
    const float* __restrict__ b2, short* __restrict__ outT)
{
    __shared__ short sW1[CDIM * CDIM];
    __shared__ short sW2[CDIM * CDIM];
    __shared__ short sXT[WW * CDIM];
    __shared__ short sXT2[WW * CDIM];
    __shared__ float sT[CDIM][65];
    __shared__ float red1[16][WW];
    __shared__ float red2[16][WW];

    const int tid = threadIdx.x;
    const int l = tid & 63;
    const int q = tid >> 6;
    const int qu = __builtin_amdgcn_readfirstlane(q);
    const int b = blockIdx.x >> 6;
    const int h = blockIdx.x & 63;

    {
        const int o = tid >> 3;
        const int i0 = (tid & 7) * 16;
        const int sw = (o & 7) << 3;
        const float* wsrc[2] = {w1, w2};
        short* wdst[2] = {sW1, sW2};
        #pragma unroll
        for (int m = 0; m < 2; ++m) {
            const float* src = wsrc[m] + o * CDIM + i0;
            short8v pk0, pk1;
            #pragma unroll
            for (int j = 0; j < 8; ++j) pk0[j] = f2bf(src[j]);
            #pragma unroll
            for (int j = 0; j < 8; ++j) pk1[j] = f2bf(src[8 + j]);
            *reinterpret_cast<short8v*>(&wdst[m][o * 128 + (i0 ^ sw)]) = pk0;
            *reinterpret_cast<short8v*>(&wdst[m][o * 128 + ((i0 + 8) ^ sw)]) = pk1;
        }
    }
    {
        const int pos = tid & 15;
        const int c0 = tid >> 4;
        const float* xrow = x + (b * CDIM * HH + h) * WW;
        #pragma unroll
        for (int rr = 0; rr < 2; ++rr) {
            const int c = c0 + rr * 64;
            const float4 v = *reinterpret_cast<const float4*>(&xrow[c * HH * WW + pos * 4]);
            #pragma unroll
            for (int m = 0; m < 4; ++m) {
                const int p = pos * 4 + m;
                sXT[p * 128 + (c ^ ((p & 7) << 3))] = f2bf(((const float*)&v)[m]);
            }
        }
    }
    __syncthreads();

    const int lm = l & 15, g = l >> 4;
    const int tm = q >> 1;
    const int tn0 = (q & 1) * 2;
    const int oa = tm * 16 + lm;
    const int arow = oa * 128, asw = (oa & 7) << 3;
    const int p0 = tn0 * 16 + lm, p1 = (tn0 + 1) * 16 + lm;
    const int bsw0 = (p0 & 7) << 3, bsw1 = (p1 & 7) << 3;

    float4v acc0 = {0.f, 0.f, 0.f, 0.f}, acc1 = {0.f, 0.f, 0.f, 0.f};
    #pragma unroll
    for (int kk = 0; kk < 4; ++kk) {
        const int ki = kk * 32 + g * 8;
        const short8v af = *reinterpret_cast<const short8v*>(&sW1[arow + (ki ^ asw)]);
        const short8v bf0 = *reinterpret_cast<const short8v*>(&sXT[p0 * 128 + (ki ^ bsw0)]);
        const short8v bf1 = *reinterpret_cast<const short8v*>(&sXT[p1 * 128 + (ki ^ bsw1)]);
        acc0 = __builtin_amdgcn_mfma_f32_16x16x32_bf16(af, bf0, acc0, 0, 0, 0);
        acc1 = __builtin_amdgcn_mfma_f32_16x16x32_bf16(af, bf1, acc1, 0, 0, 0);
    }
    #pragma unroll
    for (int r = 0; r < 4; ++r) sT[tm * 16 + g * 4 + r][p0] = acc0[r];
    #pragma unroll
    for (int r = 0; r < 4; ++r) sT[tm * 16 + g * 4 + r][p1] = acc1[r];
    __syncthreads();

    {
        const int p = l;
        float vals[8];
        float s1 = 0.f, s2 = 0.f;
        #pragma unroll
        for (int j = 0; j < 8; ++j) {
            const float v = sT[qu * 8 + j][p] + b1[qu * 8 + j];
            vals[j] = v; s1 += v; s2 += v * v;
        }
        red1[q][p] = s1; red2[q][p] = s2;
        __syncthreads();
        float t1 = 0.f, t2 = 0.f;
        #pragma unroll
        for (int j = 0; j < 16; ++j) { t1 += red1[j][p]; t2 += red2[j][p]; }
        const float mean = t1 * (1.0f / 128.0f);
        const float var  = t2 * (1.0f / 128.0f) - mean * mean;
        const float rstd = rsqrtf(var + 1e-6f);
        short8v pk;
        #pragma unroll
        for (int j = 0; j < 8; ++j) {
            float v = (vals[j] - mean) * rstd * lnw[qu * 8 + j] + lnb[qu * 8 + j];
            if (SILU) v = v * sigm(v);
            pk[j] = f2bf(v);
        }
        *reinterpret_cast<short8v*>(&sXT2[p * 128 + ((qu * 8) ^ ((p & 7) << 3))]) = pk;
    }
    __syncthreads();

    {
        float4v a0 = {0.f, 0.f, 0.f, 0.f}, a1 = {0.f, 0.f, 0.f, 0.f};
        #pragma unroll
        for (int kk = 0; kk < 4; ++kk) {
            const int ki = kk * 32 + g * 8;
            const short8v af = *reinterpret_cast<const short8v*>(&sW2[arow + (ki ^ asw)]);
            const short8v bf0 = *reinterpret_cast<const short8v*>(&sXT2[p0 * 128 + (ki ^ bsw0)]);
            const short8v bf1 = *reinterpret_cast<const short8v*>(&sXT2[p1 * 128 + (ki ^ bsw1)]);
            a0 = __builtin_amdgcn_mfma_f32_16x16x32_bf16(af, bf0, a0, 0, 0, 0);
            a1 = __builtin_amdgcn_mfma_f32_16x16x32_bf16(af, bf1, a1, 0, 0, 0);
        }
        const float4 bv = *reinterpret_cast<const float4*>(&b2[tm * 16 + g * 4]);
        #pragma unroll
        for (int r = 0; r < 4; ++r) {
            const float bias = ((const float*)&bv)[r];
            sT[tm * 16 + g * 4 + r][p0] = a0[r] + bias;
            sT[tm * 16 + g * 4 + r][p1] = a1[r] + bias;
        }
    }
    __syncthreads();
    {
        const int p = tid >> 4;
        const int c0 = (tid & 15) * 8;
        short8v pk;
        #pragma unroll
        for (int j = 0; j < 8; ++j) pk[j] = f2bf(sT[c0 + j][p]);
        *reinterpret_cast<short8v*>(&outT[((b * HH + h) * WW + p) * CDIM + c0]) = pk;
    }
}

// ---- fused: Gram-MFMA sim (direct band scatter, no in-loop barriers)
//      -> softmax*spatial -> MFMA fixup -> wts
__global__ __launch_bounds__(1024) void simfix_kernel(
    const short* __restrict__ pxt, const float* __restrict__ sigma_p,
    const float* __restrict__ sem,
    const float* __restrict__ w1, const float* __restrict__ b1,
    const float* __restrict__ lnw, const float* __restrict__ lnb,
    const float* __restrict__ w2, const float* __restrict__ b2,
    float* __restrict__ wts)
{
    __shared__ alignas(16) char sBig[7 * WW * CDIM * 2];   // 114,688 B
    __shared__ alignas(16) char sAux[64 * 66 * 4];         //  16,896 B: {red1,red2}
    __shared__ alignas(16) float sSim[DSQ][64];            //  12,544 B
    __shared__ alignas(16) float sCmb[DSQ][66];            //  12,936 B

    short* rows = reinterpret_cast<short*>(sBig);          // Gram: 7 x [64][128] bf16 swz
    // fixup overlay of sBig (rows dead after Gram):
    short* B1   = reinterpret_cast<short*>(sBig);          // [64 px][192] bf16 swz
    short* A1   = reinterpret_cast<short*>(sBig + 24576);  // [64 o ][192] bf16 swz
    short* B2   = reinterpret_cast<short*>(sBig + 49152);  // [64 px][64]  bf16 swz
    short* A2   = reinterpret_cast<short*>(sBig + 57344);  // [64 o ][64]  bf16 swz
    float* fSem = reinterpret_cast<float*>(sBig + 65536);  // [128][64] f32
    float* prm  = reinterpret_cast<float*>(sBig + 98304);  // b1p|lnwp|lnbp|b2p x64

    float (*red1)[65] = reinterpret_cast<float(*)[65]>(sAux);
    float (*red2)[65] = reinterpret_cast<float(*)[65]>(sAux + 16 * 65 * 4);

    const int tid = threadIdx.x;
    const int l = tid & 63;
    const int q = tid >> 6;
    const int b = blockIdx.x >> 6;
    const int h = blockIdx.x & 63;

    // ---- stage 7 reflected rows, bf16 [row][p][c] swz ----
    for (int idx = tid; idx < 7 * WW * 16; idx += 1024) {
        const int cchunk = idx & 15;
        const int p = (idx >> 4) & 63;
        const int row = idx >> 10;
        const int hp = reflect64(h + row - RR);
        const short8v v = *reinterpret_cast<const short8v*>(
            &pxt[((b * HH + hp) * WW + p) * CDIM + cchunk * 8]);
        *reinterpret_cast<short8v*>(
            &rows[(row * WW + p) * CDIM + ((cchunk * 8) ^ ((p & 7) << 3))]) = v;
    }
    __syncthreads();

    // ---- Gram MFMA per ki, direct band scatter (no in-loop barriers) ----
    const int lm = l & 15, g = l >> 4;
    const int tm = q >> 2, tn = q & 3;
    const int pa = tm * 16 + lm;
    const int pxb = tn * 16 + lm;
    const int abase = (3 * WW + pa) * CDIM, as_ = (pa & 7) << 3;
    const int bs_ = (pxb & 7) << 3;

    short8v afr[4];
    #pragma unroll
    for (int kk = 0; kk < 4; ++kk)
        afr[kk] = *reinterpret_cast<const short8v*>(
            &rows[abase + ((kk * 32 + g * 8) ^ as_)]);

    const float rscale = 0.088388347648318447f;  // 1/sqrt(128)
    const int pbv = tn * 16 + lm;                // this lane's D column (pb)
    for (int ki = 0; ki < 7; ++ki) {
        float4v acc = {0.f, 0.f, 0.f, 0.f};
        const int bbase = (ki * WW + pxb) * CDIM;
        #pragma unroll
        for (int kk = 0; kk < 4; ++kk) {
            const short8v bf = *reinterpret_cast<const short8v*>(
                &rows[bbase + ((kk * 32 + g * 8) ^ bs_)]);
            acc = __builtin_amdgcn_mfma_f32_16x16x32_bf16(afr[kk], bf, acc, 0, 0, 0);
        }
        // lane holds D[pa_r][pbv], pa_r = tm*16 + g*4 + r. Scatter the 7-wide band.
        #pragma unroll
        for (int r = 0; r < 4; ++r) {
            const int pa_r = tm * 16 + g * 4 + r;
            #pragma unroll
            for (int kj = 0; kj < 7; ++kj) {
                if (reflect64(pa_r + kj - RR) == pbv)
                    sSim[ki * 7 + kj][pa_r] = acc[r] * rscale;
            }
        }
    }
    __syncthreads();     // sSim complete; rows dead -> stage fixup overlays

    // A1: w1 -> bf16 [64][192], layout [0:49]=cmb-cols, [49:64]=0, [64:192]=sem-cols
    for (int idx = tid; idx < 64 * 24; idx += 1024) {
        const int o = idx / 24;
        const int ch0 = (idx % 24) * 8;
        short8v pk;
        #pragma unroll
        for (int j = 0; j < 8; ++j) {
            const int c = ch0 + j;
            float v = 0.f;
            if (o < DSQ) {
                if (c < DSQ) v = w1[o * 177 + c];
                else if (c >= 64) v = w1[o * 177 + DSQ + (c - 64)];
            }
            pk[j] = f2bf(v);
        }
        *reinterpret_cast<short8v*>(&A1[o * 192 + (ch0 ^ ((o & 7) << 3))]) = pk;
    }
    // A2: w2 -> bf16 [64][64], zero-padded
    for (int idx = tid; idx < 64 * 8; idx += 1024) {
        const int o = idx >> 3;
        const int ch0 = (idx & 7) * 8;
        short8v pk;
        #pragma unroll
        for (int j = 0; j < 8; ++j) {
            const int c = ch0 + j;
            pk[j] = (o < DSQ && c < DSQ) ? f2bf(w2[o * DSQ + c]) : (short)0;
        }
        *reinterpret_cast<short8v*>(&A2[o * 64 + (ch0 ^ ((o & 7) << 3))]) = pk;
    }
    // B2 zero-fill
    {
        const short8v z = {0, 0, 0, 0, 0, 0, 0, 0};
        for (int idx = tid; idx < 64 * 8; idx += 1024)
            *reinterpret_cast<short8v*>(&B2[idx * 8]) = z;
    }
    // B1 pad cols [49..64) zero
    for (int idx = tid; idx < 64 * 15; idx += 1024) {
        const int p = idx / 15, c = DSQ + idx % 15;
        B1[p * 192 + (c ^ ((p & 7) << 3))] = 0;
    }
    // params
    for (int idx = tid; idx < 256; idx += 1024) {
        const int a = idx >> 6, i = idx & 63;
        float v = 0.f;
        if (i < DSQ) {
            if (a == 0) v = b1[i];
            else if (a == 1) v = lnw[i];
            else if (a == 2) v = lnb[i];
            else v = b2[i];
        }
        prm[a * 64 + i] = v;
    }
    // fSem f32 [c][p]
    {
        const float* srow = sem + (b * CDIM * HH + h) * WW;
        for (int idx = tid; idx < CDIM * 16; idx += 1024) {
            const int r = idx >> 4, pos = idx & 15;
            *reinterpret_cast<float4*>(&fSem[r * WW + pos * 4]) =
                *reinterpret_cast<const float4*>(&srow[r * HH * WW + pos * 4]);
        }
    }
    // softmax * spatial kernel -> sCmb f32 + B1 cmb-cols bf16
    {
        float rv[DSQ];
        #pragma unroll
        for (int n = 0; n < DSQ; ++n) rv[n] = sSim[n][l];
        float m = -1e30f;
        #pragma unroll
        for (int n = 0; n < DSQ; ++n) m = fmaxf(m, rv[n]);
        float ssum = 0.f;
        #pragma unroll
        for (int n = 0; n < DSQ; ++n) ssum += __expf(rv[n] - m);
        const float inv = 1.0f / ssum;
        const float sigma = sigma_p[0];
        const float inv2s2 = 1.0f / (2.0f * sigma * sigma);
        const int swl = (l & 7) << 3;
        #pragma unroll
        for (int k = 0; k < 4; ++k) {
            const int n = q + 16 * k;
            if (n < DSQ) {
                const int ki = n / 7, kj = n % 7;
                const float dx = (float)(ki - 3) * (1.0f / 3.0f);
                const float dy = (float)(kj - 3) * (1.0f / 3.0f);
                const float sk = __expf(-(dx * dx + dy * dy) * inv2s2);
                const float cv = __expf(rv[n] - m) * inv * sk;
                sCmb[n][l] = cv;
                B1[l * 192 + (n ^ swl)] = f2bf(cv);
            }
        }
    }
    __syncthreads();
    // B1 sem-cols: transpose-pack from fSem
    {
        const int c0 = q * 8;
        short8v pk;
        #pragma unroll
        for (int j = 0; j < 8; ++j) pk[j] = f2bf(fSem[(c0 + j) * WW + l]);
        *reinterpret_cast<short8v*>(&B1[l * 192 + ((64 + c0) ^ ((l & 7) << 3))]) = pk;
    }
    __syncthreads();

    // ---- fixup conv1 MFMA: [64 o x 192] x [192 x 64 px] ----
    const int oA = tm * 16 + lm;
    const int aswz = (oA & 7) << 3;
    const int p = tn * 16 + lm;
    const int bswz = (p & 7) << 3;

    float4v acc = {0.f, 0.f, 0.f, 0.f};
    #pragma unroll
    for (int kk = 0; kk < 6; ++kk) {
        const int ki = kk * 32 + g * 8;
        const short8v af = *reinterpret_cast<const short8v*>(&A1[oA * 192 + (ki ^ aswz)]);
        const short8v bf = *reinterpret_cast<const short8v*>(&B1[p * 192 + (ki ^ bswz)]);
        acc = __builtin_amdgcn_mfma_f32_16x16x32_bf16(af, bf, acc, 0, 0, 0);
    }
    float vals[4];
    float s1 = 0.f, s2 = 0.f;
    #pragma unroll
    for (int r = 0; r < 4; ++r) {
        const int o = tm * 16 + g * 4 + r;
        const float v = acc[r] + prm[o];
        vals[r] = v;
        if (o < DSQ) { s1 += v; s2 += v * v; }
    }
    red1[tm * 4 + g][p] = s1;
    red2[tm * 4 + g][p] = s2;
    __syncthreads();
    float t1 = 0.f, t2 = 0.f;
    #pragma unroll
    for (int j = 0; j < 16; ++j) { t1 += red1[j][p]; t2 += red2[j][p]; }
    const float mean = t1 * (1.0f / 49.0f);
    const float var  = t2 * (1.0f / 49.0f) - mean * mean;
    const float rstd = rsqrtf(var + 1e-6f);
    #pragma unroll
    for (int r = 0; r < 4; ++r) {
        const int o = tm * 16 + g * 4 + r;
        if (o < DSQ) {
            const float v = (vals[r] - mean) * rstd * prm[64 + o] + prm[128 + o];
            const float sv = v * sigm(v);
            B2[p * 64 + (o ^ bswz)] = f2bf(sv);
        }
    }
    __syncthreads();

    // ---- fixup conv2 MFMA ----
    float4v acc2 = {0.f, 0.f, 0.f, 0.f};
    #pragma unroll
    for (int kk = 0; kk < 2; ++kk) {
        const int ki = kk * 32 + g * 8;
        const short8v af = *reinterpret_cast<const short8v*>(&A2[oA * 64 + (ki ^ aswz)]);
        const short8v bf = *reinterpret_cast<const short8v*>(&B2[p * 64 + (ki ^ bswz)]);
        acc2 = __builtin_amdgcn_mfma_f32_16x16x32_bf16(af, bf, acc2, 0, 0, 0);
    }
    float c2v[4];
    float ps = 0.f;
    #pragma unroll
    for (int r = 0; r < 4; ++r) {
        const int o = tm * 16 + g * 4 + r;
        if (o < DSQ) {
            const float f = acc2[r] + prm[192 + o];
            c2v[r] = sCmb[o][p] * (1.0f + sigm(f));
            ps += c2v[r];
        } else c2v[r] = 0.f;
    }
    red1[tm * 4 + g][p] = ps;
    __syncthreads();
    float tot = 0.f;
    #pragma unroll
    for (int j = 0; j < 16; ++j) tot += red1[j][p];
    const float invt = 1.0f / (tot + 1e-7f);
    float* wrow = wts + (b * DSQ * HH + h) * WW;
    #pragma unroll
    for (int r = 0; r < 4; ++r) {
        const int o = tm * 16 + g * 4 + r;
        if (o < DSQ) wrow[o * HH * WW + p] = c2v[r] * invt;
    }
}

// ---- fused: aggregate -> (bf16 sXT) -> output_proj conv-LN-conv MFMA -> d_out
__global__ __launch_bounds__(1024) void aggproj_kernel(
    const float* __restrict__ spatial, const float* __restrict__ wts,
    const float* __restrict__ w1, const float* __restrict__ b1,
    const float* __restrict__ lnw, const float* __restrict__ lnb,
    const float* __restrict__ w2, const float* __restrict__ b2,
    float* __restrict__ out)
{
    __shared__ alignas(16) char sBufC[32 * DD * WW * 4];   // 57.3 KB: sS | sT
    __shared__ short sWb[CDIM * CDIM];
    __shared__ short sXT[WW * CDIM];
    __shared__ short sXT2[WW * CDIM];
    __shared__ float red1[16][WW];
    __shared__ float red2[16][WW];

    float (*sS)[DD * WW] = reinterpret_cast<float(*)[DD * WW]>(sBufC);
    float (*sT)[65]      = reinterpret_cast<float(*)[65]>(sBufC);

    const int tid = threadIdx.x;
    const int l = tid & 63;
    const int q = tid >> 6;
    const int qu = __builtin_amdgcn_readfirstlane(q);
    const int b = blockIdx.x >> 6;
    const int h = blockIdx.x & 63;

    {
        const int o = tid >> 3;
        const int i0 = (tid & 7) * 16;
        const int sw = (o & 7) << 3;
        const float* src = w1 + o * CDIM + i0;
        short8v pk0, pk1;
        #pragma unroll
        for (int j = 0; j < 8; ++j) pk0[j] = f2bf(src[j]);
        #pragma unroll
        for (int j = 0; j < 8; ++j) pk1[j] = f2bf(src[8 + j]);
        *reinterpret_cast<short8v*>(&sWb[o * 128 + (i0 ^ sw)]) = pk0;
        *reinterpret_cast<short8v*>(&sWb[o * 128 + ((i0 + 8) ^ sw)]) = pk1;
    }
    float wv[DSQ];
    {
        const float* wrow = wts + (b * DSQ * HH + h) * WW + l;
        #pragma unroll
        for (int n = 0; n < DSQ; ++n) wv[n] = wrow[n * HH * WW];
    }
    int coff[DD];
    #pragma unroll
    for (int kj = 0; kj < DD; ++kj) coff[kj] = reflect64(l + kj - RR);

    const float* sb = spatial + b * CDIM * HH * WW;
    for (int cc = 0; cc < 4; ++cc) {
        __syncthreads();
        for (int idx = tid; idx < 32 * DD * 16; idx += 1024) {
            const int pos = idx & 15;
            const int rk  = idx >> 4;
            const int cl  = rk / 7;
            const int ki  = rk - cl * 7;
            const int hp  = reflect64(h + ki - RR);
            *reinterpret_cast<float4*>(&sS[cl][ki * WW + pos * 4]) =
                *reinterpret_cast<const float4*>(
                    &sb[(cc * 32 + cl) * HH * WW + hp * WW + pos * 4]);
        }
        __syncthreads();
        float acc0 = 0.f, acc1 = 0.f;
        const int c0 = q * 2;
        #pragma unroll
        for (int n = 0; n < DSQ; ++n) {
            const int ki = n / 7, kj = n % 7;
            const int off = ki * WW + coff[kj];
            acc0 = fmaf(sS[c0][off],     wv[n], acc0);
            acc1 = fmaf(sS[c0 + 1][off], wv[n], acc1);
        }
        const int cg = cc * 32 + c0;
        const int p = l, psw = (p & 7) << 3;
        sXT[p * 128 + (cg ^ psw)]       = f2bf(acc0);
        sXT[p * 128 + ((cg + 1) ^ psw)] = f2bf(acc1);
    }
    __syncthreads();

    const int lm = l & 15, g = l >> 4;
    const int tm = q >> 1;
    const int tn0 = (q & 1) * 2;
    const int oa = tm * 16 + lm;
    const int arow = oa * 128, asw = (oa & 7) << 3;
    const int p0 = tn0 * 16 + lm, p1 = (tn0 + 1) * 16 + lm;
    const int bsw0 = (p0 & 7) << 3, bsw1 = (p1 & 7) << 3;

    float4v acc0 = {0.f, 0.f, 0.f, 0.f}, acc1 = {0.f, 0.f, 0.f, 0.f};
    #pragma unroll
    for (int kk = 0; kk < 4; ++kk) {
        const int ki = kk * 32 + g * 8;
        const short8v af = *reinterpret_cast<const short8v*>(&sWb[arow + (ki ^ asw)]);
        const short8v bf0 = *reinterpret_cast<const short8v*>(&sXT[p0 * 128 + (ki ^ bsw0)]);
        const short8v bf1 = *reinterpret_cast<const short8v*>(&sXT[p1 * 128 + (ki ^ bsw1)]);
        acc0 = __builtin_amdgcn_mfma_f32_16x16x32_bf16(af, bf0, acc0, 0, 0, 0);
        acc1 = __builtin_amdgcn_mfma_f32_16x16x32_bf16(af, bf1, acc1, 0, 0, 0);
    }
    #pragma unroll
    for (int r = 0; r < 4; ++r) sT[tm * 16 + g * 4 + r][p0] = acc0[r];
    #pragma unroll
    for (int r = 0; r < 4; ++r) sT[tm * 16 + g * 4 + r][p1] = acc1[r];
    __syncthreads();

    {
        const int o = tid >> 3;
        const int i0 = (tid & 7) * 16;
        const int sw = (o & 7) << 3;
        const float* src = w2 + o * CDIM + i0;
        short8v pk0, pk1;
        #pragma unroll
        for (int j = 0; j < 8; ++j) pk0[j] = f2bf(src[j]);
        #pragma unroll
        for (int j = 0; j < 8; ++j) pk1[j] = f2bf(src[8 + j]);
        *reinterpret_cast<short8v*>(&sWb[o * 128 + (i0 ^ sw)]) = pk0;
        *reinterpret_cast<short8v*>(&sWb[o * 128 + ((i0 + 8) ^ sw)]) = pk1;
    }
    {
        const int p = l;
        float vals[8];
        float s1 = 0.f, s2 = 0.f;
        #pragma unroll
        for (int j = 0; j < 8; ++j) {
            const float v = sT[qu * 8 + j][p] + b1[qu * 8 + j];
            vals[j] = v; s1 += v; s2 += v * v;
        }
        red1[q][p] = s1; red2[q][p] = s2;
        __syncthreads();
        float t1 = 0.f, t2 = 0.f;
        #pragma unroll
        for (int j = 0; j < 16; ++j) { t1 += red1[j][p]; t2 += red2[j][p]; }
        const float mean = t1 * (1.0f / 128.0f);
        const float var  = t2 * (1.0f / 128.0f) - mean * mean;
        const float rstd = rsqrtf(var + 1e-6f);
        short8v pk;
        #pragma unroll
        for (int j = 0; j < 8; ++j) {
            const float v = (vals[j] - mean) * rstd * lnw[qu * 8 + j] + lnb[qu * 8 + j];
            pk[j] = f2bf(v);
        }
        *reinterpret_cast<short8v*>(&sXT2[p * 128 + ((qu * 8) ^ ((p & 7) << 3))]) = pk;
    }
    __syncthreads();

    {
        float4v a0 = {0.f, 0.f, 0.f, 0.f}, a1 = {0.f, 0.f, 0.f, 0.f};
        #pragma unroll
        for (int kk = 0; kk < 4; ++kk) {
            const int ki = kk * 32 + g * 8;
            const short8v af = *reinterpret_cast<const short8v*>(&sWb[arow + (ki ^ asw)]);
            const short8v bf0 = *reinterpret_cast<const short8v*>(&sXT2[p0 * 128 + (ki ^ bsw0)]);
            const short8v bf1 = *reinterpret_cast<const short8v*>(&sXT2[p1 * 128 + (ki ^ bsw1)]);
            a0 = __builtin_amdgcn_mfma_f32_16x16x32_bf16(af, bf0, a0, 0, 0, 0);
            a1 = __builtin_amdgcn_mfma_f32_16x16x32_bf16(af, bf1, a1, 0, 0, 0);
        }
        const float4 bv = *reinterpret_cast<const float4*>(&b2[tm * 16 + g * 4]);
        float* obase = out + (b * CDIM * HH + h) * WW;
        #pragma unroll
        for (int r = 0; r < 4; ++r) {
            const float bias = ((const float*)&bv)[r];
            obase[(tm * 16 + g * 4 + r) * HH * WW + p0] = a0[r] + bias;
            obase[(tm * 16 + g * 4 + r) * HH * WW + p1] = a1[r] + bias;
        }
    }
}

extern "C" void kernel_launch(void* const* d_in, const int* in_sizes, int n_in,
                              void* d_out, int out_size, void* d_ws, size_t ws_size,
                              hipStream_t stream) {
    (void)in_sizes; (void)n_in; (void)out_size; (void)ws_size;
    const float* spatial  = (const float*)d_in[0];
    const float* semantic = (const float*)d_in[1];
    const float* rp_w1 = (const float*)d_in[2];
    const float* rp_b1 = (const float*)d_in[3];
    const float* rp_lnw = (const float*)d_in[4];
    const float* rp_lnb = (const float*)d_in[5];
    const float* rp_w2 = (const float*)d_in[6];
    const float* rp_b2 = (const float*)d_in[7];
    const float* fx_w1 = (const float*)d_in[8];
    const float* fx_b1 = (const float*)d_in[9];
    const float* fx_lnw = (const float*)d_in[10];
    const float* fx_lnb = (const float*)d_in[11];
    const float* fx_w2 = (const float*)d_in[12];
    const float* fx_b2 = (const float*)d_in[13];
    const float* sigma = (const float*)d_in[14];
    const float* op_w1 = (const float*)d_in[15];
    const float* op_b1 = (const float*)d_in[16];
    const float* op_lnw = (const float*)d_in[17];
    const float* op_lnb = (const float*)d_in[18];
    const float* op_w2 = (const float*)d_in[19];
    const float* op_b2 = (const float*)d_in[20];

    char* wsb = (char*)d_ws;
    short* pxt    = (short*)wsb;                             // 4 MB bf16 [b][h][p][c]
    float* wtsbuf = (float*)(wsb + 4u * 1024u * 1024u);      // 3.2 MB
    float* outp   = (float*)d_out;

    dim3 grid(BB * HH), blk(1024);
    proj_kernel<true><<<grid, blk, 0, stream>>>(semantic, rp_w1, rp_b1, rp_lnw, rp_lnb,
                                                rp_w2, rp_b2, pxt);
    simfix_kernel<<<grid, blk, 0, stream>>>(pxt, sigma, semantic, fx_w1, fx_b1,
                                            fx_lnw, fx_lnb, fx_w2, fx_b2, wtsbuf);
    aggproj_kernel<<<grid, blk, 0, stream>>>(spatial, wtsbuf, op_w1, op_b1, op_lnw,
                                             op_lnb, op_w2, op_b2, outp);
}

// Round 14
// 62.121 us; speedup vs baseline: 1.1191x; 1.1191x over previous
//
#include <hip/hip_runtime.h>
#include <cstdint>

#define BB 4
#define CDIM 128
#define HH 64
#define WW 64
#define RR 3
#define DD 7
#define DSQ 49

typedef __attribute__((ext_vector_type(8))) short short8v;   // 8 bf16 = 4 VGPR
typedef __attribute__((ext_vector_type(4))) float float4v;

__device__ __forceinline__ int reflect64(int p) {
    p = (p < 0) ? -p : p;
    return (p > 63) ? (126 - p) : p;
}
__device__ __forceinline__ float sigm(float x) { return 1.0f / (1.0f + __expf(-x)); }
__device__ __forceinline__ short f2bf(float f) {     // f32 -> bf16 RNE
    uint32_t u = __float_as_uint(f);
    u += 0x7FFF + ((u >> 16) & 1);
    return (short)(u >> 16);
}

// ---- range_proj: conv1x1 -> LN -> SiLU -> conv1x1 via bf16 MFMA.
// Output: bf16 TRANSPOSED [b][h][p][c].
template<bool SILU>
__global__ __launch_bounds__(1024) void proj_kernel(
    const float* __restrict__ x, const float* __restrict__ w1,
    const float* __restrict__ b1, const float* __restrict__ lnw,
    const float* __restrict__ lnb, const float* __restrict__ w2,
    const float* __restrict__ b2, short* __restrict__ outT)
{
    __shared__ short sW1[CDIM * CDIM];
    __shared__ short sW2[CDIM * CDIM];
    __shared__ short sXT[WW * CDIM];
    __shared__ short sXT2[WW * CDIM];
    __shared__ float sT[CDIM][65];
    __shared__ float red1[16][WW];
    __shared__ float red2[16][WW];

    const int tid = threadIdx.x;
    const int l = tid & 63;
    const int q = tid >> 6;
    const int qu = __builtin_amdgcn_readfirstlane(q);
    const int b = blockIdx.x >> 6;
    const int h = blockIdx.x & 63;

    {
        const int o = tid >> 3;
        const int i0 = (tid & 7) * 16;
        const int sw = (o & 7) << 3;
        const float* wsrc[2] = {w1, w2};
        short* wdst[2] = {sW1, sW2};
        #pragma unroll
        for (int m = 0; m < 2; ++m) {
            const float* src = wsrc[m] + o * CDIM + i0;
            short8v pk0, pk1;
            #pragma unroll
            for (int j = 0; j < 8; ++j) pk0[j] = f2bf(src[j]);
            #pragma unroll
            for (int j = 0; j < 8; ++j) pk1[j] = f2bf(src[8 + j]);
            *reinterpret_cast<short8v*>(&wdst[m][o * 128 + (i0 ^ sw)]) = pk0;
            *reinterpret_cast<short8v*>(&wdst[m][o * 128 + ((i0 + 8) ^ sw)]) = pk1;
        }
    }
    {
        const int pos = tid & 15;
        const int c0 = tid >> 4;
        const float* xrow = x + (b * CDIM * HH + h) * WW;
        #pragma unroll
        for (int rr = 0; rr < 2; ++rr) {
            const int c = c0 + rr * 64;
            const float4 v = *reinterpret_cast<const float4*>(&xrow[c * HH * WW + pos * 4]);
            #pragma unroll
            for (int m = 0; m < 4; ++m) {
                const int p = pos * 4 + m;
                sXT[p * 128 + (c ^ ((p & 7) << 3))] = f2bf(((const float*)&v)[m]);
            }
        }
    }
    __syncthreads();

    const int lm = l & 15, g = l >> 4;
    const int tm = q >> 1;
    const int tn0 = (q & 1) * 2;
    const int oa = tm * 16 + lm;
    const int arow = oa * 128, asw = (oa & 7) << 3;
    const int p0 = tn0 * 16 + lm, p1 = (tn0 + 1) * 16 + lm;
    const int bsw0 = (p0 & 7) << 3, bsw1 = (p1 & 7) << 3;

    float4v acc0 = {0.f, 0.f, 0.f, 0.f}, acc1 = {0.f, 0.f, 0.f, 0.f};
    #pragma unroll
    for (int kk = 0; kk < 4; ++kk) {
        const int ki = kk * 32 + g * 8;
        const short8v af = *reinterpret_cast<const short8v*>(&sW1[arow + (ki ^ asw)]);
        const short8v bf0 = *reinterpret_cast<const short8v*>(&sXT[p0 * 128 + (ki ^ bsw0)]);
        const short8v bf1 = *reinterpret_cast<const short8v*>(&sXT[p1 * 128 + (ki ^ bsw1)]);
        acc0 = __builtin_amdgcn_mfma_f32_16x16x32_bf16(af, bf0, acc0, 0, 0, 0);
        acc1 = __builtin_amdgcn_mfma_f32_16x16x32_bf16(af, bf1, acc1, 0, 0, 0);
    }
    #pragma unroll
    for (int r = 0; r < 4; ++r) sT[tm * 16 + g * 4 + r][p0] = acc0[r];
    #pragma unroll
    for (int r = 0; r < 4; ++r) sT[tm * 16 + g * 4 + r][p1] = acc1[r];
    __syncthreads();

    {
        const int p = l;
        float vals[8];
        float s1 = 0.f, s2 = 0.f;
        #pragma unroll
        for (int j = 0; j < 8; ++j) {
            const float v = sT[qu * 8 + j][p] + b1[qu * 8 + j];
            vals[j] = v; s1 += v; s2 += v * v;
        }
        red1[q][p] = s1; red2[q][p] = s2;
        __syncthreads();
        float t1 = 0.f, t2 = 0.f;
        #pragma unroll
        for (int j = 0; j < 16; ++j) { t1 += red1[j][p]; t2 += red2[j][p]; }
        const float mean = t1 * (1.0f / 128.0f);
        const float var  = t2 * (1.0f / 128.0f) - mean * mean;
        const float rstd = rsqrtf(var + 1e-6f);
        short8v pk;
        #pragma unroll
        for (int j = 0; j < 8; ++j) {
            float v = (vals[j] - mean) * rstd * lnw[qu * 8 + j] + lnb[qu * 8 + j];
            if (SILU) v = v * sigm(v);
            pk[j] = f2bf(v);
        }
        *reinterpret_cast<short8v*>(&sXT2[p * 128 + ((qu * 8) ^ ((p & 7) << 3))]) = pk;
    }
    __syncthreads();

    {
        float4v a0 = {0.f, 0.f, 0.f, 0.f}, a1 = {0.f, 0.f, 0.f, 0.f};
        #pragma unroll
        for (int kk = 0; kk < 4; ++kk) {
            const int ki = kk * 32 + g * 8;
            const short8v af = *reinterpret_cast<const short8v*>(&sW2[arow + (ki ^ asw)]);
            const short8v bf0 = *reinterpret_cast<const short8v*>(&sXT2[p0 * 128 + (ki ^ bsw0)]);
            const short8v bf1 = *reinterpret_cast<const short8v*>(&sXT2[p1 * 128 + (ki ^ bsw1)]);
            a0 = __builtin_amdgcn_mfma_f32_16x16x32_bf16(af, bf0, a0, 0, 0, 0);
            a1 = __builtin_amdgcn_mfma_f32_16x16x32_bf16(af, bf1, a1, 0, 0, 0);
        }
        const float4 bv = *reinterpret_cast<const float4*>(&b2[tm * 16 + g * 4]);
        #pragma unroll
        for (int r = 0; r < 4; ++r) {
            const float bias = ((const float*)&bv)[r];
            sT[tm * 16 + g * 4 + r][p0] = a0[r] + bias;
            sT[tm * 16 + g * 4 + r][p1] = a1[r] + bias;
        }
    }
    __syncthreads();
    {
        const int p = tid >> 4;
        const int c0 = (tid & 15) * 8;
        short8v pk;
        #pragma unroll
        for (int j = 0; j < 8; ++j) pk[j] = f2bf(sT[c0 + j][p]);
        *reinterpret_cast<short8v*>(&outT[((b * HH + h) * WW + p) * CDIM + c0]) = pk;
    }
}

// ---- fully fused: Gram-MFMA sim -> softmax*spatial -> MFMA fixup (wts in LDS)
//      -> aggregate -> output_proj MFMA -> d_out
__global__ __launch_bounds__(1024) void simfixagg_kernel(
    const short* __restrict__ pxt, const float* __restrict__ sigma_p,
    const float* __restrict__ sem,
    const float* __restrict__ fw1, const float* __restrict__ fb1,
    const float* __restrict__ flnw, const float* __restrict__ flnb,
    const float* __restrict__ fw2, const float* __restrict__ fb2,
    const float* __restrict__ spatial,
    const float* __restrict__ ow1, const float* __restrict__ ob1,
    const float* __restrict__ olnw, const float* __restrict__ olnb,
    const float* __restrict__ ow2, const float* __restrict__ ob2,
    float* __restrict__ out)
{
    __shared__ alignas(16) char sBig[7 * WW * CDIM * 2];   // 114,688 B
    __shared__ alignas(16) char sAux[64 * 66 * 4];         //  16,896 B
    __shared__ alignas(16) float sSimWts[DSQ][64];         //  12,544 B: sSim then sWts
    __shared__ alignas(16) float sCmb[DSQ][66];            //  12,936 B

    // Gram phase
    short* rows = reinterpret_cast<short*>(sBig);
    // fixup overlay
    short* B1   = reinterpret_cast<short*>(sBig);          // [64 px][192]
    short* A1   = reinterpret_cast<short*>(sBig + 24576);  // [64 o ][192]
    short* B2   = reinterpret_cast<short*>(sBig + 49152);  // [64 px][64]
    short* A2   = reinterpret_cast<short*>(sBig + 57344);  // [64 o ][64]
    float* fSem = reinterpret_cast<float*>(sBig + 65536);  // [128][64]
    float* prm  = reinterpret_cast<float*>(sBig + 98304);  // 4 x 64
    // agg/op-proj overlay
    float (*sS)[DD * WW] = reinterpret_cast<float(*)[DD * WW]>(sBig);   // 57,344
    float (*sT)[65]      = reinterpret_cast<float(*)[65]>(sBig);        // 33,280
    short* sWb = reinterpret_cast<short*>(sBig + 57344);                // 32,768
    short* sXT = reinterpret_cast<short*>(sBig + 90112);                // 16,384

    float (*sP64)[66] = reinterpret_cast<float(*)[66]>(sAux);
    float (*red1)[65] = reinterpret_cast<float(*)[65]>(sAux);
    float (*red2)[65] = reinterpret_cast<float(*)[65]>(sAux + 16 * 65 * 4);

    const int tid = threadIdx.x;
    const int l = tid & 63;
    const int q = tid >> 6;
    const int qu = __builtin_amdgcn_readfirstlane(q);
    const int b = blockIdx.x >> 6;
    const int h = blockIdx.x & 63;

    // ---- stage 7 reflected rows, bf16 [row][p][c] swz ----
    for (int idx = tid; idx < 7 * WW * 16; idx += 1024) {
        const int cchunk = idx & 15;
        const int p = (idx >> 4) & 63;
        const int row = idx >> 10;
        const int hp = reflect64(h + row - RR);
        const short8v v = *reinterpret_cast<const short8v*>(
            &pxt[((b * HH + hp) * WW + p) * CDIM + cchunk * 8]);
        *reinterpret_cast<short8v*>(
            &rows[(row * WW + p) * CDIM + ((cchunk * 8) ^ ((p & 7) << 3))]) = v;
    }
    __syncthreads();

    // ---- Gram MFMA per ki (sP64 gather variant, r12-validated) ----
    const int lm = l & 15, g = l >> 4;
    const int tm = q >> 2, tn = q & 3;
    const int pa = tm * 16 + lm;
    const int pxb = tn * 16 + lm;
    const int abase = (3 * WW + pa) * CDIM, as_ = (pa & 7) << 3;
    const int bs_ = (pxb & 7) << 3;

    short8v afr[4];
    #pragma unroll
    for (int kk = 0; kk < 4; ++kk)
        afr[kk] = *reinterpret_cast<const short8v*>(
            &rows[abase + ((kk * 32 + g * 8) ^ as_)]);

    const float rscale = 0.088388347648318447f;  // 1/sqrt(128)
    for (int ki = 0; ki < 7; ++ki) {
        float4v acc = {0.f, 0.f, 0.f, 0.f};
        const int bbase = (ki * WW + pxb) * CDIM;
        #pragma unroll
        for (int kk = 0; kk < 4; ++kk) {
            const short8v bf = *reinterpret_cast<const short8v*>(
                &rows[bbase + ((kk * 32 + g * 8) ^ bs_)]);
            acc = __builtin_amdgcn_mfma_f32_16x16x32_bf16(afr[kk], bf, acc, 0, 0, 0);
        }
        #pragma unroll
        for (int r = 0; r < 4; ++r)
            sP64[tm * 16 + g * 4 + r][tn * 16 + lm] = acc[r];
        __syncthreads();
        if (tid < 448) {
            const int kj = tid >> 6, p = tid & 63;
            sSimWts[ki * 7 + kj][p] = sP64[p][reflect64(p + kj - RR)] * rscale;
        }
        __syncthreads();
    }
    // rows/sP64 dead -> stage fixup overlays

    // A1: fw1 -> bf16 [64][192]: [0:49]=cmb-cols, [49:64]=0, [64:192]=sem-cols
    for (int idx = tid; idx < 64 * 24; idx += 1024) {
        const int o = idx / 24;
        const int ch0 = (idx % 24) * 8;
        short8v pk;
        #pragma unroll
        for (int j = 0; j < 8; ++j) {
            const int c = ch0 + j;
            float v = 0.f;
            if (o < DSQ) {
                if (c < DSQ) v = fw1[o * 177 + c];
                else if (c >= 64) v = fw1[o * 177 + DSQ + (c - 64)];
            }
            pk[j] = f2bf(v);
        }
        *reinterpret_cast<short8v*>(&A1[o * 192 + (ch0 ^ ((o & 7) << 3))]) = pk;
    }
    // A2: fw2 -> bf16 [64][64], zero-padded
    for (int idx = tid; idx < 64 * 8; idx += 1024) {
        const int o = idx >> 3;
        const int ch0 = (idx & 7) * 8;
        short8v pk;
        #pragma unroll
        for (int j = 0; j < 8; ++j) {
            const int c = ch0 + j;
            pk[j] = (o < DSQ && c < DSQ) ? f2bf(fw2[o * DSQ + c]) : (short)0;
        }
        *reinterpret_cast<short8v*>(&A2[o * 64 + (ch0 ^ ((o & 7) << 3))]) = pk;
    }
    // B2 zero-fill
    {
        const short8v z = {0, 0, 0, 0, 0, 0, 0, 0};
        for (int idx = tid; idx < 64 * 8; idx += 1024)
            *reinterpret_cast<short8v*>(&B2[idx * 8]) = z;
    }
    // B1 pad cols [49..64) zero
    for (int idx = tid; idx < 64 * 15; idx += 1024) {
        const int p = idx / 15, c = DSQ + idx % 15;
        B1[p * 192 + (c ^ ((p & 7) << 3))] = 0;
    }
    // params
    for (int idx = tid; idx < 256; idx += 1024) {
        const int a = idx >> 6, i = idx & 63;
        float v = 0.f;
        if (i < DSQ) {
            if (a == 0) v = fb1[i];
            else if (a == 1) v = flnw[i];
            else if (a == 2) v = flnb[i];
            else v = fb2[i];
        }
        prm[a * 64 + i] = v;
    }
    // fSem f32 [c][p]
    {
        const float* srow = sem + (b * CDIM * HH + h) * WW;
        for (int idx = tid; idx < CDIM * 16; idx += 1024) {
            const int r = idx >> 4, pos = idx & 15;
            *reinterpret_cast<float4*>(&fSem[r * WW + pos * 4]) =
                *reinterpret_cast<const float4*>(&srow[r * HH * WW + pos * 4]);
        }
    }
    // softmax * spatial kernel -> sCmb f32 + B1 cmb-cols bf16
    {
        float rv[DSQ];
        #pragma unroll
        for (int n = 0; n < DSQ; ++n) rv[n] = sSimWts[n][l];
        float m = -1e30f;
        #pragma unroll
        for (int n = 0; n < DSQ; ++n) m = fmaxf(m, rv[n]);
        float ssum = 0.f;
        #pragma unroll
        for (int n = 0; n < DSQ; ++n) ssum += __expf(rv[n] - m);
        const float inv = 1.0f / ssum;
        const float sigma = sigma_p[0];
        const float inv2s2 = 1.0f / (2.0f * sigma * sigma);
        const int swl = (l & 7) << 3;
        #pragma unroll
        for (int k = 0; k < 4; ++k) {
            const int n = q + 16 * k;
            if (n < DSQ) {
                const int ki = n / 7, kj = n % 7;
                const float dx = (float)(ki - 3) * (1.0f / 3.0f);
                const float dy = (float)(kj - 3) * (1.0f / 3.0f);
                const float sk = __expf(-(dx * dx + dy * dy) * inv2s2);
                const float cv = __expf(rv[n] - m) * inv * sk;
                sCmb[n][l] = cv;
                B1[l * 192 + (n ^ swl)] = f2bf(cv);
            }
        }
    }
    __syncthreads();
    // B1 sem-cols: transpose-pack from fSem
    {
        const int c0 = q * 8;
        short8v pk;
        #pragma unroll
        for (int j = 0; j < 8; ++j) pk[j] = f2bf(fSem[(c0 + j) * WW + l]);
        *reinterpret_cast<short8v*>(&B1[l * 192 + ((64 + c0) ^ ((l & 7) << 3))]) = pk;
    }
    __syncthreads();

    // ---- fixup conv1 MFMA ----
    const int oA = tm * 16 + lm;
    const int aswz = (oA & 7) << 3;
    const int p = tn * 16 + lm;
    const int bswz = (p & 7) << 3;

    float4v facc = {0.f, 0.f, 0.f, 0.f};
    #pragma unroll
    for (int kk = 0; kk < 6; ++kk) {
        const int ki = kk * 32 + g * 8;
        const short8v af = *reinterpret_cast<const short8v*>(&A1[oA * 192 + (ki ^ aswz)]);
        const short8v bf = *reinterpret_cast<const short8v*>(&B1[p * 192 + (ki ^ bswz)]);
        facc = __builtin_amdgcn_mfma_f32_16x16x32_bf16(af, bf, facc, 0, 0, 0);
    }
    float vals[4];
    float s1 = 0.f, s2 = 0.f;
    #pragma unroll
    for (int r = 0; r < 4; ++r) {
        const int o = tm * 16 + g * 4 + r;
        const float v = facc[r] + prm[o];
        vals[r] = v;
        if (o < DSQ) { s1 += v; s2 += v * v; }
    }
    red1[tm * 4 + g][p] = s1;
    red2[tm * 4 + g][p] = s2;
    __syncthreads();
    float t1 = 0.f, t2 = 0.f;
    #pragma unroll
    for (int j = 0; j < 16; ++j) { t1 += red1[j][p]; t2 += red2[j][p]; }
    const float mean = t1 * (1.0f / 49.0f);
    const float var  = t2 * (1.0f / 49.0f) - mean * mean;
    const float rstd = rsqrtf(var + 1e-6f);
    #pragma unroll
    for (int r = 0; r < 4; ++r) {
        const int o = tm * 16 + g * 4 + r;
        if (o < DSQ) {
            const float v = (vals[r] - mean) * rstd * prm[64 + o] + prm[128 + o];
            const float sv = v * sigm(v);
            B2[p * 64 + (o ^ bswz)] = f2bf(sv);
        }
    }
    __syncthreads();

    // ---- fixup conv2 MFMA + gate + normalize -> sWts (LDS) ----
    float4v facc2 = {0.f, 0.f, 0.f, 0.f};
    #pragma unroll
    for (int kk = 0; kk < 2; ++kk) {
        const int ki = kk * 32 + g * 8;
        const short8v af = *reinterpret_cast<const short8v*>(&A2[oA * 64 + (ki ^ aswz)]);
        const short8v bf = *reinterpret_cast<const short8v*>(&B2[p * 64 + (ki ^ bswz)]);
        facc2 = __builtin_amdgcn_mfma_f32_16x16x32_bf16(af, bf, facc2, 0, 0, 0);
    }
    float c2v[4];
    float ps = 0.f;
    #pragma unroll
    for (int r = 0; r < 4; ++r) {
        const int o = tm * 16 + g * 4 + r;
        if (o < DSQ) {
            const float f = facc2[r] + prm[192 + o];
            c2v[r] = sCmb[o][p] * (1.0f + sigm(f));
            ps += c2v[r];
        } else c2v[r] = 0.f;
    }
    red1[tm * 4 + g][p] = ps;
    __syncthreads();
    float tot = 0.f;
    #pragma unroll
    for (int j = 0; j < 16; ++j) tot += red1[j][p];
    const float invt = 1.0f / (tot + 1e-7f);
    #pragma unroll
    for (int r = 0; r < 4; ++r) {
        const int o = tm * 16 + g * 4 + r;
        if (o < DSQ) sSimWts[o][p] = c2v[r] * invt;   // sSim region reused as sWts
    }
    __syncthreads();

    // ---- aggregate phase (wts from LDS) ----
    // stage op_w1 bf16 swizzled into sWb
    {
        const int o = tid >> 3;
        const int i0 = (tid & 7) * 16;
        const int sw = (o & 7) << 3;
        const float* src = ow1 + o * CDIM + i0;
        short8v pk0, pk1;
        #pragma unroll
        for (int j = 0; j < 8; ++j) pk0[j] = f2bf(src[j]);
        #pragma unroll
        for (int j = 0; j < 8; ++j) pk1[j] = f2bf(src[8 + j]);
        *reinterpret_cast<short8v*>(&sWb[o * 128 + (i0 ^ sw)]) = pk0;
        *reinterpret_cast<short8v*>(&sWb[o * 128 + ((i0 + 8) ^ sw)]) = pk1;
    }
    float wv[DSQ];
    #pragma unroll
    for (int n = 0; n < DSQ; ++n) wv[n] = sSimWts[n][l];
    int coff[DD];
    #pragma unroll
    for (int kj = 0; kj < DD; ++kj) coff[kj] = reflect64(l + kj - RR);

    const float* sb = spatial + b * CDIM * HH * WW;
    for (int cc = 0; cc < 4; ++cc) {
        __syncthreads();
        for (int idx = tid; idx < 32 * DD * 16; idx += 1024) {
            const int pos = idx & 15;
            const int rk  = idx >> 4;
            const int cl  = rk / 7;
            const int ki  = rk - cl * 7;
            const int hp  = reflect64(h + ki - RR);
            *reinterpret_cast<float4*>(&sS[cl][ki * WW + pos * 4]) =
                *reinterpret_cast<const float4*>(
                    &sb[(cc * 32 + cl) * HH * WW + hp * WW + pos * 4]);
        }
        __syncthreads();
        float a0 = 0.f, a1 = 0.f;
        const int c0 = q * 2;
        #pragma unroll
        for (int n = 0; n < DSQ; ++n) {
            const int ki = n / 7, kj = n % 7;       // compile-time
            const int off = ki * WW + coff[kj];
            a0 = fmaf(sS[c0][off],     wv[n], a0);
            a1 = fmaf(sS[c0 + 1][off], wv[n], a1);
        }
        const int cg = cc * 32 + c0;
        const int psw = (l & 7) << 3;
        sXT[l * 128 + (cg ^ psw)]       = f2bf(a0);
        sXT[l * 128 + ((cg + 1) ^ psw)] = f2bf(a1);
    }
    __syncthreads();          // sXT complete; sS dead

    // ---- output_proj conv1 MFMA ----
    const int tmo = q >> 1;
    const int tn0 = (q & 1) * 2;
    const int oaop = tmo * 16 + lm;
    const int arow = oaop * 128, asw = (oaop & 7) << 3;
    const int p0 = tn0 * 16 + lm, p1 = (tn0 + 1) * 16 + lm;
    const int bsw0 = (p0 & 7) << 3, bsw1 = (p1 & 7) << 3;

    {
        float4v a0 = {0.f, 0.f, 0.f, 0.f}, a1 = {0.f, 0.f, 0.f, 0.f};
        #pragma unroll
        for (int kk = 0; kk < 4; ++kk) {
            const int ki = kk * 32 + g * 8;
            const short8v af = *reinterpret_cast<const short8v*>(&sWb[arow + (ki ^ asw)]);
            const short8v bf0 = *reinterpret_cast<const short8v*>(&sXT[p0 * 128 + (ki ^ bsw0)]);
            const short8v bf1 = *reinterpret_cast<const short8v*>(&sXT[p1 * 128 + (ki ^ bsw1)]);
            a0 = __builtin_amdgcn_mfma_f32_16x16x32_bf16(af, bf0, a0, 0, 0, 0);
            a1 = __builtin_amdgcn_mfma_f32_16x16x32_bf16(af, bf1, a1, 0, 0, 0);
        }
        __syncthreads();      // sS/sT region free; sXT reads done (will rewrite below)
        #pragma unroll
        for (int r = 0; r < 4; ++r) sT[tmo * 16 + g * 4 + r][p0] = a0[r];
        #pragma unroll
        for (int r = 0; r < 4; ++r) sT[tmo * 16 + g * 4 + r][p1] = a1[r];
    }
    __syncthreads();

    // restage sWb = op_w2; bias + LN(128) -> sXT (reused as conv2 B operand)
    {
        const int o = tid >> 3;
        const int i0 = (tid & 7) * 16;
        const int sw = (o & 7) << 3;
        const float* src = ow2 + o * CDIM + i0;
        short8v pk0, pk1;
        #pragma unroll
        for (int j = 0; j < 8; ++j) pk0[j] = f2bf(src[j]);
        #pragma unroll
        for (int j = 0; j < 8; ++j) pk1[j] = f2bf(src[8 + j]);
        *reinterpret_cast<short8v*>(&sWb[o * 128 + (i0 ^ sw)]) = pk0;
        *reinterpret_cast<short8v*>(&sWb[o * 128 + ((i0 + 8) ^ sw)]) = pk1;
    }
    {
        float vals2[8];
        float u1 = 0.f, u2 = 0.f;
        #pragma unroll
        for (int j = 0; j < 8; ++j) {
            const float v = sT[qu * 8 + j][l] + ob1[qu * 8 + j];
            vals2[j] = v; u1 += v; u2 += v * v;
        }
        red1[q][l] = u1; red2[q][l] = u2;
        __syncthreads();
        float v1 = 0.f, v2 = 0.f;
        #pragma unroll
        for (int j = 0; j < 16; ++j) { v1 += red1[j][l]; v2 += red2[j][l]; }
        const float mn = v1 * (1.0f / 128.0f);
        const float vr = v2 * (1.0f / 128.0f) - mn * mn;
        const float rs = rsqrtf(vr + 1e-6f);
        short8v pk;
        #pragma unroll
        for (int j = 0; j < 8; ++j) {
            const float v = (vals2[j] - mn) * rs * olnw[qu * 8 + j] + olnb[qu * 8 + j];
            pk[j] = f2bf(v);
        }
        *reinterpret_cast<short8v*>(&sXT[l * 128 + ((qu * 8) ^ ((l & 7) << 3))]) = pk;
    }
    __syncthreads();

    // ---- output_proj conv2 MFMA + bias -> out ----
    {
        float4v a0 = {0.f, 0.f, 0.f, 0.f}, a1 = {0.f, 0.f, 0.f, 0.f};
        #pragma unroll
        for (int kk = 0; kk < 4; ++kk) {
            const int ki = kk * 32 + g * 8;
            const short8v af = *reinterpret_cast<const short8v*>(&sWb[arow + (ki ^ asw)]);
            const short8v bf0 = *reinterpret_cast<const short8v*>(&sXT[p0 * 128 + (ki ^ bsw0)]);
            const short8v bf1 = *reinterpret_cast<const short8v*>(&sXT[p1 * 128 + (ki ^ bsw1)]);
            a0 = __builtin_amdgcn_mfma_f32_16x16x32_bf16(af, bf0, a0, 0, 0, 0);
            a1 = __builtin_amdgcn_mfma_f32_16x16x32_bf16(af, bf1, a1, 0, 0, 0);
        }
        const float4 bv = *reinterpret_cast<const float4*>(&ob2[tmo * 16 + g * 4]);
        float* obase = out + (b * CDIM * HH + h) * WW;
        #pragma unroll
        for (int r = 0; r < 4; ++r) {
            const float bias = ((const float*)&bv)[r];
            obase[(tmo * 16 + g * 4 + r) * HH * WW + p0] = a0[r] + bias;
            obase[(tmo * 16 + g * 4 + r) * HH * WW + p1] = a1[r] + bias;
        }
    }
}

extern "C" void kernel_launch(void* const* d_in, const int* in_sizes, int n_in,
                              void* d_out, int out_size, void* d_ws, size_t ws_size,
                              hipStream_t stream) {
    (void)in_sizes; (void)n_in; (void)out_size; (void)ws_size;
    const float* spatial  = (const float*)d_in[0];
    const float* semantic = (const float*)d_in[1];
    const float* rp_w1 = (const float*)d_in[2];
    const float* rp_b1 = (const float*)d_in[3];
    const float* rp_lnw = (const float*)d_in[4];
    const float* rp_lnb = (const float*)d_in[5];
    const float* rp_w2 = (const float*)d_in[6];
    const float* rp_b2 = (const float*)d_in[7];
    const float* fx_w1 = (const float*)d_in[8];
    const float* fx_b1 = (const float*)d_in[9];
    const float* fx_lnw = (const float*)d_in[10];
    const float* fx_lnb = (const float*)d_in[11];
    const float* fx_w2 = (const float*)d_in[12];
    const float* fx_b2 = (const float*)d_in[13];
    const float* sigma = (const float*)d_in[14];
    const float* op_w1 = (const float*)d_in[15];
    const float* op_b1 = (const float*)d_in[16];
    const float* op_lnw = (const float*)d_in[17];
    const float* op_lnb = (const float*)d_in[18];
    const float* op_w2 = (const float*)d_in[19];
    const float* op_b2 = (const float*)d_in[20];

    char* wsb = (char*)d_ws;
    short* pxt  = (short*)wsb;                   // 4 MB bf16 [b][h][p][c]
    float* outp = (float*)d_out;

    dim3 grid(BB * HH), blk(1024);
    proj_kernel<true><<<grid, blk, 0, stream>>>(semantic, rp_w1, rp_b1, rp_lnw, rp_lnb,
                                                rp_w2, rp_b2, pxt);
    simfixagg_kernel<<<grid, blk, 0, stream>>>(pxt, sigma, semantic,
                                               fx_w1, fx_b1, fx_lnw, fx_lnb, fx_w2, fx_b2,
                                               spatial,
                                               op_w1, op_b1, op_lnw, op_lnb, op_w2, op_b2,
                                               outp);
}

// Round 15
// 61.862 us; speedup vs baseline: 1.1238x; 1.0042x over previous
//
#include <hip/hip_runtime.h>
#include <cstdint>

#define BB 4
#define CDIM 128
#define HH 64
#define WW 64
#define RR 3
#define DD 7
#define DSQ 49

typedef __attribute__((ext_vector_type(8))) short short8v;   // 8 bf16 = 4 VGPR
typedef __attribute__((ext_vector_type(4))) float float4v;

__device__ __forceinline__ int reflect64(int p) {
    p = (p < 0) ? -p : p;
    return (p > 63) ? (126 - p) : p;
}
__device__ __forceinline__ float sigm(float x) { return 1.0f / (1.0f + __expf(-x)); }
__device__ __forceinline__ short f2bf(float f) {     // f32 -> bf16 RNE
    uint32_t u = __float_as_uint(f);
    u += 0x7FFF + ((u >> 16) & 1);
    return (short)(u >> 16);
}

// ---- range_proj: conv1x1 -> LN -> SiLU -> conv1x1 via bf16 MFMA.
// Output: bf16 TRANSPOSED [b][h][p][c].
template<bool SILU>
__global__ __launch_bounds__(1024) void proj_kernel(
    const float* __restrict__ x, const float* __restrict__ w1,
    const float* __restrict__ b1, const float* __restrict__ lnw,
    const float* __restrict__ lnb, const float* __restrict__ w2,
    const float* __restrict__ b2, short* __restrict__ outT)
{
    __shared__ short sW1[CDIM * CDIM];
    __shared__ short sW2[CDIM * CDIM];
    __shared__ short sXT[WW * CDIM];
    __shared__ short sXT2[WW * CDIM];
    __shared__ float sT[CDIM][65];
    __shared__ float red1[16][WW];
    __shared__ float red2[16][WW];

    const int tid = threadIdx.x;
    const int l = tid & 63;
    const int q = tid >> 6;
    const int qu = __builtin_amdgcn_readfirstlane(q);
    const int b = blockIdx.x >> 6;
    const int h = blockIdx.x & 63;

    {
        const int o = tid >> 3;
        const int i0 = (tid & 7) * 16;
        const int sw = (o & 7) << 3;
        const float* wsrc[2] = {w1, w2};
        short* wdst[2] = {sW1, sW2};
        #pragma unroll
        for (int m = 0; m < 2; ++m) {
            const float* src = wsrc[m] + o * CDIM + i0;
            short8v pk0, pk1;
            #pragma unroll
            for (int j = 0; j < 8; ++j) pk0[j] = f2bf(src[j]);
            #pragma unroll
            for (int j = 0; j < 8; ++j) pk1[j] = f2bf(src[8 + j]);
            *reinterpret_cast<short8v*>(&wdst[m][o * 128 + (i0 ^ sw)]) = pk0;
            *reinterpret_cast<short8v*>(&wdst[m][o * 128 + ((i0 + 8) ^ sw)]) = pk1;
        }
    }
    {
        const int pos = tid & 15;
        const int c0 = tid >> 4;
        const float* xrow = x + (b * CDIM * HH + h) * WW;
        #pragma unroll
        for (int rr = 0; rr < 2; ++rr) {
            const int c = c0 + rr * 64;
            const float4 v = *reinterpret_cast<const float4*>(&xrow[c * HH * WW + pos * 4]);
            #pragma unroll
            for (int m = 0; m < 4; ++m) {
                const int p = pos * 4 + m;
                sXT[p * 128 + (c ^ ((p & 7) << 3))] = f2bf(((const float*)&v)[m]);
            }
        }
    }
    __syncthreads();

    const int lm = l & 15, g = l >> 4;
    const int tm = q >> 1;
    const int tn0 = (q & 1) * 2;
    const int oa = tm * 16 + lm;
    const int arow = oa * 128, asw = (oa & 7) << 3;
    const int p0 = tn0 * 16 + lm, p1 = (tn0 + 1) * 16 + lm;
    const int bsw0 = (p0 & 7) << 3, bsw1 = (p1 & 7) << 3;

    float4v acc0 = {0.f, 0.f, 0.f, 0.f}, acc1 = {0.f, 0.f, 0.f, 0.f};
    #pragma unroll
    for (int kk = 0; kk < 4; ++kk) {
        const int ki = kk * 32 + g * 8;
        const short8v af = *reinterpret_cast<const short8v*>(&sW1[arow + (ki ^ asw)]);
        const short8v bf0 = *reinterpret_cast<const short8v*>(&sXT[p0 * 128 + (ki ^ bsw0)]);
        const short8v bf1 = *reinterpret_cast<const short8v*>(&sXT[p1 * 128 + (ki ^ bsw1)]);
        acc0 = __builtin_amdgcn_mfma_f32_16x16x32_bf16(af, bf0, acc0, 0, 0, 0);
        acc1 = __builtin_amdgcn_mfma_f32_16x16x32_bf16(af, bf1, acc1, 0, 0, 0);
    }
    #pragma unroll
    for (int r = 0; r < 4; ++r) sT[tm * 16 + g * 4 + r][p0] = acc0[r];
    #pragma unroll
    for (int r = 0; r < 4; ++r) sT[tm * 16 + g * 4 + r][p1] = acc1[r];
    __syncthreads();

    {
        const int p = l;
        float vals[8];
        float s1 = 0.f, s2 = 0.f;
        #pragma unroll
        for (int j = 0; j < 8; ++j) {
            const float v = sT[qu * 8 + j][p] + b1[qu * 8 + j];
            vals[j] = v; s1 += v; s2 += v * v;
        }
        red1[q][p] = s1; red2[q][p] = s2;
        __syncthreads();
        float t1 = 0.f, t2 = 0.f;
        #pragma unroll
        for (int j = 0; j < 16; ++j) { t1 += red1[j][p]; t2 += red2[j][p]; }
        const float mean = t1 * (1.0f / 128.0f);
        const float var  = t2 * (1.0f / 128.0f) - mean * mean;
        const float rstd = rsqrtf(var + 1e-6f);
        short8v pk;
        #pragma unroll
        for (int j = 0; j < 8; ++j) {
            float v = (vals[j] - mean) * rstd * lnw[qu * 8 + j] + lnb[qu * 8 + j];
            if (SILU) v = v * sigm(v);
            pk[j] = f2bf(v);
        }
        *reinterpret_cast<short8v*>(&sXT2[p * 128 + ((qu * 8) ^ ((p & 7) << 3))]) = pk;
    }
    __syncthreads();

    {
        float4v a0 = {0.f, 0.f, 0.f, 0.f}, a1 = {0.f, 0.f, 0.f, 0.f};
        #pragma unroll
        for (int kk = 0; kk < 4; ++kk) {
            const int ki = kk * 32 + g * 8;
            const short8v af = *reinterpret_cast<const short8v*>(&sW2[arow + (ki ^ asw)]);
            const short8v bf0 = *reinterpret_cast<const short8v*>(&sXT2[p0 * 128 + (ki ^ bsw0)]);
            const short8v bf1 = *reinterpret_cast<const short8v*>(&sXT2[p1 * 128 + (ki ^ bsw1)]);
            a0 = __builtin_amdgcn_mfma_f32_16x16x32_bf16(af, bf0, a0, 0, 0, 0);
            a1 = __builtin_amdgcn_mfma_f32_16x16x32_bf16(af, bf1, a1, 0, 0, 0);
        }
        const float4 bv = *reinterpret_cast<const float4*>(&b2[tm * 16 + g * 4]);
        #pragma unroll
        for (int r = 0; r < 4; ++r) {
            const float bias = ((const float*)&bv)[r];
            sT[tm * 16 + g * 4 + r][p0] = a0[r] + bias;
            sT[tm * 16 + g * 4 + r][p1] = a1[r] + bias;
        }
    }
    __syncthreads();
    {
        const int p = tid >> 4;
        const int c0 = (tid & 15) * 8;
        short8v pk;
        #pragma unroll
        for (int j = 0; j < 8; ++j) pk[j] = f2bf(sT[c0 + j][p]);
        *reinterpret_cast<short8v*>(&outT[((b * HH + h) * WW + p) * CDIM + c0]) = pk;
    }
}

// ---- fully fused: Gram-MFMA sim -> softmax*spatial -> MFMA fixup (wts in LDS)
//      -> aggregate (XCD-swizzled, reg-prefetched) -> output_proj MFMA -> d_out
__global__ __launch_bounds__(1024) void simfixagg_kernel(
    const short* __restrict__ pxt, const float* __restrict__ sigma_p,
    const float* __restrict__ sem,
    const float* __restrict__ fw1, const float* __restrict__ fb1,
    const float* __restrict__ flnw, const float* __restrict__ flnb,
    const float* __restrict__ fw2, const float* __restrict__ fb2,
    const float* __restrict__ spatial,
    const float* __restrict__ ow1, const float* __restrict__ ob1,
    const float* __restrict__ olnw, const float* __restrict__ olnb,
    const float* __restrict__ ow2, const float* __restrict__ ob2,
    float* __restrict__ out)
{
    __shared__ alignas(16) char sBig[7 * WW * CDIM * 2];   // 114,688 B
    __shared__ alignas(16) char sAux[64 * 66 * 4];         //  16,896 B
    __shared__ alignas(16) float sSimWts[DSQ][64];         //  12,544 B: sSim then sWts
    __shared__ alignas(16) float sCmb[DSQ][66];            //  12,936 B

    // Gram phase
    short* rows = reinterpret_cast<short*>(sBig);
    // fixup overlay
    short* B1   = reinterpret_cast<short*>(sBig);          // [64 px][192]
    short* A1   = reinterpret_cast<short*>(sBig + 24576);  // [64 o ][192]
    short* B2   = reinterpret_cast<short*>(sBig + 49152);  // [64 px][64]
    short* A2   = reinterpret_cast<short*>(sBig + 57344);  // [64 o ][64]
    float* fSem = reinterpret_cast<float*>(sBig + 65536);  // [128][64]
    float* prm  = reinterpret_cast<float*>(sBig + 98304);  // 4 x 64
    // agg/op-proj overlay
    float (*sS)[DD * WW] = reinterpret_cast<float(*)[DD * WW]>(sBig);   // 57,344
    float (*sT)[65]      = reinterpret_cast<float(*)[65]>(sBig);        // 33,280
    short* sWb = reinterpret_cast<short*>(sBig + 57344);                // 32,768
    short* sXT = reinterpret_cast<short*>(sBig + 90112);                // 16,384

    float (*sP64)[66] = reinterpret_cast<float(*)[66]>(sAux);
    float (*red1)[65] = reinterpret_cast<float(*)[65]>(sAux);
    float (*red2)[65] = reinterpret_cast<float(*)[65]>(sAux + 16 * 65 * 4);

    const int tid = threadIdx.x;
    const int l = tid & 63;
    const int q = tid >> 6;
    const int qu = __builtin_amdgcn_readfirstlane(q);
    // XCD-bijective swizzle (256 blocks, 8 XCDs): XCD k owns 32 consecutive rows.
    const int lbid = ((blockIdx.x & 7) << 5) | (blockIdx.x >> 3);
    const int b = lbid >> 6;
    const int h = lbid & 63;

    // ---- stage 7 reflected rows, bf16 [row][p][c] swz ----
    for (int idx = tid; idx < 7 * WW * 16; idx += 1024) {
        const int cchunk = idx & 15;
        const int p = (idx >> 4) & 63;
        const int row = idx >> 10;
        const int hp = reflect64(h + row - RR);
        const short8v v = *reinterpret_cast<const short8v*>(
            &pxt[((b * HH + hp) * WW + p) * CDIM + cchunk * 8]);
        *reinterpret_cast<short8v*>(
            &rows[(row * WW + p) * CDIM + ((cchunk * 8) ^ ((p & 7) << 3))]) = v;
    }
    __syncthreads();

    // ---- Gram MFMA per ki (sP64 gather variant, r12-validated) ----
    const int lm = l & 15, g = l >> 4;
    const int tm = q >> 2, tn = q & 3;
    const int pa = tm * 16 + lm;
    const int pxb = tn * 16 + lm;
    const int abase = (3 * WW + pa) * CDIM, as_ = (pa & 7) << 3;
    const int bs_ = (pxb & 7) << 3;

    short8v afr[4];
    #pragma unroll
    for (int kk = 0; kk < 4; ++kk)
        afr[kk] = *reinterpret_cast<const short8v*>(
            &rows[abase + ((kk * 32 + g * 8) ^ as_)]);

    const float rscale = 0.088388347648318447f;  // 1/sqrt(128)
    for (int ki = 0; ki < 7; ++ki) {
        float4v acc = {0.f, 0.f, 0.f, 0.f};
        const int bbase = (ki * WW + pxb) * CDIM;
        #pragma unroll
        for (int kk = 0; kk < 4; ++kk) {
            const short8v bf = *reinterpret_cast<const short8v*>(
                &rows[bbase + ((kk * 32 + g * 8) ^ bs_)]);
            acc = __builtin_amdgcn_mfma_f32_16x16x32_bf16(afr[kk], bf, acc, 0, 0, 0);
        }
        #pragma unroll
        for (int r = 0; r < 4; ++r)
            sP64[tm * 16 + g * 4 + r][tn * 16 + lm] = acc[r];
        __syncthreads();
        if (tid < 448) {
            const int kj = tid >> 6, p = tid & 63;
            sSimWts[ki * 7 + kj][p] = sP64[p][reflect64(p + kj - RR)] * rscale;
        }
        __syncthreads();
    }
    // rows/sP64 dead -> stage fixup overlays

    // A1: fw1 -> bf16 [64][192]: [0:49]=cmb-cols, [49:64]=0, [64:192]=sem-cols
    for (int idx = tid; idx < 64 * 24; idx += 1024) {
        const int o = idx / 24;
        const int ch0 = (idx % 24) * 8;
        short8v pk;
        #pragma unroll
        for (int j = 0; j < 8; ++j) {
            const int c = ch0 + j;
            float v = 0.f;
            if (o < DSQ) {
                if (c < DSQ) v = fw1[o * 177 + c];
                else if (c >= 64) v = fw1[o * 177 + DSQ + (c - 64)];
            }
            pk[j] = f2bf(v);
        }
        *reinterpret_cast<short8v*>(&A1[o * 192 + (ch0 ^ ((o & 7) << 3))]) = pk;
    }
    // A2: fw2 -> bf16 [64][64], zero-padded
    for (int idx = tid; idx < 64 * 8; idx += 1024) {
        const int o = idx >> 3;
        const int ch0 = (idx & 7) * 8;
        short8v pk;
        #pragma unroll
        for (int j = 0; j < 8; ++j) {
            const int c = ch0 + j;
            pk[j] = (o < DSQ && c < DSQ) ? f2bf(fw2[o * DSQ + c]) : (short)0;
        }
        *reinterpret_cast<short8v*>(&A2[o * 64 + (ch0 ^ ((o & 7) << 3))]) = pk;
    }
    // B2 zero-fill
    {
        const short8v z = {0, 0, 0, 0, 0, 0, 0, 0};
        for (int idx = tid; idx < 64 * 8; idx += 1024)
            *reinterpret_cast<short8v*>(&B2[idx * 8]) = z;
    }
    // B1 pad cols [49..64) zero
    for (int idx = tid; idx < 64 * 15; idx += 1024) {
        const int p = idx / 15, c = DSQ + idx % 15;
        B1[p * 192 + (c ^ ((p & 7) << 3))] = 0;
    }
    // params
    for (int idx = tid; idx < 256; idx += 1024) {
        const int a = idx >> 6, i = idx & 63;
        float v = 0.f;
        if (i < DSQ) {
            if (a == 0) v = fb1[i];
            else if (a == 1) v = flnw[i];
            else if (a == 2) v = flnb[i];
            else v = fb2[i];
        }
        prm[a * 64 + i] = v;
    }
    // fSem f32 [c][p]
    {
        const float* srow = sem + (b * CDIM * HH + h) * WW;
        for (int idx = tid; idx < CDIM * 16; idx += 1024) {
            const int r = idx >> 4, pos = idx & 15;
            *reinterpret_cast<float4*>(&fSem[r * WW + pos * 4]) =
                *reinterpret_cast<const float4*>(&srow[r * HH * WW + pos * 4]);
        }
    }
    // softmax * spatial kernel -> sCmb f32 + B1 cmb-cols bf16
    {
        float rv[DSQ];
        #pragma unroll
        for (int n = 0; n < DSQ; ++n) rv[n] = sSimWts[n][l];
        float m = -1e30f;
        #pragma unroll
        for (int n = 0; n < DSQ; ++n) m = fmaxf(m, rv[n]);
        float ssum = 0.f;
        #pragma unroll
        for (int n = 0; n < DSQ; ++n) ssum += __expf(rv[n] - m);
        const float inv = 1.0f / ssum;
        const float sigma = sigma_p[0];
        const float inv2s2 = 1.0f / (2.0f * sigma * sigma);
        const int swl = (l & 7) << 3;
        #pragma unroll
        for (int k = 0; k < 4; ++k) {
            const int n = q + 16 * k;
            if (n < DSQ) {
                const int ki = n / 7, kj = n % 7;
                const float dx = (float)(ki - 3) * (1.0f / 3.0f);
                const float dy = (float)(kj - 3) * (1.0f / 3.0f);
                const float sk = __expf(-(dx * dx + dy * dy) * inv2s2);
                const float cv = __expf(rv[n] - m) * inv * sk;
                sCmb[n][l] = cv;
                B1[l * 192 + (n ^ swl)] = f2bf(cv);
            }
        }
    }
    __syncthreads();
    // B1 sem-cols: transpose-pack from fSem
    {
        const int c0 = q * 8;
        short8v pk;
        #pragma unroll
        for (int j = 0; j < 8; ++j) pk[j] = f2bf(fSem[(c0 + j) * WW + l]);
        *reinterpret_cast<short8v*>(&B1[l * 192 + ((64 + c0) ^ ((l & 7) << 3))]) = pk;
    }
    __syncthreads();

    // ---- fixup conv1 MFMA ----
    const int oA = tm * 16 + lm;
    const int aswz = (oA & 7) << 3;
    const int p = tn * 16 + lm;
    const int bswz = (p & 7) << 3;

    float4v facc = {0.f, 0.f, 0.f, 0.f};
    #pragma unroll
    for (int kk = 0; kk < 6; ++kk) {
        const int ki = kk * 32 + g * 8;
        const short8v af = *reinterpret_cast<const short8v*>(&A1[oA * 192 + (ki ^ aswz)]);
        const short8v bf = *reinterpret_cast<const short8v*>(&B1[p * 192 + (ki ^ bswz)]);
        facc = __builtin_amdgcn_mfma_f32_16x16x32_bf16(af, bf, facc, 0, 0, 0);
    }
    float vals[4];
    float s1 = 0.f, s2 = 0.f;
    #pragma unroll
    for (int r = 0; r < 4; ++r) {
        const int o = tm * 16 + g * 4 + r;
        const float v = facc[r] + prm[o];
        vals[r] = v;
        if (o < DSQ) { s1 += v; s2 += v * v; }
    }
    red1[tm * 4 + g][p] = s1;
    red2[tm * 4 + g][p] = s2;
    __syncthreads();
    float t1 = 0.f, t2 = 0.f;
    #pragma unroll
    for (int j = 0; j < 16; ++j) { t1 += red1[j][p]; t2 += red2[j][p]; }
    const float mean = t1 * (1.0f / 49.0f);
    const float var  = t2 * (1.0f / 49.0f) - mean * mean;
    const float rstd = rsqrtf(var + 1e-6f);
    #pragma unroll
    for (int r = 0; r < 4; ++r) {
        const int o = tm * 16 + g * 4 + r;
        if (o < DSQ) {
            const float v = (vals[r] - mean) * rstd * prm[64 + o] + prm[128 + o];
            const float sv = v * sigm(v);
            B2[p * 64 + (o ^ bswz)] = f2bf(sv);
        }
    }
    __syncthreads();

    // ---- fixup conv2 MFMA + gate + normalize -> sWts (LDS) ----
    float4v facc2 = {0.f, 0.f, 0.f, 0.f};
    #pragma unroll
    for (int kk = 0; kk < 2; ++kk) {
        const int ki = kk * 32 + g * 8;
        const short8v af = *reinterpret_cast<const short8v*>(&A2[oA * 64 + (ki ^ aswz)]);
        const short8v bf = *reinterpret_cast<const short8v*>(&B2[p * 64 + (ki ^ bswz)]);
        facc2 = __builtin_amdgcn_mfma_f32_16x16x32_bf16(af, bf, facc2, 0, 0, 0);
    }
    float c2v[4];
    float ps = 0.f;
    #pragma unroll
    for (int r = 0; r < 4; ++r) {
        const int o = tm * 16 + g * 4 + r;
        if (o < DSQ) {
            const float f = facc2[r] + prm[192 + o];
            c2v[r] = sCmb[o][p] * (1.0f + sigm(f));
            ps += c2v[r];
        } else c2v[r] = 0.f;
    }
    red1[tm * 4 + g][p] = ps;
    __syncthreads();
    float tot = 0.f;
    #pragma unroll
    for (int j = 0; j < 16; ++j) tot += red1[j][p];
    const float invt = 1.0f / (tot + 1e-7f);
    #pragma unroll
    for (int r = 0; r < 4; ++r) {
        const int o = tm * 16 + g * 4 + r;
        if (o < DSQ) sSimWts[o][p] = c2v[r] * invt;   // sSim region reused as sWts
    }
    __syncthreads();

    // ---- aggregate phase (wts from LDS, T14 reg-prefetched staging) ----
    // stage op_w1 bf16 swizzled into sWb
    {
        const int o = tid >> 3;
        const int i0 = (tid & 7) * 16;
        const int sw = (o & 7) << 3;
        const float* src = ow1 + o * CDIM + i0;
        short8v pk0, pk1;
        #pragma unroll
        for (int j = 0; j < 8; ++j) pk0[j] = f2bf(src[j]);
        #pragma unroll
        for (int j = 0; j < 8; ++j) pk1[j] = f2bf(src[8 + j]);
        *reinterpret_cast<short8v*>(&sWb[o * 128 + (i0 ^ sw)]) = pk0;
        *reinterpret_cast<short8v*>(&sWb[o * 128 + ((i0 + 8) ^ sw)]) = pk1;
    }
    float wv[DSQ];
    #pragma unroll
    for (int n = 0; n < DSQ; ++n) wv[n] = sSimWts[n][l];
    int coff[DD];
    #pragma unroll
    for (int kj = 0; kj < DD; ++kj) coff[kj] = reflect64(l + kj - RR);

    const float* sb = spatial + b * CDIM * HH * WW;
    float4 pre[4];
    // issue loads for chunk cc (3584 float4s; threads 512..1023 do 3, clamp dup on 4th)
    #define LD_CHUNK(cc)                                                          \
        _Pragma("unroll")                                                         \
        for (int it = 0; it < 4; ++it) {                                          \
            int idx = tid + it * 1024;                                            \
            if (idx > 3583) idx = 3583;                                           \
            const int pos = idx & 15;                                             \
            const int rk  = idx >> 4;                                             \
            const int cl  = rk / 7;                                               \
            const int ki  = rk - cl * 7;                                          \
            const int hp  = reflect64(h + ki - RR);                               \
            pre[it] = *reinterpret_cast<const float4*>(                           \
                &sb[((cc) * 32 + cl) * HH * WW + hp * WW + pos * 4]);             \
        }
    #define ST_CHUNK()                                                            \
        _Pragma("unroll")                                                         \
        for (int it = 0; it < 4; ++it) {                                          \
            const int idx = tid + it * 1024;                                      \
            if (idx < 3584) {                                                     \
                const int pos = idx & 15;                                         \
                const int rk  = idx >> 4;                                         \
                const int cl  = rk / 7;                                           \
                const int ki  = rk - cl * 7;                                      \
                *reinterpret_cast<float4*>(&sS[cl][ki * WW + pos * 4]) = pre[it]; \
            }                                                                     \
        }

    LD_CHUNK(0);
    ST_CHUNK();
    __syncthreads();
    for (int cc = 0; cc < 4; ++cc) {
        if (cc < 3) { LD_CHUNK(cc + 1); }       // overlap HBM latency with compute
        float a0 = 0.f, a1 = 0.f;
        const int c0 = q * 2;
        #pragma unroll
        for (int n = 0; n < DSQ; ++n) {
            const int ki = n / 7, kj = n % 7;   // compile-time
            const int off = ki * WW + coff[kj];
            a0 = fmaf(sS[c0][off],     wv[n], a0);
            a1 = fmaf(sS[c0 + 1][off], wv[n], a1);
        }
        const int cg = cc * 32 + c0;
        const int psw = (l & 7) << 3;
        sXT[l * 128 + (cg ^ psw)]       = f2bf(a0);
        sXT[l * 128 + ((cg + 1) ^ psw)] = f2bf(a1);
        __syncthreads();                        // all sS reads done
        if (cc < 3) { ST_CHUNK(); __syncthreads(); }
    }
    #undef LD_CHUNK
    #undef ST_CHUNK

    // ---- output_proj conv1 MFMA ----
    const int tmo = q >> 1;
    const int tn0 = (q & 1) * 2;
    const int oaop = tmo * 16 + lm;
    const int arow = oaop * 128, asw = (oaop & 7) << 3;
    const int p0 = tn0 * 16 + lm, p1 = (tn0 + 1) * 16 + lm;
    const int bsw0 = (p0 & 7) << 3, bsw1 = (p1 & 7) << 3;

    {
        float4v a0 = {0.f, 0.f, 0.f, 0.f}, a1 = {0.f, 0.f, 0.f, 0.f};
        #pragma unroll
        for (int kk = 0; kk < 4; ++kk) {
            const int ki = kk * 32 + g * 8;
            const short8v af = *reinterpret_cast<const short8v*>(&sWb[arow + (ki ^ asw)]);
            const short8v bf0 = *reinterpret_cast<const short8v*>(&sXT[p0 * 128 + (ki ^ bsw0)]);
            const short8v bf1 = *reinterpret_cast<const short8v*>(&sXT[p1 * 128 + (ki ^ bsw1)]);
            a0 = __builtin_amdgcn_mfma_f32_16x16x32_bf16(af, bf0, a0, 0, 0, 0);
            a1 = __builtin_amdgcn_mfma_f32_16x16x32_bf16(af, bf1, a1, 0, 0, 0);
        }
        __syncthreads();      // sS/sT region free; sXT reads done (will rewrite below)
        #pragma unroll
        for (int r = 0; r < 4; ++r) sT[tmo * 16 + g * 4 + r][p0] = a0[r];
        #pragma unroll
        for (int r = 0; r < 4; ++r) sT[tmo * 16 + g * 4 + r][p1] = a1[r];
    }
    __syncthreads();

    // restage sWb = op_w2; bias + LN(128) -> sXT (reused as conv2 B operand)
    {
        const int o = tid >> 3;
        const int i0 = (tid & 7) * 16;
        const int sw = (o & 7) << 3;
        const float* src = ow2 + o * CDIM + i0;
        short8v pk0, pk1;
        #pragma unroll
        for (int j = 0; j < 8; ++j) pk0[j] = f2bf(src[j]);
        #pragma unroll
        for (int j = 0; j < 8; ++j) pk1[j] = f2bf(src[8 + j]);
        *reinterpret_cast<short8v*>(&sWb[o * 128 + (i0 ^ sw)]) = pk0;
        *reinterpret_cast<short8v*>(&sWb[o * 128 + ((i0 + 8) ^ sw)]) = pk1;
    }
    {
        float vals2[8];
        float u1 = 0.f, u2 = 0.f;
        #pragma unroll
        for (int j = 0; j < 8; ++j) {
            const float v = sT[qu * 8 + j][l] + ob1[qu * 8 + j];
            vals2[j] = v; u1 += v; u2 += v * v;
        }
        red1[q][l] = u1; red2[q][l] = u2;
        __syncthreads();
        float v1 = 0.f, v2 = 0.f;
        #pragma unroll
        for (int j = 0; j < 16; ++j) { v1 += red1[j][l]; v2 += red2[j][l]; }
        const float mn = v1 * (1.0f / 128.0f);
        const float vr = v2 * (1.0f / 128.0f) - mn * mn;
        const float rs = rsqrtf(vr + 1e-6f);
        short8v pk;
        #pragma unroll
        for (int j = 0; j < 8; ++j) {
            const float v = (vals2[j] - mn) * rs * olnw[qu * 8 + j] + olnb[qu * 8 + j];
            pk[j] = f2bf(v);
        }
        *reinterpret_cast<short8v*>(&sXT[l * 128 + ((qu * 8) ^ ((l & 7) << 3))]) = pk;
    }
    __syncthreads();

    // ---- output_proj conv2 MFMA + bias -> out ----
    {
        float4v a0 = {0.f, 0.f, 0.f, 0.f}, a1 = {0.f, 0.f, 0.f, 0.f};
        #pragma unroll
        for (int kk = 0; kk < 4; ++kk) {
            const int ki = kk * 32 + g * 8;
            const short8v af = *reinterpret_cast<const short8v*>(&sWb[arow + (ki ^ asw)]);
            const short8v bf0 = *reinterpret_cast<const short8v*>(&sXT[p0 * 128 + (ki ^ bsw0)]);
            const short8v bf1 = *reinterpret_cast<const short8v*>(&sXT[p1 * 128 + (ki ^ bsw1)]);
            a0 = __builtin_amdgcn_mfma_f32_16x16x32_bf16(af, bf0, a0, 0, 0, 0);
            a1 = __builtin_amdgcn_mfma_f32_16x16x32_bf16(af, bf1, a1, 0, 0, 0);
        }
        const float4 bv = *reinterpret_cast<const float4*>(&ob2[tmo * 16 + g * 4]);
        float* obase = out + (b * CDIM * HH + h) * WW;
        #pragma unroll
        for (int r = 0; r < 4; ++r) {
            const float bias = ((const float*)&bv)[r];
            obase[(tmo * 16 + g * 4 + r) * HH * WW + p0] = a0[r] + bias;
            obase[(tmo * 16 + g * 4 + r) * HH * WW + p1] = a1[r] + bias;
        }
    }
}

extern "C" void kernel_launch(void* const* d_in, const int* in_sizes, int n_in,
                              void* d_out, int out_size, void* d_ws, size_t ws_size,
                              hipStream_t stream) {
    (void)in_sizes; (void)n_in; (void)out_size; (void)ws_size;
    const float* spatial  = (const float*)d_in[0];
    const float* semantic = (const float*)d_in[1];
    const float* rp_w1 = (const float*)d_in[2];
    const float* rp_b1 = (const float*)d_in[3];
    const float* rp_lnw = (const float*)d_in[4];
    const float* rp_lnb = (const float*)d_in[5];
    const float* rp_w2 = (const float*)d_in[6];
    const float* rp_b2 = (const float*)d_in[7];
    const float* fx_w1 = (const float*)d_in[8];
    const float* fx_b1 = (const float*)d_in[9];
    const float* fx_lnw = (const float*)d_in[10];
    const float* fx_lnb = (const float*)d_in[11];
    const float* fx_w2 = (const float*)d_in[12];
    const float* fx_b2 = (const float*)d_in[13];
    const float* sigma = (const float*)d_in[14];
    const float* op_w1 = (const float*)d_in[15];
    const float* op_b1 = (const float*)d_in[16];
    const float* op_lnw = (const float*)d_in[17];
    const float* op_lnb = (const float*)d_in[18];
    const float* op_w2 = (const float*)d_in[19];
    const float* op_b2 = (const float*)d_in[20];

    char* wsb = (char*)d_ws;
    short* pxt  = (short*)wsb;                   // 4 MB bf16 [b][h][p][c]
    float* outp = (float*)d_out;

    dim3 grid(BB * HH), blk(1024);
    proj_kernel<true><<<grid, blk, 0, stream>>>(semantic, rp_w1, rp_b1, rp_lnw, rp_lnb,
                                                rp_w2, rp_b2, pxt);
    simfixagg_kernel<<<grid, blk, 0, stream>>>(pxt, sigma, semantic,
                                               fx_w1, fx_b1, fx_lnw, fx_lnb, fx_w2, fx_b2,
                                               spatial,
                                               op_w1, op_b1, op_lnw, op_lnb, op_w2, op_b2,
                                               outp);
}

// Round 16
// 54.426 us; speedup vs baseline: 1.2774x; 1.1366x over previous
//
#include <hip/hip_runtime.h>
#include <cstdint>

#define BB 4
#define CDIM 128
#define HH 64
#define WW 64
#define RR 3
#define DD 7
#define DSQ 49

typedef __attribute__((ext_vector_type(8))) short short8v;   // 8 bf16 = 4 VGPR
typedef __attribute__((ext_vector_type(4))) float float4v;

__device__ __forceinline__ int reflect64(int p) {
    p = (p < 0) ? -p : p;
    return (p > 63) ? (126 - p) : p;
}
__device__ __forceinline__ float sigm(float x) { return 1.0f / (1.0f + __expf(-x)); }
__device__ __forceinline__ short f2bf(float f) {     // f32 -> bf16 RNE
    uint32_t u = __float_as_uint(f);
    u += 0x7FFF + ((u >> 16) & 1);
    return (short)(u >> 16);
}

// ---- range_proj: conv1x1 -> LN -> SiLU -> conv1x1 via bf16 MFMA.
// Output: bf16 TRANSPOSED [b][h][p][c].
template<bool SILU>
__global__ __launch_bounds__(1024) void proj_kernel(
    const float* __restrict__ x, const float* __restrict__ w1,
    const float* __restrict__ b1, const float* __restrict__ lnw,
    const float* __restrict__ lnb, const float* __restrict__ w2,
    const float* __restrict__ b2, short* __restrict__ outT)
{
    __shared__ short sW1[CDIM * CDIM];
    __shared__ short sW2[CDIM * CDIM];
    __shared__ short sXT[WW * CDIM];
    __shared__ short sXT2[WW * CDIM];
    __shared__ float sT[CDIM][65];
    __shared__ float red1[16][WW];
    __shared__ float red2[16][WW];

    const int tid = threadIdx.x;
    const int l = tid & 63;
    const int q = tid >> 6;
    const int qu = __builtin_amdgcn_readfirstlane(q);
    const int b = blockIdx.x >> 6;
    const int h = blockIdx.x & 63;

    {
        const int o = tid >> 3;
        const int i0 = (tid & 7) * 16;
        const int sw = (o & 7) << 3;
        const float* wsrc[2] = {w1, w2};
        short* wdst[2] = {sW1, sW2};
        #pragma unroll
        for (int m = 0; m < 2; ++m) {
            const float* src = wsrc[m] + o * CDIM + i0;
            short8v pk0, pk1;
            #pragma unroll
            for (int j = 0; j < 8; ++j) pk0[j] = f2bf(src[j]);
            #pragma unroll
            for (int j = 0; j < 8; ++j) pk1[j] = f2bf(src[8 + j]);
            *reinterpret_cast<short8v*>(&wdst[m][o * 128 + (i0 ^ sw)]) = pk0;
            *reinterpret_cast<short8v*>(&wdst[m][o * 128 + ((i0 + 8) ^ sw)]) = pk1;
        }
    }
    {
        const int pos = tid & 15;
        const int c0 = tid >> 4;
        const float* xrow = x + (b * CDIM * HH + h) * WW;
        #pragma unroll
        for (int rr = 0; rr < 2; ++rr) {
            const int c = c0 + rr * 64;
            const float4 v = *reinterpret_cast<const float4*>(&xrow[c * HH * WW + pos * 4]);
            #pragma unroll
            for (int m = 0; m < 4; ++m) {
                const int p = pos * 4 + m;
                sXT[p * 128 + (c ^ ((p & 7) << 3))] = f2bf(((const float*)&v)[m]);
            }
        }
    }
    __syncthreads();

    const int lm = l & 15, g = l >> 4;
    const int tm = q >> 1;
    const int tn0 = (q & 1) * 2;
    const int oa = tm * 16 + lm;
    const int arow = oa * 128, asw = (oa & 7) << 3;
    const int p0 = tn0 * 16 + lm, p1 = (tn0 + 1) * 16 + lm;
    const int bsw0 = (p0 & 7) << 3, bsw1 = (p1 & 7) << 3;

    float4v acc0 = {0.f, 0.f, 0.f, 0.f}, acc1 = {0.f, 0.f, 0.f, 0.f};
    #pragma unroll
    for (int kk = 0; kk < 4; ++kk) {
        const int ki = kk * 32 + g * 8;
        const short8v af = *reinterpret_cast<const short8v*>(&sW1[arow + (ki ^ asw)]);
        const short8v bf0 = *reinterpret_cast<const short8v*>(&sXT[p0 * 128 + (ki ^ bsw0)]);
        const short8v bf1 = *reinterpret_cast<const short8v*>(&sXT[p1 * 128 + (ki ^ bsw1)]);
        acc0 = __builtin_amdgcn_mfma_f32_16x16x32_bf16(af, bf0, acc0, 0, 0, 0);
        acc1 = __builtin_amdgcn_mfma_f32_16x16x32_bf16(af, bf1, acc1, 0, 0, 0);
    }
    #pragma unroll
    for (int r = 0; r < 4; ++r) sT[tm * 16 + g * 4 + r][p0] = acc0[r];
    #pragma unroll
    for (int r = 0; r < 4; ++r) sT[tm * 16 + g * 4 + r][p1] = acc1[r];
    __syncthreads();

    {
        const int p = l;
        float vals[8];
        float s1 = 0.f, s2 = 0.f;
        #pragma unroll
        for (int j = 0; j < 8; ++j) {
            const float v = sT[qu * 8 + j][p] + b1[qu * 8 + j];
            vals[j] = v; s1 += v; s2 += v * v;
        }
        red1[q][p] = s1; red2[q][p] = s2;
        __syncthreads();
        float t1 = 0.f, t2 = 0.f;
        #pragma unroll
        for (int j = 0; j < 16; ++j) { t1 += red1[j][p]; t2 += red2[j][p]; }
        const float mean = t1 * (1.0f / 128.0f);
        const float var  = t2 * (1.0f / 128.0f) - mean * mean;
        const float rstd = rsqrtf(var + 1e-6f);
        short8v pk;
        #pragma unroll
        for (int j = 0; j < 8; ++j) {
            float v = (vals[j] - mean) * rstd * lnw[qu * 8 + j] + lnb[qu * 8 + j];
            if (SILU) v = v * sigm(v);
            pk[j] = f2bf(v);
        }
        *reinterpret_cast<short8v*>(&sXT2[p * 128 + ((qu * 8) ^ ((p & 7) << 3))]) = pk;
    }
    __syncthreads();

    {
        float4v a0 = {0.f, 0.f, 0.f, 0.f}, a1 = {0.f, 0.f, 0.f, 0.f};
        #pragma unroll
        for (int kk = 0; kk < 4; ++kk) {
            const int ki = kk * 32 + g * 8;
            const short8v af = *reinterpret_cast<const short8v*>(&sW2[arow + (ki ^ asw)]);
            const short8v bf0 = *reinterpret_cast<const short8v*>(&sXT2[p0 * 128 + (ki ^ bsw0)]);
            const short8v bf1 = *reinterpret_cast<const short8v*>(&sXT2[p1 * 128 + (ki ^ bsw1)]);
            a0 = __builtin_amdgcn_mfma_f32_16x16x32_bf16(af, bf0, a0, 0, 0, 0);
            a1 = __builtin_amdgcn_mfma_f32_16x16x32_bf16(af, bf1, a1, 0, 0, 0);
        }
        const float4 bv = *reinterpret_cast<const float4*>(&b2[tm * 16 + g * 4]);
        #pragma unroll
        for (int r = 0; r < 4; ++r) {
            const float bias = ((const float*)&bv)[r];
            sT[tm * 16 + g * 4 + r][p0] = a0[r] + bias;
            sT[tm * 16 + g * 4 + r][p1] = a1[r] + bias;
        }
    }
    __syncthreads();
    {
        const int p = tid >> 4;
        const int c0 = (tid & 15) * 8;
        short8v pk;
        #pragma unroll
        for (int j = 0; j < 8; ++j) pk[j] = f2bf(sT[c0 + j][p]);
        *reinterpret_cast<short8v*>(&outT[((b * HH + h) * WW + p) * CDIM + c0]) = pk;
    }
}

// ---- fully fused: Gram-MFMA sim -> softmax*spatial -> MFMA fixup (wts in LDS)
//      -> banded-W MFMA aggregate -> output_proj MFMA -> d_out
__global__ __launch_bounds__(1024) void simfixagg_kernel(
    const short* __restrict__ pxt, const float* __restrict__ sigma_p,
    const float* __restrict__ sem,
    const float* __restrict__ fw1, const float* __restrict__ fb1,
    const float* __restrict__ flnw, const float* __restrict__ flnb,
    const float* __restrict__ fw2, const float* __restrict__ fb2,
    const float* __restrict__ spatial,
    const float* __restrict__ ow1, const float* __restrict__ ob1,
    const float* __restrict__ olnw, const float* __restrict__ olnb,
    const float* __restrict__ ow2, const float* __restrict__ ob2,
    float* __restrict__ out)
{
    __shared__ alignas(16) char sBig[7 * WW * CDIM * 2];   // 114,688 B
    __shared__ alignas(16) char sAux[64 * 66 * 4];         //  16,896 B
    __shared__ alignas(16) float sSimWts[DSQ][64];         //  12,544 B: sSim then sWts
    __shared__ alignas(16) float sCmb[DSQ][66];            //  12,936 B

    // Gram phase
    short* rows = reinterpret_cast<short*>(sBig);
    // fixup overlay
    short* B1   = reinterpret_cast<short*>(sBig);          // [64 px][192]
    short* A1   = reinterpret_cast<short*>(sBig + 24576);  // [64 o ][192]
    short* B2   = reinterpret_cast<short*>(sBig + 49152);  // [64 px][64]
    short* A2   = reinterpret_cast<short*>(sBig + 57344);  // [64 o ][64]
    float* fSem = reinterpret_cast<float*>(sBig + 65536);  // [128][64]
    float* prm  = reinterpret_cast<float*>(sBig + 98304);  // 4 x 64
    // agg/op-proj overlay
    short* W0   = reinterpret_cast<short*>(sBig);          // [64][72] bf16 banded
    short* W1   = reinterpret_cast<short*>(sBig + 9216);
    short* sSa  = reinterpret_cast<short*>(sBig + 18432);  // S row [128][64] bf16
    float (*sT)[65] = reinterpret_cast<float(*)[65]>(sBig);             // 33,280
    short* sWb  = reinterpret_cast<short*>(sBig + 57344);               // 32,768
    short* sXT  = reinterpret_cast<short*>(sBig + 90112);               // 16,384

    float (*sP64)[66] = reinterpret_cast<float(*)[66]>(sAux);
    float (*red1)[65] = reinterpret_cast<float(*)[65]>(sAux);
    float (*red2)[65] = reinterpret_cast<float(*)[65]>(sAux + 16 * 65 * 4);

    const int tid = threadIdx.x;
    const int l = tid & 63;
    const int q = tid >> 6;
    const int qu = __builtin_amdgcn_readfirstlane(q);
    // XCD-bijective swizzle (256 blocks, 8 XCDs): XCD k owns 32 consecutive rows.
    const int lbid = ((blockIdx.x & 7) << 5) | (blockIdx.x >> 3);
    const int b = lbid >> 6;
    const int h = lbid & 63;

    // ---- stage 7 reflected rows, bf16 [row][p][c] swz ----
    for (int idx = tid; idx < 7 * WW * 16; idx += 1024) {
        const int cchunk = idx & 15;
        const int p = (idx >> 4) & 63;
        const int row = idx >> 10;
        const int hp = reflect64(h + row - RR);
        const short8v v = *reinterpret_cast<const short8v*>(
            &pxt[((b * HH + hp) * WW + p) * CDIM + cchunk * 8]);
        *reinterpret_cast<short8v*>(
            &rows[(row * WW + p) * CDIM + ((cchunk * 8) ^ ((p & 7) << 3))]) = v;
    }
    __syncthreads();

    // ---- Gram MFMA per ki (sP64 gather variant, r12-validated) ----
    const int lm = l & 15, g = l >> 4;
    const int tm = q >> 2, tn = q & 3;
    const int pa = tm * 16 + lm;
    const int pxb = tn * 16 + lm;
    const int abase = (3 * WW + pa) * CDIM, as_ = (pa & 7) << 3;
    const int bs_ = (pxb & 7) << 3;

    short8v afr[4];
    #pragma unroll
    for (int kk = 0; kk < 4; ++kk)
        afr[kk] = *reinterpret_cast<const short8v*>(
            &rows[abase + ((kk * 32 + g * 8) ^ as_)]);

    const float rscale = 0.088388347648318447f;  // 1/sqrt(128)
    for (int ki = 0; ki < 7; ++ki) {
        float4v acc = {0.f, 0.f, 0.f, 0.f};
        const int bbase = (ki * WW + pxb) * CDIM;
        #pragma unroll
        for (int kk = 0; kk < 4; ++kk) {
            const short8v bf = *reinterpret_cast<const short8v*>(
                &rows[bbase + ((kk * 32 + g * 8) ^ bs_)]);
            acc = __builtin_amdgcn_mfma_f32_16x16x32_bf16(afr[kk], bf, acc, 0, 0, 0);
        }
        #pragma unroll
        for (int r = 0; r < 4; ++r)
            sP64[tm * 16 + g * 4 + r][tn * 16 + lm] = acc[r];
        __syncthreads();
        if (tid < 448) {
            const int kj = tid >> 6, p = tid & 63;
            sSimWts[ki * 7 + kj][p] = sP64[p][reflect64(p + kj - RR)] * rscale;
        }
        __syncthreads();
    }
    // rows/sP64 dead -> stage fixup overlays

    // A1: fw1 -> bf16 [64][192]: [0:49]=cmb-cols, [49:64]=0, [64:192]=sem-cols
    for (int idx = tid; idx < 64 * 24; idx += 1024) {
        const int o = idx / 24;
        const int ch0 = (idx % 24) * 8;
        short8v pk;
        #pragma unroll
        for (int j = 0; j < 8; ++j) {
            const int c = ch0 + j;
            float v = 0.f;
            if (o < DSQ) {
                if (c < DSQ) v = fw1[o * 177 + c];
                else if (c >= 64) v = fw1[o * 177 + DSQ + (c - 64)];
            }
            pk[j] = f2bf(v);
        }
        *reinterpret_cast<short8v*>(&A1[o * 192 + (ch0 ^ ((o & 7) << 3))]) = pk;
    }
    // A2: fw2 -> bf16 [64][64], zero-padded
    for (int idx = tid; idx < 64 * 8; idx += 1024) {
        const int o = idx >> 3;
        const int ch0 = (idx & 7) * 8;
        short8v pk;
        #pragma unroll
        for (int j = 0; j < 8; ++j) {
            const int c = ch0 + j;
            pk[j] = (o < DSQ && c < DSQ) ? f2bf(fw2[o * DSQ + c]) : (short)0;
        }
        *reinterpret_cast<short8v*>(&A2[o * 64 + (ch0 ^ ((o & 7) << 3))]) = pk;
    }
    // B2 zero-fill
    {
        const short8v z = {0, 0, 0, 0, 0, 0, 0, 0};
        for (int idx = tid; idx < 64 * 8; idx += 1024)
            *reinterpret_cast<short8v*>(&B2[idx * 8]) = z;
    }
    // B1 pad cols [49..64) zero
    for (int idx = tid; idx < 64 * 15; idx += 1024) {
        const int p = idx / 15, c = DSQ + idx % 15;
        B1[p * 192 + (c ^ ((p & 7) << 3))] = 0;
    }
    // params
    for (int idx = tid; idx < 256; idx += 1024) {
        const int a = idx >> 6, i = idx & 63;
        float v = 0.f;
        if (i < DSQ) {
            if (a == 0) v = fb1[i];
            else if (a == 1) v = flnw[i];
            else if (a == 2) v = flnb[i];
            else v = fb2[i];
        }
        prm[a * 64 + i] = v;
    }
    // fSem f32 [c][p]
    {
        const float* srow = sem + (b * CDIM * HH + h) * WW;
        for (int idx = tid; idx < CDIM * 16; idx += 1024) {
            const int r = idx >> 4, pos = idx & 15;
            *reinterpret_cast<float4*>(&fSem[r * WW + pos * 4]) =
                *reinterpret_cast<const float4*>(&srow[r * HH * WW + pos * 4]);
        }
    }
    // softmax * spatial kernel -> sCmb f32 + B1 cmb-cols bf16
    {
        float rv[DSQ];
        #pragma unroll
        for (int n = 0; n < DSQ; ++n) rv[n] = sSimWts[n][l];
        float m = -1e30f;
        #pragma unroll
        for (int n = 0; n < DSQ; ++n) m = fmaxf(m, rv[n]);
        float ssum = 0.f;
        #pragma unroll
        for (int n = 0; n < DSQ; ++n) ssum += __expf(rv[n] - m);
        const float inv = 1.0f / ssum;
        const float sigma = sigma_p[0];
        const float inv2s2 = 1.0f / (2.0f * sigma * sigma);
        const int swl = (l & 7) << 3;
        #pragma unroll
        for (int k = 0; k < 4; ++k) {
            const int n = q + 16 * k;
            if (n < DSQ) {
                const int ki = n / 7, kj = n % 7;
                const float dx = (float)(ki - 3) * (1.0f / 3.0f);
                const float dy = (float)(kj - 3) * (1.0f / 3.0f);
                const float sk = __expf(-(dx * dx + dy * dy) * inv2s2);
                const float cv = __expf(rv[n] - m) * inv * sk;
                sCmb[n][l] = cv;
                B1[l * 192 + (n ^ swl)] = f2bf(cv);
            }
        }
    }
    __syncthreads();
    // B1 sem-cols: transpose-pack from fSem
    {
        const int c0 = q * 8;
        short8v pk;
        #pragma unroll
        for (int j = 0; j < 8; ++j) pk[j] = f2bf(fSem[(c0 + j) * WW + l]);
        *reinterpret_cast<short8v*>(&B1[l * 192 + ((64 + c0) ^ ((l & 7) << 3))]) = pk;
    }
    __syncthreads();

    // ---- fixup conv1 MFMA ----
    const int oA = tm * 16 + lm;
    const int aswz = (oA & 7) << 3;
    const int p = tn * 16 + lm;
    const int bswz = (p & 7) << 3;

    float4v facc = {0.f, 0.f, 0.f, 0.f};
    #pragma unroll
    for (int kk = 0; kk < 6; ++kk) {
        const int ki = kk * 32 + g * 8;
        const short8v af = *reinterpret_cast<const short8v*>(&A1[oA * 192 + (ki ^ aswz)]);
        const short8v bf = *reinterpret_cast<const short8v*>(&B1[p * 192 + (ki ^ bswz)]);
        facc = __builtin_amdgcn_mfma_f32_16x16x32_bf16(af, bf, facc, 0, 0, 0);
    }
    float vals[4];
    float s1 = 0.f, s2 = 0.f;
    #pragma unroll
    for (int r = 0; r < 4; ++r) {
        const int o = tm * 16 + g * 4 + r;
        const float v = facc[r] + prm[o];
        vals[r] = v;
        if (o < DSQ) { s1 += v; s2 += v * v; }
    }
    red1[tm * 4 + g][p] = s1;
    red2[tm * 4 + g][p] = s2;
    __syncthreads();
    float t1 = 0.f, t2 = 0.f;
    #pragma unroll
    for (int j = 0; j < 16; ++j) { t1 += red1[j][p]; t2 += red2[j][p]; }
    const float mean = t1 * (1.0f / 49.0f);
    const float var  = t2 * (1.0f / 49.0f) - mean * mean;
    const float rstd = rsqrtf(var + 1e-6f);
    #pragma unroll
    for (int r = 0; r < 4; ++r) {
        const int o = tm * 16 + g * 4 + r;
        if (o < DSQ) {
            const float v = (vals[r] - mean) * rstd * prm[64 + o] + prm[128 + o];
            const float sv = v * sigm(v);
            B2[p * 64 + (o ^ bswz)] = f2bf(sv);
        }
    }
    __syncthreads();

    // ---- fixup conv2 MFMA + gate + normalize -> sWts (LDS) ----
    float4v facc2 = {0.f, 0.f, 0.f, 0.f};
    #pragma unroll
    for (int kk = 0; kk < 2; ++kk) {
        const int ki = kk * 32 + g * 8;
        const short8v af = *reinterpret_cast<const short8v*>(&A2[oA * 64 + (ki ^ aswz)]);
        const short8v bf = *reinterpret_cast<const short8v*>(&B2[p * 64 + (ki ^ bswz)]);
        facc2 = __builtin_amdgcn_mfma_f32_16x16x32_bf16(af, bf, facc2, 0, 0, 0);
    }
    float c2v[4];
    float ps = 0.f;
    #pragma unroll
    for (int r = 0; r < 4; ++r) {
        const int o = tm * 16 + g * 4 + r;
        if (o < DSQ) {
            const float f = facc2[r] + prm[192 + o];
            c2v[r] = sCmb[o][p] * (1.0f + sigm(f));
            ps += c2v[r];
        } else c2v[r] = 0.f;
    }
    red1[tm * 4 + g][p] = ps;
    __syncthreads();
    float tot = 0.f;
    #pragma unroll
    for (int j = 0; j < 16; ++j) tot += red1[j][p];
    const float invt = 1.0f / (tot + 1e-7f);
    #pragma unroll
    for (int r = 0; r < 4; ++r) {
        const int o = tm * 16 + g * 4 + r;
        if (o < DSQ) sSimWts[o][p] = c2v[r] * invt;   // sSim region reused as sWts
    }
    __syncthreads();

    // ---- aggregate via banded-W MFMA (wts stay in LDS) ----
    // stage op_w1 bf16 swizzled into sWb
    {
        const int o = tid >> 3;
        const int i0 = (tid & 7) * 16;
        const int sw = (o & 7) << 3;
        const float* src = ow1 + o * CDIM + i0;
        short8v pk0, pk1;
        #pragma unroll
        for (int j = 0; j < 8; ++j) pk0[j] = f2bf(src[j]);
        #pragma unroll
        for (int j = 0; j < 8; ++j) pk1[j] = f2bf(src[8 + j]);
        *reinterpret_cast<short8v*>(&sWb[o * 128 + (i0 ^ sw)]) = pk0;
        *reinterpret_cast<short8v*>(&sWb[o * 128 + ((i0 + 8) ^ sw)]) = pk1;
    }

    const float* sb = spatial + b * CDIM * HH * WW;
    float4 sreg[2];
    #define LD_SROW(KI)                                                          \
        { const int hp_ = reflect64(h + (KI) - RR);                              \
          _Pragma("unroll")                                                      \
          for (int j = 0; j < 2; ++j) {                                          \
              const int idx = tid * 2 + j;                                       \
              const int c = idx >> 4, pos = idx & 15;                            \
              sreg[j] = *reinterpret_cast<const float4*>(                        \
                  &sb[(c * HH + hp_) * WW + pos * 4]);                           \
          } }
    #define ST_SROW()                                                            \
        { _Pragma("unroll")                                                      \
          for (int j = 0; j < 2; ++j) {                                          \
              const int idx = tid * 2 + j;                                       \
              const int c = idx >> 4, pos = idx & 15;                            \
              const int sw_ = (c & 7) << 3;                                      \
              _Pragma("unroll")                                                  \
              for (int m = 0; m < 4; ++m)                                        \
                  sSa[c * 64 + ((pos * 4 + m) ^ sw_)] =                          \
                      f2bf(((const float*)&sreg[j])[m]);                         \
          } }
    #define ZERO_W(DST)                                                          \
        { const short8v z8 = {0,0,0,0,0,0,0,0};                                  \
          if (tid < 576) *reinterpret_cast<short8v*>(&(DST)[tid * 8]) = z8; }
    #define SCATTER_W(DST, KIN)                                                  \
        if (tid < 64) {                                                          \
            const int pp_ = tid;                                                 \
            const int s_ = (pp_ > 3) ? (pp_ - 3) : 0;                            \
            float col[7] = {0.f, 0.f, 0.f, 0.f, 0.f, 0.f, 0.f};                  \
            _Pragma("unroll")                                                    \
            for (int kj = 0; kj < 7; ++kj) {                                     \
                const int pr = reflect64(pp_ + kj - RR);                         \
                const float wv_ = sSimWts[(KIN) * 7 + kj][pp_];                  \
                const int id_ = pr - s_;                                         \
                _Pragma("unroll")                                                \
                for (int jj = 0; jj < 7; ++jj) if (id_ == jj) col[jj] += wv_;    \
            }                                                                    \
            _Pragma("unroll")                                                    \
            for (int jj = 0; jj < 7; ++jj) {                                     \
                const int pr = s_ + jj;                                          \
                if (pr < 64) (DST)[pp_ * 72 + pr] = f2bf(col[jj]);               \
            }                                                                    \
        }

    // prologue: zero W0/W1, load S0
    ZERO_W(W0);
    ZERO_W(W1);
    LD_SROW(0);
    __syncthreads();
    SCATTER_W(W0, 0);
    ST_SROW();
    __syncthreads();

    // agg GEMM tiles: M=128 (c), N=64 (p). wave q: tmA=q>>1, N-tiles (q&1)*2 +{0,1}
    const int tmA = q >> 1;
    const int oaA = tmA * 16 + lm;
    const int arA = oaA * 64, aswA = (oaA & 7) << 3;
    const int pA0 = ((q & 1) * 2) * 16 + lm, pA1 = ((q & 1) * 2 + 1) * 16 + lm;

    float4v ag0 = {0.f, 0.f, 0.f, 0.f}, ag1 = {0.f, 0.f, 0.f, 0.f};
    for (int ki = 0; ki < 7; ++ki) {
        if (ki < 6) LD_SROW(ki + 1);
        const short* Wc = (ki & 1) ? W1 : W0;
        #pragma unroll
        for (int kk = 0; kk < 2; ++kk) {
            const int k0 = kk * 32 + g * 8;
            const short8v a8 = *reinterpret_cast<const short8v*>(&sSa[arA + (k0 ^ aswA)]);
            const short8v b80 = *reinterpret_cast<const short8v*>(&Wc[pA0 * 72 + k0]);
            const short8v b81 = *reinterpret_cast<const short8v*>(&Wc[pA1 * 72 + k0]);
            ag0 = __builtin_amdgcn_mfma_f32_16x16x32_bf16(a8, b80, ag0, 0, 0, 0);
            ag1 = __builtin_amdgcn_mfma_f32_16x16x32_bf16(a8, b81, ag1, 0, 0, 0);
        }
        if (ki < 6) { SCATTER_W(((ki & 1) ? W0 : W1), ki + 1); }
        __syncthreads();
        if (ki < 6) {
            ST_SROW();
            if (ki & 1) { ZERO_W(W1); } else { ZERO_W(W0); }   // just-read buf -> scatter tgt at ki+1
            __syncthreads();
        }
    }
    #undef LD_SROW
    #undef ST_SROW
    #undef ZERO_W
    #undef SCATTER_W

    // write agg result as bf16 op-proj B operand sXT[p][c]
    {
        #pragma unroll
        for (int r = 0; r < 4; ++r) {
            const int c = tmA * 16 + g * 4 + r;
            sXT[pA0 * 128 + (c ^ ((pA0 & 7) << 3))] = f2bf(ag0[r]);
            sXT[pA1 * 128 + (c ^ ((pA1 & 7) << 3))] = f2bf(ag1[r]);
        }
    }
    __syncthreads();

    // ---- output_proj conv1 MFMA ----
    const int tmo = q >> 1;
    const int tn0 = (q & 1) * 2;
    const int oaop = tmo * 16 + lm;
    const int arow = oaop * 128, asw = (oaop & 7) << 3;
    const int p0 = tn0 * 16 + lm, p1 = (tn0 + 1) * 16 + lm;
    const int bsw0 = (p0 & 7) << 3, bsw1 = (p1 & 7) << 3;

    {
        float4v a0 = {0.f, 0.f, 0.f, 0.f}, a1 = {0.f, 0.f, 0.f, 0.f};
        #pragma unroll
        for (int kk = 0; kk < 4; ++kk) {
            const int ki = kk * 32 + g * 8;
            const short8v af = *reinterpret_cast<const short8v*>(&sWb[arow + (ki ^ asw)]);
            const short8v bf0 = *reinterpret_cast<const short8v*>(&sXT[p0 * 128 + (ki ^ bsw0)]);
            const short8v bf1 = *reinterpret_cast<const short8v*>(&sXT[p1 * 128 + (ki ^ bsw1)]);
            a0 = __builtin_amdgcn_mfma_f32_16x16x32_bf16(af, bf0, a0, 0, 0, 0);
            a1 = __builtin_amdgcn_mfma_f32_16x16x32_bf16(af, bf1, a1, 0, 0, 0);
        }
        __syncthreads();      // W/S region free for sT
        #pragma unroll
        for (int r = 0; r < 4; ++r) sT[tmo * 16 + g * 4 + r][p0] = a0[r];
        #pragma unroll
        for (int r = 0; r < 4; ++r) sT[tmo * 16 + g * 4 + r][p1] = a1[r];
    }
    __syncthreads();

    // restage sWb = op_w2; bias + LN(128) -> sXT (reused as conv2 B operand)
    {
        const int o = tid >> 3;
        const int i0 = (tid & 7) * 16;
        const int sw = (o & 7) << 3;
        const float* src = ow2 + o * CDIM + i0;
        short8v pk0, pk1;
        #pragma unroll
        for (int j = 0; j < 8; ++j) pk0[j] = f2bf(src[j]);
        #pragma unroll
        for (int j = 0; j < 8; ++j) pk1[j] = f2bf(src[8 + j]);
        *reinterpret_cast<short8v*>(&sWb[o * 128 + (i0 ^ sw)]) = pk0;
        *reinterpret_cast<short8v*>(&sWb[o * 128 + ((i0 + 8) ^ sw)]) = pk1;
    }
    {
        float vals2[8];
        float u1 = 0.f, u2 = 0.f;
        #pragma unroll
        for (int j = 0; j < 8; ++j) {
            const float v = sT[qu * 8 + j][l] + ob1[qu * 8 + j];
            vals2[j] = v; u1 += v; u2 += v * v;
        }
        red1[q][l] = u1; red2[q][l] = u2;
        __syncthreads();
        float v1 = 0.f, v2 = 0.f;
        #pragma unroll
        for (int j = 0; j < 16; ++j) { v1 += red1[j][l]; v2 += red2[j][l]; }
        const float mn = v1 * (1.0f / 128.0f);
        const float vr = v2 * (1.0f / 128.0f) - mn * mn;
        const float rs = rsqrtf(vr + 1e-6f);
        short8v pk;
        #pragma unroll
        for (int j = 0; j < 8; ++j) {
            const float v = (vals2[j] - mn) * rs * olnw[qu * 8 + j] + olnb[qu * 8 + j];
            pk[j] = f2bf(v);
        }
        *reinterpret_cast<short8v*>(&sXT[l * 128 + ((qu * 8) ^ ((l & 7) << 3))]) = pk;
    }
    __syncthreads();

    // ---- output_proj conv2 MFMA + bias -> out ----
    {
        float4v a0 = {0.f, 0.f, 0.f, 0.f}, a1 = {0.f, 0.f, 0.f, 0.f};
        #pragma unroll
        for (int kk = 0; kk < 4; ++kk) {
            const int ki = kk * 32 + g * 8;
            const short8v af = *reinterpret_cast<const short8v*>(&sWb[arow + (ki ^ asw)]);
            const short8v bf0 = *reinterpret_cast<const short8v*>(&sXT[p0 * 128 + (ki ^ bsw0)]);
            const short8v bf1 = *reinterpret_cast<const short8v*>(&sXT[p1 * 128 + (ki ^ bsw1)]);
            a0 = __builtin_amdgcn_mfma_f32_16x16x32_bf16(af, bf0, a0, 0, 0, 0);
            a1 = __builtin_amdgcn_mfma_f32_16x16x32_bf16(af, bf1, a1, 0, 0, 0);
        }
        const float4 bv = *reinterpret_cast<const float4*>(&ob2[tmo * 16 + g * 4]);
        float* obase = out + (b * CDIM * HH + h) * WW;
        #pragma unroll
        for (int r = 0; r < 4; ++r) {
            const float bias = ((const float*)&bv)[r];
            obase[(tmo * 16 + g * 4 + r) * HH * WW + p0] = a0[r] + bias;
            obase[(tmo * 16 + g * 4 + r) * HH * WW + p1] = a1[r] + bias;
        }
    }
}

extern "C" void kernel_launch(void* const* d_in, const int* in_sizes, int n_in,
                              void* d_out, int out_size, void* d_ws, size_t ws_size,
                              hipStream_t stream) {
    (void)in_sizes; (void)n_in; (void)out_size; (void)ws_size;
    const float* spatial  = (const float*)d_in[0];
    const float* semantic = (const float*)d_in[1];
    const float* rp_w1 = (const float*)d_in[2];
    const float* rp_b1 = (const float*)d_in[3];
    const float* rp_lnw = (const float*)d_in[4];
    const float* rp_lnb = (const float*)d_in[5];
    const float* rp_w2 = (const float*)d_in[6];
    const float* rp_b2 = (const float*)d_in[7];
    const float* fx_w1 = (const float*)d_in[8];
    const float* fx_b1 = (const float*)d_in[9];
    const float* fx_lnw = (const float*)d_in[10];
    const float* fx_lnb = (const float*)d_in[11];
    const float* fx_w2 = (const float*)d_in[12];
    const float* fx_b2 = (const float*)d_in[13];
    const float* sigma = (const float*)d_in[14];
    const float* op_w1 = (const float*)d_in[15];
    const float* op_b1 = (const float*)d_in[16];
    const float* op_lnw = (const float*)d_in[17];
    const float* op_lnb = (const float*)d_in[18];
    const float* op_w2 = (const float*)d_in[19];
    const float* op_b2 = (const float*)d_in[20];

    char* wsb = (char*)d_ws;
    short* pxt  = (short*)wsb;                   // 4 MB bf16 [b][h][p][c]
    float* outp = (float*)d_out;

    dim3 grid(BB * HH), blk(1024);
    proj_kernel<true><<<grid, blk, 0, stream>>>(semantic, rp_w1, rp_b1, rp_lnw, rp_lnb,
                                                rp_w2, rp_b2, pxt);
    simfixagg_kernel<<<grid, blk, 0, stream>>>(pxt, sigma, semantic,
                                               fx_w1, fx_b1, fx_lnw, fx_lnb, fx_w2, fx_b2,
                                               spatial,
                                               op_w1, op_b1, op_lnw, op_lnb, op_w2, op_b2,
                                               outp);
}

// Round 17
// 48.838 us; speedup vs baseline: 1.4235x; 1.1144x over previous
//
#include <hip/hip_runtime.h>
#include <cstdint>

#define BB 4
#define CDIM 128
#define HH 64
#define WW 64
#define RR 3
#define DD 7
#define DSQ 49

typedef __attribute__((ext_vector_type(8))) short short8v;   // 8 bf16 = 4 VGPR
typedef __attribute__((ext_vector_type(4))) short short4v;   // 4 bf16 = 2 VGPR
typedef __attribute__((ext_vector_type(4))) float float4v;

__device__ __forceinline__ int reflect64(int p) {
    p = (p < 0) ? -p : p;
    return (p > 63) ? (126 - p) : p;
}
__device__ __forceinline__ float sigm(float x) { return 1.0f / (1.0f + __expf(-x)); }
__device__ __forceinline__ short f2bf(float f) {     // f32 -> bf16 RNE
    uint32_t u = __float_as_uint(f);
    u += 0x7FFF + ((u >> 16) & 1);
    return (short)(u >> 16);
}

// ---- range_proj: conv1x1 -> LN -> SiLU -> conv1x1 via bf16 MFMA.
// Output: bf16 TRANSPOSED [b][h][p][c].
template<bool SILU>
__global__ __launch_bounds__(1024) void proj_kernel(
    const float* __restrict__ x, const float* __restrict__ w1,
    const float* __restrict__ b1, const float* __restrict__ lnw,
    const float* __restrict__ lnb, const float* __restrict__ w2,
    const float* __restrict__ b2, short* __restrict__ outT)
{
    __shared__ short sW1[CDIM * CDIM];
    __shared__ short sW2[CDIM * CDIM];
    __shared__ short sXT[WW * CDIM];
    __shared__ short sXT2[WW * CDIM];
    __shared__ float sT[CDIM][65];
    __shared__ float red1[16][WW];
    __shared__ float red2[16][WW];

    const int tid = threadIdx.x;
    const int l = tid & 63;
    const int q = tid >> 6;
    const int qu = __builtin_amdgcn_readfirstlane(q);
    const int b = blockIdx.x >> 6;
    const int h = blockIdx.x & 63;

    {
        const int o = tid >> 3;
        const int i0 = (tid & 7) * 16;
        const int sw = (o & 7) << 3;
        const float* wsrc[2] = {w1, w2};
        short* wdst[2] = {sW1, sW2};
        #pragma unroll
        for (int m = 0; m < 2; ++m) {
            const float* src = wsrc[m] + o * CDIM + i0;
            short8v pk0, pk1;
            #pragma unroll
            for (int j = 0; j < 8; ++j) pk0[j] = f2bf(src[j]);
            #pragma unroll
            for (int j = 0; j < 8; ++j) pk1[j] = f2bf(src[8 + j]);
            *reinterpret_cast<short8v*>(&wdst[m][o * 128 + (i0 ^ sw)]) = pk0;
            *reinterpret_cast<short8v*>(&wdst[m][o * 128 + ((i0 + 8) ^ sw)]) = pk1;
        }
    }
    {
        const int pos = tid & 15;
        const int c0 = tid >> 4;
        const float* xrow = x + (b * CDIM * HH + h) * WW;
        #pragma unroll
        for (int rr = 0; rr < 2; ++rr) {
            const int c = c0 + rr * 64;
            const float4 v = *reinterpret_cast<const float4*>(&xrow[c * HH * WW + pos * 4]);
            #pragma unroll
            for (int m = 0; m < 4; ++m) {
                const int p = pos * 4 + m;
                sXT[p * 128 + (c ^ ((p & 7) << 3))] = f2bf(((const float*)&v)[m]);
            }
        }
    }
    __syncthreads();

    const int lm = l & 15, g = l >> 4;
    const int tm = q >> 1;
    const int tn0 = (q & 1) * 2;
    const int oa = tm * 16 + lm;
    const int arow = oa * 128, asw = (oa & 7) << 3;
    const int p0 = tn0 * 16 + lm, p1 = (tn0 + 1) * 16 + lm;
    const int bsw0 = (p0 & 7) << 3, bsw1 = (p1 & 7) << 3;

    float4v acc0 = {0.f, 0.f, 0.f, 0.f}, acc1 = {0.f, 0.f, 0.f, 0.f};
    #pragma unroll
    for (int kk = 0; kk < 4; ++kk) {
        const int ki = kk * 32 + g * 8;
        const short8v af = *reinterpret_cast<const short8v*>(&sW1[arow + (ki ^ asw)]);
        const short8v bf0 = *reinterpret_cast<const short8v*>(&sXT[p0 * 128 + (ki ^ bsw0)]);
        const short8v bf1 = *reinterpret_cast<const short8v*>(&sXT[p1 * 128 + (ki ^ bsw1)]);
        acc0 = __builtin_amdgcn_mfma_f32_16x16x32_bf16(af, bf0, acc0, 0, 0, 0);
        acc1 = __builtin_amdgcn_mfma_f32_16x16x32_bf16(af, bf1, acc1, 0, 0, 0);
    }
    #pragma unroll
    for (int r = 0; r < 4; ++r) sT[tm * 16 + g * 4 + r][p0] = acc0[r];
    #pragma unroll
    for (int r = 0; r < 4; ++r) sT[tm * 16 + g * 4 + r][p1] = acc1[r];
    __syncthreads();

    {
        const int p = l;
        float vals[8];
        float s1 = 0.f, s2 = 0.f;
        #pragma unroll
        for (int j = 0; j < 8; ++j) {
            const float v = sT[qu * 8 + j][p] + b1[qu * 8 + j];
            vals[j] = v; s1 += v; s2 += v * v;
        }
        red1[q][p] = s1; red2[q][p] = s2;
        __syncthreads();
        float t1 = 0.f, t2 = 0.f;
        #pragma unroll
        for (int j = 0; j < 16; ++j) { t1 += red1[j][p]; t2 += red2[j][p]; }
        const float mean = t1 * (1.0f / 128.0f);
        const float var  = t2 * (1.0f / 128.0f) - mean * mean;
        const float rstd = rsqrtf(var + 1e-6f);
        short8v pk;
        #pragma unroll
        for (int j = 0; j < 8; ++j) {
            float v = (vals[j] - mean) * rstd * lnw[qu * 8 + j] + lnb[qu * 8 + j];
            if (SILU) v = v * sigm(v);
            pk[j] = f2bf(v);
        }
        *reinterpret_cast<short8v*>(&sXT2[p * 128 + ((qu * 8) ^ ((p & 7) << 3))]) = pk;
    }
    __syncthreads();

    {
        float4v a0 = {0.f, 0.f, 0.f, 0.f}, a1 = {0.f, 0.f, 0.f, 0.f};
        #pragma unroll
        for (int kk = 0; kk < 4; ++kk) {
            const int ki = kk * 32 + g * 8;
            const short8v af = *reinterpret_cast<const short8v*>(&sW2[arow + (ki ^ asw)]);
            const short8v bf0 = *reinterpret_cast<const short8v*>(&sXT2[p0 * 128 + (ki ^ bsw0)]);
            const short8v bf1 = *reinterpret_cast<const short8v*>(&sXT2[p1 * 128 + (ki ^ bsw1)]);
            a0 = __builtin_amdgcn_mfma_f32_16x16x32_bf16(af, bf0, a0, 0, 0, 0);
            a1 = __builtin_amdgcn_mfma_f32_16x16x32_bf16(af, bf1, a1, 0, 0, 0);
        }
        const float4 bv = *reinterpret_cast<const float4*>(&b2[tm * 16 + g * 4]);
        #pragma unroll
        for (int r = 0; r < 4; ++r) {
            const float bias = ((const float*)&bv)[r];
            sT[tm * 16 + g * 4 + r][p0] = a0[r] + bias;
            sT[tm * 16 + g * 4 + r][p1] = a1[r] + bias;
        }
    }
    __syncthreads();
    {
        const int p = tid >> 4;
        const int c0 = (tid & 15) * 8;
        short8v pk;
        #pragma unroll
        for (int j = 0; j < 8; ++j) pk[j] = f2bf(sT[c0 + j][p]);
        *reinterpret_cast<short8v*>(&outT[((b * HH + h) * WW + p) * CDIM + c0]) = pk;
    }
}

// ---- fully fused: Gram-MFMA sim -> softmax*spatial -> MFMA fixup (wts in LDS)
//      -> banded-W7 MFMA aggregate (1 barrier/iter) -> output_proj MFMA -> d_out
__global__ __launch_bounds__(1024) void simfixagg_kernel(
    const short* __restrict__ pxt, const float* __restrict__ sigma_p,
    const float* __restrict__ sem,
    const float* __restrict__ fw1, const float* __restrict__ fb1,
    const float* __restrict__ flnw, const float* __restrict__ flnb,
    const float* __restrict__ fw2, const float* __restrict__ fb2,
    const float* __restrict__ spatial,
    const float* __restrict__ ow1, const float* __restrict__ ob1,
    const float* __restrict__ olnw, const float* __restrict__ olnb,
    const float* __restrict__ ow2, const float* __restrict__ ob2,
    float* __restrict__ out)
{
    __shared__ alignas(16) char sBig[7 * WW * CDIM * 2];   // 114,688 B
    __shared__ alignas(16) char sAux[64 * 66 * 4];         //  16,896 B
    __shared__ alignas(16) float sSimWts[DSQ][64];         //  12,544 B: sSim then sWts
    __shared__ alignas(16) float sCmb[DSQ][66];            //  12,936 B

    // Gram phase
    short* rows = reinterpret_cast<short*>(sBig);
    // fixup overlay
    short* B1   = reinterpret_cast<short*>(sBig);          // [64 px][192]
    short* A1   = reinterpret_cast<short*>(sBig + 24576);  // [64 o ][192]
    short* B2   = reinterpret_cast<short*>(sBig + 49152);  // [64 px][64]
    short* A2   = reinterpret_cast<short*>(sBig + 57344);  // [64 o ][64]
    float* fSem = reinterpret_cast<float*>(sBig + 65536);  // [128][64]
    float* prm  = reinterpret_cast<float*>(sBig + 98304);  // 4 x 64
    // agg overlay: W7 [7][64][72] bf16 (64,512) + S double-buffer
    short* W7   = reinterpret_cast<short*>(sBig);          // 0 .. 64,512
    short* sSa0 = reinterpret_cast<short*>(sBig + 64512);  // [128][64] bf16
    short* sSa1 = reinterpret_cast<short*>(sBig + 80896);  // [128][64] bf16
    // op-proj overlay (after agg; W7/sSa dead)
    short* sWb  = reinterpret_cast<short*>(sBig);                       // 32,768
    short* sXT  = reinterpret_cast<short*>(sBig + 32768);               // 16,384
    float (*sT)[65] = reinterpret_cast<float(*)[65]>(sBig + 49152);     // 33,280

    float (*sP64)[66] = reinterpret_cast<float(*)[66]>(sAux);
    float (*red1)[65] = reinterpret_cast<float(*)[65]>(sAux);
    float (*red2)[65] = reinterpret_cast<float(*)[65]>(sAux + 16 * 65 * 4);

    const int tid = threadIdx.x;
    const int l = tid & 63;
    const int q = tid >> 6;
    const int qu = __builtin_amdgcn_readfirstlane(q);
    // XCD-bijective swizzle (256 blocks, 8 XCDs): XCD k owns 32 consecutive rows.
    const int lbid = ((blockIdx.x & 7) << 5) | (blockIdx.x >> 3);
    const int b = lbid >> 6;
    const int h = lbid & 63;

    // ---- stage 7 reflected rows, bf16 [row][p][c] swz ----
    for (int idx = tid; idx < 7 * WW * 16; idx += 1024) {
        const int cchunk = idx & 15;
        const int p = (idx >> 4) & 63;
        const int row = idx >> 10;
        const int hp = reflect64(h + row - RR);
        const short8v v = *reinterpret_cast<const short8v*>(
            &pxt[((b * HH + hp) * WW + p) * CDIM + cchunk * 8]);
        *reinterpret_cast<short8v*>(
            &rows[(row * WW + p) * CDIM + ((cchunk * 8) ^ ((p & 7) << 3))]) = v;
    }
    __syncthreads();

    // ---- Gram MFMA per ki (sP64 gather variant, r12-validated) ----
    const int lm = l & 15, g = l >> 4;
    const int tm = q >> 2, tn = q & 3;
    const int pa = tm * 16 + lm;
    const int pxb = tn * 16 + lm;
    const int abase = (3 * WW + pa) * CDIM, as_ = (pa & 7) << 3;
    const int bs_ = (pxb & 7) << 3;

    short8v afr[4];
    #pragma unroll
    for (int kk = 0; kk < 4; ++kk)
        afr[kk] = *reinterpret_cast<const short8v*>(
            &rows[abase + ((kk * 32 + g * 8) ^ as_)]);

    const float rscale = 0.088388347648318447f;  // 1/sqrt(128)
    for (int ki = 0; ki < 7; ++ki) {
        float4v acc = {0.f, 0.f, 0.f, 0.f};
        const int bbase = (ki * WW + pxb) * CDIM;
        #pragma unroll
        for (int kk = 0; kk < 4; ++kk) {
            const short8v bf = *reinterpret_cast<const short8v*>(
                &rows[bbase + ((kk * 32 + g * 8) ^ bs_)]);
            acc = __builtin_amdgcn_mfma_f32_16x16x32_bf16(afr[kk], bf, acc, 0, 0, 0);
        }
        #pragma unroll
        for (int r = 0; r < 4; ++r)
            sP64[tm * 16 + g * 4 + r][tn * 16 + lm] = acc[r];
        __syncthreads();
        if (tid < 448) {
            const int kj = tid >> 6, p = tid & 63;
            sSimWts[ki * 7 + kj][p] = sP64[p][reflect64(p + kj - RR)] * rscale;
        }
        __syncthreads();
    }
    // rows/sP64 dead -> stage fixup overlays

    // A1: fw1 -> bf16 [64][192]: [0:49]=cmb-cols, [49:64]=0, [64:192]=sem-cols
    for (int idx = tid; idx < 64 * 24; idx += 1024) {
        const int o = idx / 24;
        const int ch0 = (idx % 24) * 8;
        short8v pk;
        #pragma unroll
        for (int j = 0; j < 8; ++j) {
            const int c = ch0 + j;
            float v = 0.f;
            if (o < DSQ) {
                if (c < DSQ) v = fw1[o * 177 + c];
                else if (c >= 64) v = fw1[o * 177 + DSQ + (c - 64)];
            }
            pk[j] = f2bf(v);
        }
        *reinterpret_cast<short8v*>(&A1[o * 192 + (ch0 ^ ((o & 7) << 3))]) = pk;
    }
    // A2: fw2 -> bf16 [64][64], zero-padded
    for (int idx = tid; idx < 64 * 8; idx += 1024) {
        const int o = idx >> 3;
        const int ch0 = (idx & 7) * 8;
        short8v pk;
        #pragma unroll
        for (int j = 0; j < 8; ++j) {
            const int c = ch0 + j;
            pk[j] = (o < DSQ && c < DSQ) ? f2bf(fw2[o * DSQ + c]) : (short)0;
        }
        *reinterpret_cast<short8v*>(&A2[o * 64 + (ch0 ^ ((o & 7) << 3))]) = pk;
    }
    // B2 zero-fill
    {
        const short8v z = {0, 0, 0, 0, 0, 0, 0, 0};
        for (int idx = tid; idx < 64 * 8; idx += 1024)
            *reinterpret_cast<short8v*>(&B2[idx * 8]) = z;
    }
    // B1 pad cols [49..64) zero
    for (int idx = tid; idx < 64 * 15; idx += 1024) {
        const int p = idx / 15, c = DSQ + idx % 15;
        B1[p * 192 + (c ^ ((p & 7) << 3))] = 0;
    }
    // params
    for (int idx = tid; idx < 256; idx += 1024) {
        const int a = idx >> 6, i = idx & 63;
        float v = 0.f;
        if (i < DSQ) {
            if (a == 0) v = fb1[i];
            else if (a == 1) v = flnw[i];
            else if (a == 2) v = flnb[i];
            else v = fb2[i];
        }
        prm[a * 64 + i] = v;
    }
    // fSem f32 [c][p]
    {
        const float* srow = sem + (b * CDIM * HH + h) * WW;
        for (int idx = tid; idx < CDIM * 16; idx += 1024) {
            const int r = idx >> 4, pos = idx & 15;
            *reinterpret_cast<float4*>(&fSem[r * WW + pos * 4]) =
                *reinterpret_cast<const float4*>(&srow[r * HH * WW + pos * 4]);
        }
    }
    // softmax * spatial kernel -> sCmb f32 + B1 cmb-cols bf16
    {
        float rv[DSQ];
        #pragma unroll
        for (int n = 0; n < DSQ; ++n) rv[n] = sSimWts[n][l];
        float m = -1e30f;
        #pragma unroll
        for (int n = 0; n < DSQ; ++n) m = fmaxf(m, rv[n]);
        float ssum = 0.f;
        #pragma unroll
        for (int n = 0; n < DSQ; ++n) ssum += __expf(rv[n] - m);
        const float inv = 1.0f / ssum;
        const float sigma = sigma_p[0];
        const float inv2s2 = 1.0f / (2.0f * sigma * sigma);
        const int swl = (l & 7) << 3;
        #pragma unroll
        for (int k = 0; k < 4; ++k) {
            const int n = q + 16 * k;
            if (n < DSQ) {
                const int ki = n / 7, kj = n % 7;
                const float dx = (float)(ki - 3) * (1.0f / 3.0f);
                const float dy = (float)(kj - 3) * (1.0f / 3.0f);
                const float sk = __expf(-(dx * dx + dy * dy) * inv2s2);
                const float cv = __expf(rv[n] - m) * inv * sk;
                sCmb[n][l] = cv;
                B1[l * 192 + (n ^ swl)] = f2bf(cv);
            }
        }
    }
    __syncthreads();
    // B1 sem-cols: transpose-pack from fSem
    {
        const int c0 = q * 8;
        short8v pk;
        #pragma unroll
        for (int j = 0; j < 8; ++j) pk[j] = f2bf(fSem[(c0 + j) * WW + l]);
        *reinterpret_cast<short8v*>(&B1[l * 192 + ((64 + c0) ^ ((l & 7) << 3))]) = pk;
    }
    __syncthreads();

    // ---- fixup conv1 MFMA ----
    const int oA = tm * 16 + lm;
    const int aswz = (oA & 7) << 3;
    const int p = tn * 16 + lm;
    const int bswz = (p & 7) << 3;

    float4v facc = {0.f, 0.f, 0.f, 0.f};
    #pragma unroll
    for (int kk = 0; kk < 6; ++kk) {
        const int ki = kk * 32 + g * 8;
        const short8v af = *reinterpret_cast<const short8v*>(&A1[oA * 192 + (ki ^ aswz)]);
        const short8v bf = *reinterpret_cast<const short8v*>(&B1[p * 192 + (ki ^ bswz)]);
        facc = __builtin_amdgcn_mfma_f32_16x16x32_bf16(af, bf, facc, 0, 0, 0);
    }
    float vals[4];
    float s1 = 0.f, s2 = 0.f;
    #pragma unroll
    for (int r = 0; r < 4; ++r) {
        const int o = tm * 16 + g * 4 + r;
        const float v = facc[r] + prm[o];
        vals[r] = v;
        if (o < DSQ) { s1 += v; s2 += v * v; }
    }
    red1[tm * 4 + g][p] = s1;
    red2[tm * 4 + g][p] = s2;
    __syncthreads();
    float t1 = 0.f, t2 = 0.f;
    #pragma unroll
    for (int j = 0; j < 16; ++j) { t1 += red1[j][p]; t2 += red2[j][p]; }
    const float mean = t1 * (1.0f / 49.0f);
    const float var  = t2 * (1.0f / 49.0f) - mean * mean;
    const float rstd = rsqrtf(var + 1e-6f);
    #pragma unroll
    for (int r = 0; r < 4; ++r) {
        const int o = tm * 16 + g * 4 + r;
        if (o < DSQ) {
            const float v = (vals[r] - mean) * rstd * prm[64 + o] + prm[128 + o];
            const float sv = v * sigm(v);
            B2[p * 64 + (o ^ bswz)] = f2bf(sv);
        }
    }
    __syncthreads();

    // ---- fixup conv2 MFMA + gate + normalize -> sWts (LDS) ----
    float4v facc2 = {0.f, 0.f, 0.f, 0.f};
    #pragma unroll
    for (int kk = 0; kk < 2; ++kk) {
        const int ki = kk * 32 + g * 8;
        const short8v af = *reinterpret_cast<const short8v*>(&A2[oA * 64 + (ki ^ aswz)]);
        const short8v bf = *reinterpret_cast<const short8v*>(&B2[p * 64 + (ki ^ bswz)]);
        facc2 = __builtin_amdgcn_mfma_f32_16x16x32_bf16(af, bf, facc2, 0, 0, 0);
    }
    float c2v[4];
    float ps = 0.f;
    #pragma unroll
    for (int r = 0; r < 4; ++r) {
        const int o = tm * 16 + g * 4 + r;
        if (o < DSQ) {
            const float f = facc2[r] + prm[192 + o];
            c2v[r] = sCmb[o][p] * (1.0f + sigm(f));
            ps += c2v[r];
        } else c2v[r] = 0.f;
    }
    red1[tm * 4 + g][p] = ps;
    __syncthreads();
    float tot = 0.f;
    #pragma unroll
    for (int j = 0; j < 16; ++j) tot += red1[j][p];
    const float invt = 1.0f / (tot + 1e-7f);
    #pragma unroll
    for (int r = 0; r < 4; ++r) {
        const int o = tm * 16 + g * 4 + r;
        if (o < DSQ) sSimWts[o][p] = c2v[r] * invt;   // sSim region reused as sWts
    }
    __syncthreads();   // wts ready; fixup buffers dead

    // ---- aggregate: build all 7 banded W in parallel; S rows double-buffered ----
    const float* sb = spatial + b * CDIM * HH * WW;
    float4 sreg[2];
    #define LD_SROW(KI)                                                          \
        { const int hp_ = reflect64(h + (KI) - RR);                              \
          _Pragma("unroll")                                                      \
          for (int j = 0; j < 2; ++j) {                                          \
              const int idx = tid * 2 + j;                                       \
              const int c = idx >> 4, pos = idx & 15;                            \
              sreg[j] = *reinterpret_cast<const float4*>(                        \
                  &sb[(c * HH + hp_) * WW + pos * 4]);                           \
          } }
    #define ST_SROW(DST)                                                         \
        { _Pragma("unroll")                                                      \
          for (int j = 0; j < 2; ++j) {                                          \
              const int idx = tid * 2 + j;                                       \
              const int c = idx >> 4, pos = idx & 15;                            \
              const int sw_ = (c & 7) << 3;                                      \
              short4v pk;                                                        \
              _Pragma("unroll")                                                  \
              for (int m = 0; m < 4; ++m) pk[m] = f2bf(((const float*)&sreg[j])[m]); \
              *reinterpret_cast<short4v*>(&(DST)[c * 64 + ((pos * 4) ^ sw_)]) = pk;  \
          } }

    LD_SROW(0);
    if (tid < 448) {   // 7 waves: wave k builds W7[k]; each thread owns one 72-short row
        const int kin = tid >> 6, pp_ = tid & 63;
        const int s_ = (pp_ > 3) ? (pp_ - 3) : 0;
        float col[7] = {0.f, 0.f, 0.f, 0.f, 0.f, 0.f, 0.f};
        #pragma unroll
        for (int kj = 0; kj < 7; ++kj) {
            const int pr = reflect64(pp_ + kj - RR);
            const float wv_ = sSimWts[kin * 7 + kj][pp_];
            const int id_ = pr - s_;
            #pragma unroll
            for (int jj = 0; jj < 7; ++jj) if (id_ == jj) col[jj] += wv_;
        }
        short* wrow = &W7[(kin * 64 + pp_) * 72];
        const short8v z8 = {0, 0, 0, 0, 0, 0, 0, 0};
        #pragma unroll
        for (int j8 = 0; j8 < 9; ++j8)
            *reinterpret_cast<short8v*>(&wrow[j8 * 8]) = z8;
        #pragma unroll
        for (int jj = 0; jj < 7; ++jj) {
            const int pr = s_ + jj;
            if (pr < 64) wrow[pr] = f2bf(col[jj]);
        }
    }
    ST_SROW(sSa0);
    __syncthreads();

    // agg GEMM: M=128 (c), N=64 (p). wave q: tmA=q>>1, N-tiles (q&1)*2 +{0,1}
    const int tmA = q >> 1;
    const int oaA = tmA * 16 + lm;
    const int arA = oaA * 64, aswA = (oaA & 7) << 3;
    const int pA0 = ((q & 1) * 2) * 16 + lm, pA1 = ((q & 1) * 2 + 1) * 16 + lm;

    float4v ag0 = {0.f, 0.f, 0.f, 0.f}, ag1 = {0.f, 0.f, 0.f, 0.f};
    for (int ki = 0; ki < 7; ++ki) {
        if (ki < 6) LD_SROW(ki + 1);
        const short* Sc = (ki & 1) ? sSa1 : sSa0;
        const short* Wc = &W7[ki * 64 * 72];
        #pragma unroll
        for (int kk = 0; kk < 2; ++kk) {
            const int k0 = kk * 32 + g * 8;
            const short8v a8 = *reinterpret_cast<const short8v*>(&Sc[arA + (k0 ^ aswA)]);
            const short8v b80 = *reinterpret_cast<const short8v*>(&Wc[pA0 * 72 + k0]);
            const short8v b81 = *reinterpret_cast<const short8v*>(&Wc[pA1 * 72 + k0]);
            ag0 = __builtin_amdgcn_mfma_f32_16x16x32_bf16(a8, b80, ag0, 0, 0, 0);
            ag1 = __builtin_amdgcn_mfma_f32_16x16x32_bf16(a8, b81, ag1, 0, 0, 0);
        }
        if (ki < 6) { ST_SROW(((ki & 1) ? sSa0 : sSa1)); }   // write next buffer
        __syncthreads();
    }
    #undef LD_SROW
    #undef ST_SROW

    // write agg result as bf16 op-proj B operand sXT[p][c]; stage op_w1 -> sWb
    {
        #pragma unroll
        for (int r = 0; r < 4; ++r) {
            const int c = tmA * 16 + g * 4 + r;
            sXT[pA0 * 128 + (c ^ ((pA0 & 7) << 3))] = f2bf(ag0[r]);
            sXT[pA1 * 128 + (c ^ ((pA1 & 7) << 3))] = f2bf(ag1[r]);
        }
    }
    {
        const int o = tid >> 3;
        const int i0 = (tid & 7) * 16;
        const int sw = (o & 7) << 3;
        const float* src = ow1 + o * CDIM + i0;
        short8v pk0, pk1;
        #pragma unroll
        for (int j = 0; j < 8; ++j) pk0[j] = f2bf(src[j]);
        #pragma unroll
        for (int j = 0; j < 8; ++j) pk1[j] = f2bf(src[8 + j]);
        *reinterpret_cast<short8v*>(&sWb[o * 128 + (i0 ^ sw)]) = pk0;
        *reinterpret_cast<short8v*>(&sWb[o * 128 + ((i0 + 8) ^ sw)]) = pk1;
    }
    __syncthreads();

    // ---- output_proj conv1 MFMA ----
    const int tmo = q >> 1;
    const int tn0 = (q & 1) * 2;
    const int oaop = tmo * 16 + lm;
    const int arow = oaop * 128, asw = (oaop & 7) << 3;
    const int p0 = tn0 * 16 + lm, p1 = (tn0 + 1) * 16 + lm;
    const int bsw0 = (p0 & 7) << 3, bsw1 = (p1 & 7) << 3;

    {
        float4v a0 = {0.f, 0.f, 0.f, 0.f}, a1 = {0.f, 0.f, 0.f, 0.f};
        #pragma unroll
        for (int kk = 0; kk < 4; ++kk) {
            const int ki = kk * 32 + g * 8;
            const short8v af = *reinterpret_cast<const short8v*>(&sWb[arow + (ki ^ asw)]);
            const short8v bf0 = *reinterpret_cast<const short8v*>(&sXT[p0 * 128 + (ki ^ bsw0)]);
            const short8v bf1 = *reinterpret_cast<const short8v*>(&sXT[p1 * 128 + (ki ^ bsw1)]);
            a0 = __builtin_amdgcn_mfma_f32_16x16x32_bf16(af, bf0, a0, 0, 0, 0);
            a1 = __builtin_amdgcn_mfma_f32_16x16x32_bf16(af, bf1, a1, 0, 0, 0);
        }
        __syncthreads();      // sSa region free for sT; conv1 reads complete
        #pragma unroll
        for (int r = 0; r < 4; ++r) sT[tmo * 16 + g * 4 + r][p0] = a0[r];
        #pragma unroll
        for (int r = 0; r < 4; ++r) sT[tmo * 16 + g * 4 + r][p1] = a1[r];
    }
    __syncthreads();

    // restage sWb = op_w2; bias + LN(128) -> sXT (reused as conv2 B operand)
    {
        const int o = tid >> 3;
        const int i0 = (tid & 7) * 16;
        const int sw = (o & 7) << 3;
        const float* src = ow2 + o * CDIM + i0;
        short8v pk0, pk1;
        #pragma unroll
        for (int j = 0; j < 8; ++j) pk0[j] = f2bf(src[j]);
        #pragma unroll
        for (int j = 0; j < 8; ++j) pk1[j] = f2bf(src[8 + j]);
        *reinterpret_cast<short8v*>(&sWb[o * 128 + (i0 ^ sw)]) = pk0;
        *reinterpret_cast<short8v*>(&sWb[o * 128 + ((i0 + 8) ^ sw)]) = pk1;
    }
    {
        float vals2[8];
        float u1 = 0.f, u2 = 0.f;
        #pragma unroll
        for (int j = 0; j < 8; ++j) {
            const float v = sT[qu * 8 + j][l] + ob1[qu * 8 + j];
            vals2[j] = v; u1 += v; u2 += v * v;
        }
        red1[q][l] = u1; red2[q][l] = u2;
        __syncthreads();
        float v1 = 0.f, v2 = 0.f;
        #pragma unroll
        for (int j = 0; j < 16; ++j) { v1 += red1[j][l]; v2 += red2[j][l]; }
        const float mn = v1 * (1.0f / 128.0f);
        const float vr = v2 * (1.0f / 128.0f) - mn * mn;
        const float rs = rsqrtf(vr + 1e-6f);
        short8v pk;
        #pragma unroll
        for (int j = 0; j < 8; ++j) {
            const float v = (vals2[j] - mn) * rs * olnw[qu * 8 + j] + olnb[qu * 8 + j];
            pk[j] = f2bf(v);
        }
        *reinterpret_cast<short8v*>(&sXT[l * 128 + ((qu * 8) ^ ((l & 7) << 3))]) = pk;
    }
    __syncthreads();

    // ---- output_proj conv2 MFMA + bias -> out ----
    {
        float4v a0 = {0.f, 0.f, 0.f, 0.f}, a1 = {0.f, 0.f, 0.f, 0.f};
        #pragma unroll
        for (int kk = 0; kk < 4; ++kk) {
            const int ki = kk * 32 + g * 8;
            const short8v af = *reinterpret_cast<const short8v*>(&sWb[arow + (ki ^ asw)]);
            const short8v bf0 = *reinterpret_cast<const short8v*>(&sXT[p0 * 128 + (ki ^ bsw0)]);
            const short8v bf1 = *reinterpret_cast<const short8v*>(&sXT[p1 * 128 + (ki ^ bsw1)]);
            a0 = __builtin_amdgcn_mfma_f32_16x16x32_bf16(af, bf0, a0, 0, 0, 0);
            a1 = __builtin_amdgcn_mfma_f32_16x16x32_bf16(af, bf1, a1, 0, 0, 0);
        }
        const float4 bv = *reinterpret_cast<const float4*>(&ob2[tmo * 16 + g * 4]);
        float* obase = out + (b * CDIM * HH + h) * WW;
        #pragma unroll
        for (int r = 0; r < 4; ++r) {
            const float bias = ((const float*)&bv)[r];
            obase[(tmo * 16 + g * 4 + r) * HH * WW + p0] = a0[r] + bias;
            obase[(tmo * 16 + g * 4 + r) * HH * WW + p1] = a1[r] + bias;
        }
    }
}

extern "C" void kernel_launch(void* const* d_in, const int* in_sizes, int n_in,
                              void* d_out, int out_size, void* d_ws, size_t ws_size,
                              hipStream_t stream) {
    (void)in_sizes; (void)n_in; (void)out_size; (void)ws_size;
    const float* spatial  = (const float*)d_in[0];
    const float* semantic = (const float*)d_in[1];
    const float* rp_w1 = (const float*)d_in[2];
    const float* rp_b1 = (const float*)d_in[3];
    const float* rp_lnw = (const float*)d_in[4];
    const float* rp_lnb = (const float*)d_in[5];
    const float* rp_w2 = (const float*)d_in[6];
    const float* rp_b2 = (const float*)d_in[7];
    const float* fx_w1 = (const float*)d_in[8];
    const float* fx_b1 = (const float*)d_in[9];
    const float* fx_lnw = (const float*)d_in[10];
    const float* fx_lnb = (const float*)d_in[11];
    const float* fx_w2 = (const float*)d_in[12];
    const float* fx_b2 = (const float*)d_in[13];
    const float* sigma = (const float*)d_in[14];
    const float* op_w1 = (const float*)d_in[15];
    const float* op_b1 = (const float*)d_in[16];
    const float* op_lnw = (const float*)d_in[17];
    const float* op_lnb = (const float*)d_in[18];
    const float* op_w2 = (const float*)d_in[19];
    const float* op_b2 = (const float*)d_in[20];

    char* wsb = (char*)d_ws;
    short* pxt  = (short*)wsb;                   // 4 MB bf16 [b][h][p][c]
    float* outp = (float*)d_out;

    dim3 grid(BB * HH), blk(1024);
    proj_kernel<true><<<grid, blk, 0, stream>>>(semantic, rp_w1, rp_b1, rp_lnw, rp_lnb,
                                                rp_w2, rp_b2, pxt);
    simfixagg_kernel<<<grid, blk, 0, stream>>>(pxt, sigma, semantic,
                                               fx_w1, fx_b1, fx_lnw, fx_lnb, fx_w2, fx_b2,
                                               spatial,
                                               op_w1, op_b1, op_lnw, op_lnb, op_w2, op_b2,
                                               outp);
}

// Round 18
// 48.268 us; speedup vs baseline: 1.4403x; 1.0118x over previous
//
#include <hip/hip_runtime.h>
#include <cstdint>

#define BB 4
#define CDIM 128
#define HH 64
#define WW 64
#define RR 3
#define DD 7
#define DSQ 49

typedef __attribute__((ext_vector_type(8))) short short8v;   // 8 bf16 = 4 VGPR
typedef __attribute__((ext_vector_type(4))) short short4v;   // 4 bf16 = 2 VGPR
typedef __attribute__((ext_vector_type(4))) float float4v;

__device__ __forceinline__ int reflect64(int p) {
    p = (p < 0) ? -p : p;
    return (p > 63) ? (126 - p) : p;
}
__device__ __forceinline__ float sigm(float x) { return 1.0f / (1.0f + __expf(-x)); }
__device__ __forceinline__ short f2bf(float f) {     // f32 -> bf16 RNE
    uint32_t u = __float_as_uint(f);
    u += 0x7FFF + ((u >> 16) & 1);
    return (short)(u >> 16);
}

// ---- range_proj: conv1x1 -> LN -> SiLU -> conv1x1 via bf16 MFMA.
// Output: bf16 TRANSPOSED [b][h][p][c].
template<bool SILU>
__global__ __launch_bounds__(1024) void proj_kernel(
    const float* __restrict__ x, const float* __restrict__ w1,
    const float* __restrict__ b1, const float* __restrict__ lnw,
    const float* __restrict__ lnb, const float* __restrict__ w2,
    const float* __restrict__ b2, short* __restrict__ outT)
{
    __shared__ short sW1[CDIM * CDIM];
    __shared__ short sW2[CDIM * CDIM];
    __shared__ short sXT[WW * CDIM];
    __shared__ short sXT2[WW * CDIM];
    __shared__ float sT[CDIM][65];
    __shared__ float red1[16][WW];
    __shared__ float red2[16][WW];

    const int tid = threadIdx.x;
    const int l = tid & 63;
    const int q = tid >> 6;
    const int qu = __builtin_amdgcn_readfirstlane(q);
    const int b = blockIdx.x >> 6;
    const int h = blockIdx.x & 63;

    {
        const int o = tid >> 3;
        const int i0 = (tid & 7) * 16;
        const int sw = (o & 7) << 3;
        const float* wsrc[2] = {w1, w2};
        short* wdst[2] = {sW1, sW2};
        #pragma unroll
        for (int m = 0; m < 2; ++m) {
            const float* src = wsrc[m] + o * CDIM + i0;
            short8v pk0, pk1;
            #pragma unroll
            for (int j = 0; j < 8; ++j) pk0[j] = f2bf(src[j]);
            #pragma unroll
            for (int j = 0; j < 8; ++j) pk1[j] = f2bf(src[8 + j]);
            *reinterpret_cast<short8v*>(&wdst[m][o * 128 + (i0 ^ sw)]) = pk0;
            *reinterpret_cast<short8v*>(&wdst[m][o * 128 + ((i0 + 8) ^ sw)]) = pk1;
        }
    }
    {
        const int pos = tid & 15;
        const int c0 = tid >> 4;
        const float* xrow = x + (b * CDIM * HH + h) * WW;
        #pragma unroll
        for (int rr = 0; rr < 2; ++rr) {
            const int c = c0 + rr * 64;
            const float4 v = *reinterpret_cast<const float4*>(&xrow[c * HH * WW + pos * 4]);
            #pragma unroll
            for (int m = 0; m < 4; ++m) {
                const int p = pos * 4 + m;
                sXT[p * 128 + (c ^ ((p & 7) << 3))] = f2bf(((const float*)&v)[m]);
            }
        }
    }
    __syncthreads();

    const int lm = l & 15, g = l >> 4;
    const int tm = q >> 1;
    const int tn0 = (q & 1) * 2;
    const int oa = tm * 16 + lm;
    const int arow = oa * 128, asw = (oa & 7) << 3;
    const int p0 = tn0 * 16 + lm, p1 = (tn0 + 1) * 16 + lm;
    const int bsw0 = (p0 & 7) << 3, bsw1 = (p1 & 7) << 3;

    float4v acc0 = {0.f, 0.f, 0.f, 0.f}, acc1 = {0.f, 0.f, 0.f, 0.f};
    #pragma unroll
    for (int kk = 0; kk < 4; ++kk) {
        const int ki = kk * 32 + g * 8;
        const short8v af = *reinterpret_cast<const short8v*>(&sW1[arow + (ki ^ asw)]);
        const short8v bf0 = *reinterpret_cast<const short8v*>(&sXT[p0 * 128 + (ki ^ bsw0)]);
        const short8v bf1 = *reinterpret_cast<const short8v*>(&sXT[p1 * 128 + (ki ^ bsw1)]);
        acc0 = __builtin_amdgcn_mfma_f32_16x16x32_bf16(af, bf0, acc0, 0, 0, 0);
        acc1 = __builtin_amdgcn_mfma_f32_16x16x32_bf16(af, bf1, acc1, 0, 0, 0);
    }
    #pragma unroll
    for (int r = 0; r < 4; ++r) sT[tm * 16 + g * 4 + r][p0] = acc0[r];
    #pragma unroll
    for (int r = 0; r < 4; ++r) sT[tm * 16 + g * 4 + r][p1] = acc1[r];
    __syncthreads();

    {
        const int p = l;
        float vals[8];
        float s1 = 0.f, s2 = 0.f;
        #pragma unroll
        for (int j = 0; j < 8; ++j) {
            const float v = sT[qu * 8 + j][p] + b1[qu * 8 + j];
            vals[j] = v; s1 += v; s2 += v * v;
        }
        red1[q][p] = s1; red2[q][p] = s2;
        __syncthreads();
        float t1 = 0.f, t2 = 0.f;
        #pragma unroll
        for (int j = 0; j < 16; ++j) { t1 += red1[j][p]; t2 += red2[j][p]; }
        const float mean = t1 * (1.0f / 128.0f);
        const float var  = t2 * (1.0f / 128.0f) - mean * mean;
        const float rstd = rsqrtf(var + 1e-6f);
        short8v pk;
        #pragma unroll
        for (int j = 0; j < 8; ++j) {
            float v = (vals[j] - mean) * rstd * lnw[qu * 8 + j] + lnb[qu * 8 + j];
            if (SILU) v = v * sigm(v);
            pk[j] = f2bf(v);
        }
        *reinterpret_cast<short8v*>(&sXT2[p * 128 + ((qu * 8) ^ ((p & 7) << 3))]) = pk;
    }
    __syncthreads();

    {
        float4v a0 = {0.f, 0.f, 0.f, 0.f}, a1 = {0.f, 0.f, 0.f, 0.f};
        #pragma unroll
        for (int kk = 0; kk < 4; ++kk) {
            const int ki = kk * 32 + g * 8;
            const short8v af = *reinterpret_cast<const short8v*>(&sW2[arow + (ki ^ asw)]);
            const short8v bf0 = *reinterpret_cast<const short8v*>(&sXT2[p0 * 128 + (ki ^ bsw0)]);
            const short8v bf1 = *reinterpret_cast<const short8v*>(&sXT2[p1 * 128 + (ki ^ bsw1)]);
            a0 = __builtin_amdgcn_mfma_f32_16x16x32_bf16(af, bf0, a0, 0, 0, 0);
            a1 = __builtin_amdgcn_mfma_f32_16x16x32_bf16(af, bf1, a1, 0, 0, 0);
        }
        const float4 bv = *reinterpret_cast<const float4*>(&b2[tm * 16 + g * 4]);
        #pragma unroll
        for (int r = 0; r < 4; ++r) {
            const float bias = ((const float*)&bv)[r];
            sT[tm * 16 + g * 4 + r][p0] = a0[r] + bias;
            sT[tm * 16 + g * 4 + r][p1] = a1[r] + bias;
        }
    }
    __syncthreads();
    {
        const int p = tid >> 4;
        const int c0 = (tid & 15) * 8;
        short8v pk;
        #pragma unroll
        for (int j = 0; j < 8; ++j) pk[j] = f2bf(sT[c0 + j][p]);
        *reinterpret_cast<short8v*>(&outT[((b * HH + h) * WW + p) * CDIM + c0]) = pk;
    }
}

// ---- fully fused: Gram-MFMA sim (barrier-light) -> softmax*spatial -> MFMA fixup
//      -> banded-W7 MFMA aggregate -> output_proj MFMA -> d_out
__global__ __launch_bounds__(1024) void simfixagg_kernel(
    const short* __restrict__ pxt, const float* __restrict__ sigma_p,
    const float* __restrict__ sem,
    const float* __restrict__ fw1, const float* __restrict__ fb1,
    const float* __restrict__ flnw, const float* __restrict__ flnb,
    const float* __restrict__ fw2, const float* __restrict__ fb2,
    const float* __restrict__ spatial,
    const float* __restrict__ ow1, const float* __restrict__ ob1,
    const float* __restrict__ olnw, const float* __restrict__ olnb,
    const float* __restrict__ ow2, const float* __restrict__ ob2,
    float* __restrict__ out)
{
    __shared__ alignas(16) char sBig[7 * WW * CDIM * 2];   // 114,688 B
    __shared__ alignas(16) char sAux[64 * 66 * 4];         //  16,896 B
    __shared__ alignas(16) float sSimWts[DSQ][64];         //  12,544 B: sSim then sWts
    __shared__ alignas(16) float sCmb[DSQ][66];            //  12,936 B

    // Gram phase
    short* rows = reinterpret_cast<short*>(sBig);
    float* sP7  = reinterpret_cast<float*>(sBig);          // [7][64][64] f32 = 114,688
    // fixup overlay
    short* B1   = reinterpret_cast<short*>(sBig);          // [64 px][192]
    short* A1   = reinterpret_cast<short*>(sBig + 24576);  // [64 o ][192]
    short* B2   = reinterpret_cast<short*>(sBig + 49152);  // [64 px][64]
    short* A2   = reinterpret_cast<short*>(sBig + 57344);  // [64 o ][64]
    float* fSem = reinterpret_cast<float*>(sBig + 65536);  // [128][64]
    float* prm  = reinterpret_cast<float*>(sBig + 98304);  // 4 x 64
    // agg overlay: W7 [7][64][72] bf16 (64,512) + S double-buffer
    short* W7   = reinterpret_cast<short*>(sBig);          // 0 .. 64,512
    short* sSa0 = reinterpret_cast<short*>(sBig + 64512);  // [128][64] bf16
    short* sSa1 = reinterpret_cast<short*>(sBig + 80896);  // [128][64] bf16
    // op-proj overlay (after agg; W7/sSa dead)
    short* sWb  = reinterpret_cast<short*>(sBig);                       // 32,768
    short* sXT  = reinterpret_cast<short*>(sBig + 32768);               // 16,384
    float (*sT)[65] = reinterpret_cast<float(*)[65]>(sBig + 49152);     // 33,280

    float (*red1)[65] = reinterpret_cast<float(*)[65]>(sAux);
    float (*red2)[65] = reinterpret_cast<float(*)[65]>(sAux + 16 * 65 * 4);

    const int tid = threadIdx.x;
    const int l = tid & 63;
    const int q = tid >> 6;
    const int qu = __builtin_amdgcn_readfirstlane(q);
    // XCD-bijective swizzle (256 blocks, 8 XCDs): XCD k owns 32 consecutive rows.
    const int lbid = ((blockIdx.x & 7) << 5) | (blockIdx.x >> 3);
    const int b = lbid >> 6;
    const int h = lbid & 63;

    // ---- stage 7 reflected rows, bf16 [row][p][c] swz ----
    for (int idx = tid; idx < 7 * WW * 16; idx += 1024) {
        const int cchunk = idx & 15;
        const int p = (idx >> 4) & 63;
        const int row = idx >> 10;
        const int hp = reflect64(h + row - RR);
        const short8v v = *reinterpret_cast<const short8v*>(
            &pxt[((b * HH + hp) * WW + p) * CDIM + cchunk * 8]);
        *reinterpret_cast<short8v*>(
            &rows[(row * WW + p) * CDIM + ((cchunk * 8) ^ ((p & 7) << 3))]) = v;
    }
    __syncthreads();

    // ---- Gram MFMA: all 7 ki, accumulators live, NO internal barriers ----
    const int lm = l & 15, g = l >> 4;
    const int tm = q >> 2, tn = q & 3;
    const int pa = tm * 16 + lm;
    const int pxb = tn * 16 + lm;
    const int abase = (3 * WW + pa) * CDIM, as_ = (pa & 7) << 3;
    const int bs_ = (pxb & 7) << 3;

    short8v afr[4];
    #pragma unroll
    for (int kk = 0; kk < 4; ++kk)
        afr[kk] = *reinterpret_cast<const short8v*>(
            &rows[abase + ((kk * 32 + g * 8) ^ as_)]);

    float4v gacc[7];
    #pragma unroll
    for (int ki = 0; ki < 7; ++ki) {
        float4v acc = {0.f, 0.f, 0.f, 0.f};
        const int bbase = (ki * WW + pxb) * CDIM;
        #pragma unroll
        for (int kk = 0; kk < 4; ++kk) {
            const short8v bf = *reinterpret_cast<const short8v*>(
                &rows[bbase + ((kk * 32 + g * 8) ^ bs_)]);
            acc = __builtin_amdgcn_mfma_f32_16x16x32_bf16(afr[kk], bf, acc, 0, 0, 0);
        }
        gacc[ki] = acc;
    }
    __syncthreads();               // all rows reads done -> sP7 overlay safe

    #pragma unroll
    for (int ki = 0; ki < 7; ++ki) {
        #pragma unroll
        for (int r = 0; r < 4; ++r)
            sP7[ki * 4096 + (tm * 16 + g * 4 + r) * 64 + pxb] = gacc[ki][r];
    }
    __syncthreads();

    const float rscale = 0.088388347648318447f;  // 1/sqrt(128)
    for (int idx = tid; idx < 7 * 7 * 64; idx += 1024) {
        const int ki = idx / 448;
        const int rem = idx - ki * 448;
        const int kj = rem >> 6, p = rem & 63;
        sSimWts[ki * 7 + kj][p] =
            sP7[ki * 4096 + p * 64 + reflect64(p + kj - RR)] * rscale;
    }
    __syncthreads();
    // sP7 dead -> stage fixup overlays

    // A1: fw1 -> bf16 [64][192]: [0:49]=cmb-cols, [49:64]=0, [64:192]=sem-cols
    for (int idx = tid; idx < 64 * 24; idx += 1024) {
        const int o = idx / 24;
        const int ch0 = (idx % 24) * 8;
        short8v pk;
        #pragma unroll
        for (int j = 0; j < 8; ++j) {
            const int c = ch0 + j;
            float v = 0.f;
            if (o < DSQ) {
                if (c < DSQ) v = fw1[o * 177 + c];
                else if (c >= 64) v = fw1[o * 177 + DSQ + (c - 64)];
            }
            pk[j] = f2bf(v);
        }
        *reinterpret_cast<short8v*>(&A1[o * 192 + (ch0 ^ ((o & 7) << 3))]) = pk;
    }
    // A2: fw2 -> bf16 [64][64], zero-padded
    for (int idx = tid; idx < 64 * 8; idx += 1024) {
        const int o = idx >> 3;
        const int ch0 = (idx & 7) * 8;
        short8v pk;
        #pragma unroll
        for (int j = 0; j < 8; ++j) {
            const int c = ch0 + j;
            pk[j] = (o < DSQ && c < DSQ) ? f2bf(fw2[o * DSQ + c]) : (short)0;
        }
        *reinterpret_cast<short8v*>(&A2[o * 64 + (ch0 ^ ((o & 7) << 3))]) = pk;
    }
    // B2 zero-fill
    {
        const short8v z = {0, 0, 0, 0, 0, 0, 0, 0};
        for (int idx = tid; idx < 64 * 8; idx += 1024)
            *reinterpret_cast<short8v*>(&B2[idx * 8]) = z;
    }
    // B1 pad cols [49..64) zero
    for (int idx = tid; idx < 64 * 15; idx += 1024) {
        const int p = idx / 15, c = DSQ + idx % 15;
        B1[p * 192 + (c ^ ((p & 7) << 3))] = 0;
    }
    // params
    for (int idx = tid; idx < 256; idx += 1024) {
        const int a = idx >> 6, i = idx & 63;
        float v = 0.f;
        if (i < DSQ) {
            if (a == 0) v = fb1[i];
            else if (a == 1) v = flnw[i];
            else if (a == 2) v = flnb[i];
            else v = fb2[i];
        }
        prm[a * 64 + i] = v;
    }
    // fSem f32 [c][p]
    {
        const float* srow = sem + (b * CDIM * HH + h) * WW;
        for (int idx = tid; idx < CDIM * 16; idx += 1024) {
            const int r = idx >> 4, pos = idx & 15;
            *reinterpret_cast<float4*>(&fSem[r * WW + pos * 4]) =
                *reinterpret_cast<const float4*>(&srow[r * HH * WW + pos * 4]);
        }
    }
    // softmax * spatial kernel -> sCmb f32 + B1 cmb-cols bf16
    {
        float rv[DSQ];
        #pragma unroll
        for (int n = 0; n < DSQ; ++n) rv[n] = sSimWts[n][l];
        float m = -1e30f;
        #pragma unroll
        for (int n = 0; n < DSQ; ++n) m = fmaxf(m, rv[n]);
        float ssum = 0.f;
        #pragma unroll
        for (int n = 0; n < DSQ; ++n) ssum += __expf(rv[n] - m);
        const float inv = 1.0f / ssum;
        const float sigma = sigma_p[0];
        const float inv2s2 = 1.0f / (2.0f * sigma * sigma);
        const int swl = (l & 7) << 3;
        #pragma unroll
        for (int k = 0; k < 4; ++k) {
            const int n = q + 16 * k;
            if (n < DSQ) {
                const int ki = n / 7, kj = n % 7;
                const float dx = (float)(ki - 3) * (1.0f / 3.0f);
                const float dy = (float)(kj - 3) * (1.0f / 3.0f);
                const float sk = __expf(-(dx * dx + dy * dy) * inv2s2);
                const float cv = __expf(rv[n] - m) * inv * sk;
                sCmb[n][l] = cv;
                B1[l * 192 + (n ^ swl)] = f2bf(cv);
            }
        }
    }
    __syncthreads();
    // B1 sem-cols: transpose-pack from fSem
    {
        const int c0 = q * 8;
        short8v pk;
        #pragma unroll
        for (int j = 0; j < 8; ++j) pk[j] = f2bf(fSem[(c0 + j) * WW + l]);
        *reinterpret_cast<short8v*>(&B1[l * 192 + ((64 + c0) ^ ((l & 7) << 3))]) = pk;
    }
    __syncthreads();

    // ---- fixup conv1 MFMA ----
    const int oA = tm * 16 + lm;
    const int aswz = (oA & 7) << 3;
    const int p = tn * 16 + lm;
    const int bswz = (p & 7) << 3;

    float4v facc = {0.f, 0.f, 0.f, 0.f};
    #pragma unroll
    for (int kk = 0; kk < 6; ++kk) {
        const int ki = kk * 32 + g * 8;
        const short8v af = *reinterpret_cast<const short8v*>(&A1[oA * 192 + (ki ^ aswz)]);
        const short8v bf = *reinterpret_cast<const short8v*>(&B1[p * 192 + (ki ^ bswz)]);
        facc = __builtin_amdgcn_mfma_f32_16x16x32_bf16(af, bf, facc, 0, 0, 0);
    }
    float vals[4];
    float s1 = 0.f, s2 = 0.f;
    #pragma unroll
    for (int r = 0; r < 4; ++r) {
        const int o = tm * 16 + g * 4 + r;
        const float v = facc[r] + prm[o];
        vals[r] = v;
        if (o < DSQ) { s1 += v; s2 += v * v; }
    }
    red1[tm * 4 + g][p] = s1;
    red2[tm * 4 + g][p] = s2;
    __syncthreads();
    float t1 = 0.f, t2 = 0.f;
    #pragma unroll
    for (int j = 0; j < 16; ++j) { t1 += red1[j][p]; t2 += red2[j][p]; }
    const float mean = t1 * (1.0f / 49.0f);
    const float var  = t2 * (1.0f / 49.0f) - mean * mean;
    const float rstd = rsqrtf(var + 1e-6f);
    #pragma unroll
    for (int r = 0; r < 4; ++r) {
        const int o = tm * 16 + g * 4 + r;
        if (o < DSQ) {
            const float v = (vals[r] - mean) * rstd * prm[64 + o] + prm[128 + o];
            const float sv = v * sigm(v);
            B2[p * 64 + (o ^ bswz)] = f2bf(sv);
        }
    }
    __syncthreads();

    // ---- fixup conv2 MFMA + gate + normalize -> sWts (LDS) ----
    float4v facc2 = {0.f, 0.f, 0.f, 0.f};
    #pragma unroll
    for (int kk = 0; kk < 2; ++kk) {
        const int ki = kk * 32 + g * 8;
        const short8v af = *reinterpret_cast<const short8v*>(&A2[oA * 64 + (ki ^ aswz)]);
        const short8v bf = *reinterpret_cast<const short8v*>(&B2[p * 64 + (ki ^ bswz)]);
        facc2 = __builtin_amdgcn_mfma_f32_16x16x32_bf16(af, bf, facc2, 0, 0, 0);
    }
    float c2v[4];
    float ps = 0.f;
    #pragma unroll
    for (int r = 0; r < 4; ++r) {
        const int o = tm * 16 + g * 4 + r;
        if (o < DSQ) {
            const float f = facc2[r] + prm[192 + o];
            c2v[r] = sCmb[o][p] * (1.0f + sigm(f));
            ps += c2v[r];
        } else c2v[r] = 0.f;
    }
    red1[tm * 4 + g][p] = ps;
    __syncthreads();
    float tot = 0.f;
    #pragma unroll
    for (int j = 0; j < 16; ++j) tot += red1[j][p];
    const float invt = 1.0f / (tot + 1e-7f);
    #pragma unroll
    for (int r = 0; r < 4; ++r) {
        const int o = tm * 16 + g * 4 + r;
        if (o < DSQ) sSimWts[o][p] = c2v[r] * invt;   // sSim region reused as sWts
    }
    __syncthreads();   // wts ready; fixup buffers dead

    // ---- aggregate: build all 7 banded W in parallel; S rows double-buffered ----
    const float* sb = spatial + b * CDIM * HH * WW;
    float4 sreg[2];
    #define LD_SROW(KI)                                                          \
        { const int hp_ = reflect64(h + (KI) - RR);                              \
          _Pragma("unroll")                                                      \
          for (int j = 0; j < 2; ++j) {                                          \
              const int idx = tid * 2 + j;                                       \
              const int c = idx >> 4, pos = idx & 15;                            \
              sreg[j] = *reinterpret_cast<const float4*>(                        \
                  &sb[(c * HH + hp_) * WW + pos * 4]);                           \
          } }
    #define ST_SROW(DST)                                                         \
        { _Pragma("unroll")                                                      \
          for (int j = 0; j < 2; ++j) {                                          \
              const int idx = tid * 2 + j;                                       \
              const int c = idx >> 4, pos = idx & 15;                            \
              const int sw_ = (c & 7) << 3;                                      \
              short4v pk;                                                        \
              _Pragma("unroll")                                                  \
              for (int m = 0; m < 4; ++m) pk[m] = f2bf(((const float*)&sreg[j])[m]); \
              *reinterpret_cast<short4v*>(&(DST)[c * 64 + ((pos * 4) ^ sw_)]) = pk;  \
          } }

    LD_SROW(0);
    if (tid < 448) {   // 7 waves: wave k builds W7[k]; each thread owns one 72-short row
        const int kin = tid >> 6, pp_ = tid & 63;
        const int s_ = (pp_ > 3) ? (pp_ - 3) : 0;
        float col[7] = {0.f, 0.f, 0.f, 0.f, 0.f, 0.f, 0.f};
        #pragma unroll
        for (int kj = 0; kj < 7; ++kj) {
            const int pr = reflect64(pp_ + kj - RR);
            const float wv_ = sSimWts[kin * 7 + kj][pp_];
            const int id_ = pr - s_;
            #pragma unroll
            for (int jj = 0; jj < 7; ++jj) if (id_ == jj) col[jj] += wv_;
        }
        short* wrow = &W7[(kin * 64 + pp_) * 72];
        const short8v z8 = {0, 0, 0, 0, 0, 0, 0, 0};
        #pragma unroll
        for (int j8 = 0; j8 < 9; ++j8)
            *reinterpret_cast<short8v*>(&wrow[j8 * 8]) = z8;
        #pragma unroll
        for (int jj = 0; jj < 7; ++jj) {
            const int pr = s_ + jj;
            if (pr < 64) wrow[pr] = f2bf(col[jj]);
        }
    }
    ST_SROW(sSa0);
    __syncthreads();

    // agg GEMM: M=128 (c), N=64 (p). wave q: tmA=q>>1, N-tiles (q&1)*2 +{0,1}
    const int tmA = q >> 1;
    const int oaA = tmA * 16 + lm;
    const int arA = oaA * 64, aswA = (oaA & 7) << 3;
    const int pA0 = ((q & 1) * 2) * 16 + lm, pA1 = ((q & 1) * 2 + 1) * 16 + lm;

    float4v ag0 = {0.f, 0.f, 0.f, 0.f}, ag1 = {0.f, 0.f, 0.f, 0.f};
    for (int ki = 0; ki < 7; ++ki) {
        if (ki < 6) LD_SROW(ki + 1);
        const short* Sc = (ki & 1) ? sSa1 : sSa0;
        const short* Wc = &W7[ki * 64 * 72];
        #pragma unroll
        for (int kk = 0; kk < 2; ++kk) {
            const int k0 = kk * 32 + g * 8;
            const short8v a8 = *reinterpret_cast<const short8v*>(&Sc[arA + (k0 ^ aswA)]);
            const short8v b80 = *reinterpret_cast<const short8v*>(&Wc[pA0 * 72 + k0]);
            const short8v b81 = *reinterpret_cast<const short8v*>(&Wc[pA1 * 72 + k0]);
            ag0 = __builtin_amdgcn_mfma_f32_16x16x32_bf16(a8, b80, ag0, 0, 0, 0);
            ag1 = __builtin_amdgcn_mfma_f32_16x16x32_bf16(a8, b81, ag1, 0, 0, 0);
        }
        if (ki < 6) { ST_SROW(((ki & 1) ? sSa0 : sSa1)); }   // write next buffer
        __syncthreads();
    }
    #undef LD_SROW
    #undef ST_SROW

    // write agg result as bf16 op-proj B operand sXT[p][c]; stage op_w1 -> sWb
    {
        #pragma unroll
        for (int r = 0; r < 4; ++r) {
            const int c = tmA * 16 + g * 4 + r;
            sXT[pA0 * 128 + (c ^ ((pA0 & 7) << 3))] = f2bf(ag0[r]);
            sXT[pA1 * 128 + (c ^ ((pA1 & 7) << 3))] = f2bf(ag1[r]);
        }
    }
    {
        const int o = tid >> 3;
        const int i0 = (tid & 7) * 16;
        const int sw = (o & 7) << 3;
        const float* src = ow1 + o * CDIM + i0;
        short8v pk0, pk1;
        #pragma unroll
        for (int j = 0; j < 8; ++j) pk0[j] = f2bf(src[j]);
        #pragma unroll
        for (int j = 0; j < 8; ++j) pk1[j] = f2bf(src[8 + j]);
        *reinterpret_cast<short8v*>(&sWb[o * 128 + (i0 ^ sw)]) = pk0;
        *reinterpret_cast<short8v*>(&sWb[o * 128 + ((i0 + 8) ^ sw)]) = pk1;
    }
    __syncthreads();

    // ---- output_proj conv1 MFMA ----
    const int tmo = q >> 1;
    const int tn0 = (q & 1) * 2;
    const int oaop = tmo * 16 + lm;
    const int arow = oaop * 128, asw = (oaop & 7) << 3;
    const int p0 = tn0 * 16 + lm, p1 = (tn0 + 1) * 16 + lm;
    const int bsw0 = (p0 & 7) << 3, bsw1 = (p1 & 7) << 3;

    {
        float4v a0 = {0.f, 0.f, 0.f, 0.f}, a1 = {0.f, 0.f, 0.f, 0.f};
        #pragma unroll
        for (int kk = 0; kk < 4; ++kk) {
            const int ki = kk * 32 + g * 8;
            const short8v af = *reinterpret_cast<const short8v*>(&sWb[arow + (ki ^ asw)]);
            const short8v bf0 = *reinterpret_cast<const short8v*>(&sXT[p0 * 128 + (ki ^ bsw0)]);
            const short8v bf1 = *reinterpret_cast<const short8v*>(&sXT[p1 * 128 + (ki ^ bsw1)]);
            a0 = __builtin_amdgcn_mfma_f32_16x16x32_bf16(af, bf0, a0, 0, 0, 0);
            a1 = __builtin_amdgcn_mfma_f32_16x16x32_bf16(af, bf1, a1, 0, 0, 0);
        }
        __syncthreads();      // sSa region free for sT; conv1 reads complete
        #pragma unroll
        for (int r = 0; r < 4; ++r) sT[tmo * 16 + g * 4 + r][p0] = a0[r];
        #pragma unroll
        for (int r = 0; r < 4; ++r) sT[tmo * 16 + g * 4 + r][p1] = a1[r];
    }
    __syncthreads();

    // restage sWb = op_w2; bias + LN(128) -> sXT (reused as conv2 B operand)
    {
        const int o = tid >> 3;
        const int i0 = (tid & 7) * 16;
        const int sw = (o & 7) << 3;
        const float* src = ow2 + o * CDIM + i0;
        short8v pk0, pk1;
        #pragma unroll
        for (int j = 0; j < 8; ++j) pk0[j] = f2bf(src[j]);
        #pragma unroll
        for (int j = 0; j < 8; ++j) pk1[j] = f2bf(src[8 + j]);
        *reinterpret_cast<short8v*>(&sWb[o * 128 + (i0 ^ sw)]) = pk0;
        *reinterpret_cast<short8v*>(&sWb[o * 128 + ((i0 + 8) ^ sw)]) = pk1;
    }
    {
        float vals2[8];
        float u1 = 0.f, u2 = 0.f;
        #pragma unroll
        for (int j = 0; j < 8; ++j) {
            const float v = sT[qu * 8 + j][l] + ob1[qu * 8 + j];
            vals2[j] = v; u1 += v; u2 += v * v;
        }
        red1[q][l] = u1; red2[q][l] = u2;
        __syncthreads();
        float v1 = 0.f, v2 = 0.f;
        #pragma unroll
        for (int j = 0; j < 16; ++j) { v1 += red1[j][l]; v2 += red2[j][l]; }
        const float mn = v1 * (1.0f / 128.0f);
        const float vr = v2 * (1.0f / 128.0f) - mn * mn;
        const float rs = rsqrtf(vr + 1e-6f);
        short8v pk;
        #pragma unroll
        for (int j = 0; j < 8; ++j) {
            const float v = (vals2[j] - mn) * rs * olnw[qu * 8 + j] + olnb[qu * 8 + j];
            pk[j] = f2bf(v);
        }
        *reinterpret_cast<short8v*>(&sXT[l * 128 + ((qu * 8) ^ ((l & 7) << 3))]) = pk;
    }
    __syncthreads();

    // ---- output_proj conv2 MFMA + bias -> out ----
    {
        float4v a0 = {0.f, 0.f, 0.f, 0.f}, a1 = {0.f, 0.f, 0.f, 0.f};
        #pragma unroll
        for (int kk = 0; kk < 4; ++kk) {
            const int ki = kk * 32 + g * 8;
            const short8v af = *reinterpret_cast<const short8v*>(&sWb[arow + (ki ^ asw)]);
            const short8v bf0 = *reinterpret_cast<const short8v*>(&sXT[p0 * 128 + (ki ^ bsw0)]);
            const short8v bf1 = *reinterpret_cast<const short8v*>(&sXT[p1 * 128 + (ki ^ bsw1)]);
            a0 = __builtin_amdgcn_mfma_f32_16x16x32_bf16(af, bf0, a0, 0, 0, 0);
            a1 = __builtin_amdgcn_mfma_f32_16x16x32_bf16(af, bf1, a1, 0, 0, 0);
        }
        const float4 bv = *reinterpret_cast<const float4*>(&ob2[tmo * 16 + g * 4]);
        float* obase = out + (b * CDIM * HH + h) * WW;
        #pragma unroll
        for (int r = 0; r < 4; ++r) {
            const float bias = ((const float*)&bv)[r];
            obase[(tmo * 16 + g * 4 + r) * HH * WW + p0] = a0[r] + bias;
            obase[(tmo * 16 + g * 4 + r) * HH * WW + p1] = a1[r] + bias;
        }
    }
}

extern "C" void kernel_launch(void* const* d_in, const int* in_sizes, int n_in,
                              void* d_out, int out_size, void* d_ws, size_t ws_size,
                              hipStream_t stream) {
    (void)in_sizes; (void)n_in; (void)out_size; (void)ws_size;
    const float* spatial  = (const float*)d_in[0];
    const float* semantic = (const float*)d_in[1];
    const float* rp_w1 = (const float*)d_in[2];
    const float* rp_b1 = (const float*)d_in[3];
    const float* rp_lnw = (const float*)d_in[4];
    const float* rp_lnb = (const float*)d_in[5];
    const float* rp_w2 = (const float*)d_in[6];
    const float* rp_b2 = (const float*)d_in[7];
    const float* fx_w1 = (const float*)d_in[8];
    const float* fx_b1 = (const float*)d_in[9];
    const float* fx_lnw = (const float*)d_in[10];
    const float* fx_lnb = (const float*)d_in[11];
    const float* fx_w2 = (const float*)d_in[12];
    const float* fx_b2 = (const float*)d_in[13];
    const float* sigma = (const float*)d_in[14];
    const float* op_w1 = (const float*)d_in[15];
    const float* op_b1 = (const float*)d_in[16];
    const float* op_lnw = (const float*)d_in[17];
    const float* op_lnb = (const float*)d_in[18];
    const float* op_w2 = (const float*)d_in[19];
    const float* op_b2 = (const float*)d_in[20];

    char* wsb = (char*)d_ws;
    short* pxt  = (short*)wsb;                   // 4 MB bf16 [b][h][p][c]
    float* outp = (float*)d_out;

    dim3 grid(BB * HH), blk(1024);
    proj_kernel<true><<<grid, blk, 0, stream>>>(semantic, rp_w1, rp_b1, rp_lnw, rp_lnb,
                                                rp_w2, rp_b2, pxt);
    simfixagg_kernel<<<grid, blk, 0, stream>>>(pxt, sigma, semantic,
                                               fx_w1, fx_b1, fx_lnw, fx_lnb, fx_w2, fx_b2,
                                               spatial,
                                               op_w1, op_b1, op_lnw, op_lnb, op_w2, op_b2,
                                               outp);
}

// Round 19
// 48.239 us; speedup vs baseline: 1.4412x; 1.0006x over previous
//
#include <hip/hip_runtime.h>
#include <cstdint>

#define BB 4
#define CDIM 128
#define HH 64
#define WW 64
#define RR 3
#define DD 7
#define DSQ 49

typedef __attribute__((ext_vector_type(8))) short short8v;   // 8 bf16 = 4 VGPR
typedef __attribute__((ext_vector_type(4))) short short4v;   // 4 bf16 = 2 VGPR
typedef __attribute__((ext_vector_type(4))) float float4v;

__device__ __forceinline__ int reflect64(int p) {
    p = (p < 0) ? -p : p;
    return (p > 63) ? (126 - p) : p;
}
__device__ __forceinline__ float sigm(float x) { return 1.0f / (1.0f + __expf(-x)); }
__device__ __forceinline__ short f2bf(float f) {     // f32 -> bf16 RNE
    uint32_t u = __float_as_uint(f);
    u += 0x7FFF + ((u >> 16) & 1);
    return (short)(u >> 16);
}

// ---- range_proj: conv1x1 -> LN -> SiLU -> conv1x1 via bf16 MFMA.
// Output: bf16 TRANSPOSED [b][h][p][c].
template<bool SILU>
__global__ __launch_bounds__(1024) void proj_kernel(
    const float* __restrict__ x, const float* __restrict__ w1,
    const float* __restrict__ b1, const float* __restrict__ lnw,
    const float* __restrict__ lnb, const float* __restrict__ w2,
    const float* __restrict__ b2, short* __restrict__ outT)
{
    __shared__ short sW1[CDIM * CDIM];
    __shared__ short sW2[CDIM * CDIM];
    __shared__ short sXT[WW * CDIM];
    __shared__ short sXT2[WW * CDIM];
    __shared__ float sT[CDIM][65];
    __shared__ float red1[16][WW];
    __shared__ float red2[16][WW];

    const int tid = threadIdx.x;
    const int l = tid & 63;
    const int q = tid >> 6;
    const int qu = __builtin_amdgcn_readfirstlane(q);
    const int b = blockIdx.x >> 6;
    const int h = blockIdx.x & 63;

    {
        const int o = tid >> 3;
        const int i0 = (tid & 7) * 16;
        const int sw = (o & 7) << 3;
        const float* wsrc[2] = {w1, w2};
        short* wdst[2] = {sW1, sW2};
        #pragma unroll
        for (int m = 0; m < 2; ++m) {
            const float* src = wsrc[m] + o * CDIM + i0;
            short8v pk0, pk1;
            #pragma unroll
            for (int j = 0; j < 8; ++j) pk0[j] = f2bf(src[j]);
            #pragma unroll
            for (int j = 0; j < 8; ++j) pk1[j] = f2bf(src[8 + j]);
            *reinterpret_cast<short8v*>(&wdst[m][o * 128 + (i0 ^ sw)]) = pk0;
            *reinterpret_cast<short8v*>(&wdst[m][o * 128 + ((i0 + 8) ^ sw)]) = pk1;
        }
    }
    {
        const int pos = tid & 15;
        const int c0 = tid >> 4;
        const float* xrow = x + (b * CDIM * HH + h) * WW;
        #pragma unroll
        for (int rr = 0; rr < 2; ++rr) {
            const int c = c0 + rr * 64;
            const float4 v = *reinterpret_cast<const float4*>(&xrow[c * HH * WW + pos * 4]);
            #pragma unroll
            for (int m = 0; m < 4; ++m) {
                const int p = pos * 4 + m;
                sXT[p * 128 + (c ^ ((p & 7) << 3))] = f2bf(((const float*)&v)[m]);
            }
        }
    }
    __syncthreads();

    const int lm = l & 15, g = l >> 4;
    const int tm = q >> 1;
    const int tn0 = (q & 1) * 2;
    const int oa = tm * 16 + lm;
    const int arow = oa * 128, asw = (oa & 7) << 3;
    const int p0 = tn0 * 16 + lm, p1 = (tn0 + 1) * 16 + lm;
    const int bsw0 = (p0 & 7) << 3, bsw1 = (p1 & 7) << 3;

    float4v acc0 = {0.f, 0.f, 0.f, 0.f}, acc1 = {0.f, 0.f, 0.f, 0.f};
    #pragma unroll
    for (int kk = 0; kk < 4; ++kk) {
        const int ki = kk * 32 + g * 8;
        const short8v af = *reinterpret_cast<const short8v*>(&sW1[arow + (ki ^ asw)]);
        const short8v bf0 = *reinterpret_cast<const short8v*>(&sXT[p0 * 128 + (ki ^ bsw0)]);
        const short8v bf1 = *reinterpret_cast<const short8v*>(&sXT[p1 * 128 + (ki ^ bsw1)]);
        acc0 = __builtin_amdgcn_mfma_f32_16x16x32_bf16(af, bf0, acc0, 0, 0, 0);
        acc1 = __builtin_amdgcn_mfma_f32_16x16x32_bf16(af, bf1, acc1, 0, 0, 0);
    }
    #pragma unroll
    for (int r = 0; r < 4; ++r) sT[tm * 16 + g * 4 + r][p0] = acc0[r];
    #pragma unroll
    for (int r = 0; r < 4; ++r) sT[tm * 16 + g * 4 + r][p1] = acc1[r];
    __syncthreads();

    {
        const int p = l;
        float vals[8];
        float s1 = 0.f, s2 = 0.f;
        #pragma unroll
        for (int j = 0; j < 8; ++j) {
            const float v = sT[qu * 8 + j][p] + b1[qu * 8 + j];
            vals[j] = v; s1 += v; s2 += v * v;
        }
        red1[q][p] = s1; red2[q][p] = s2;
        __syncthreads();
        float t1 = 0.f, t2 = 0.f;
        #pragma unroll
        for (int j = 0; j < 16; ++j) { t1 += red1[j][p]; t2 += red2[j][p]; }
        const float mean = t1 * (1.0f / 128.0f);
        const float var  = t2 * (1.0f / 128.0f) - mean * mean;
        const float rstd = rsqrtf(var + 1e-6f);
        short8v pk;
        #pragma unroll
        for (int j = 0; j < 8; ++j) {
            float v = (vals[j] - mean) * rstd * lnw[qu * 8 + j] + lnb[qu * 8 + j];
            if (SILU) v = v * sigm(v);
            pk[j] = f2bf(v);
        }
        *reinterpret_cast<short8v*>(&sXT2[p * 128 + ((qu * 8) ^ ((p & 7) << 3))]) = pk;
    }
    __syncthreads();

    {
        float4v a0 = {0.f, 0.f, 0.f, 0.f}, a1 = {0.f, 0.f, 0.f, 0.f};
        #pragma unroll
        for (int kk = 0; kk < 4; ++kk) {
            const int ki = kk * 32 + g * 8;
            const short8v af = *reinterpret_cast<const short8v*>(&sW2[arow + (ki ^ asw)]);
            const short8v bf0 = *reinterpret_cast<const short8v*>(&sXT2[p0 * 128 + (ki ^ bsw0)]);
            const short8v bf1 = *reinterpret_cast<const short8v*>(&sXT2[p1 * 128 + (ki ^ bsw1)]);
            a0 = __builtin_amdgcn_mfma_f32_16x16x32_bf16(af, bf0, a0, 0, 0, 0);
            a1 = __builtin_amdgcn_mfma_f32_16x16x32_bf16(af, bf1, a1, 0, 0, 0);
        }
        const float4 bv = *reinterpret_cast<const float4*>(&b2[tm * 16 + g * 4]);
        #pragma unroll
        for (int r = 0; r < 4; ++r) {
            const float bias = ((const float*)&bv)[r];
            sT[tm * 16 + g * 4 + r][p0] = a0[r] + bias;
            sT[tm * 16 + g * 4 + r][p1] = a1[r] + bias;
        }
    }
    __syncthreads();
    {
        const int p = tid >> 4;
        const int c0 = (tid & 15) * 8;
        short8v pk;
        #pragma unroll
        for (int j = 0; j < 8; ++j) pk[j] = f2bf(sT[c0 + j][p]);
        *reinterpret_cast<short8v*>(&outT[((b * HH + h) * WW + p) * CDIM + c0]) = pk;
    }
}

// ---- fully fused: Gram-MFMA sim (T14 weight prefetch in flight) -> softmax*spatial
//      -> MFMA fixup -> banded-W7 MFMA aggregate -> output_proj MFMA -> d_out
__global__ __launch_bounds__(1024) void simfixagg_kernel(
    const short* __restrict__ pxt, const float* __restrict__ sigma_p,
    const float* __restrict__ sem,
    const float* __restrict__ fw1, const float* __restrict__ fb1,
    const float* __restrict__ flnw, const float* __restrict__ flnb,
    const float* __restrict__ fw2, const float* __restrict__ fb2,
    const float* __restrict__ spatial,
    const float* __restrict__ ow1, const float* __restrict__ ob1,
    const float* __restrict__ olnw, const float* __restrict__ olnb,
    const float* __restrict__ ow2, const float* __restrict__ ob2,
    float* __restrict__ out)
{
    __shared__ alignas(16) char sBig[7 * WW * CDIM * 2];   // 114,688 B
    __shared__ alignas(16) char sAux[64 * 66 * 4];         //  16,896 B
    __shared__ alignas(16) float sSimWts[DSQ][64];         //  12,544 B: sSim then sWts
    __shared__ alignas(16) float sCmb[DSQ][66];            //  12,936 B

    // Gram phase
    short* rows = reinterpret_cast<short*>(sBig);
    float* sP7  = reinterpret_cast<float*>(sBig);          // [7][64][64] f32 = 114,688
    // fixup overlay
    short* B1   = reinterpret_cast<short*>(sBig);          // [64 px][192]
    short* A1   = reinterpret_cast<short*>(sBig + 24576);  // [64 o ][192]
    short* B2   = reinterpret_cast<short*>(sBig + 49152);  // [64 px][64]
    short* A2   = reinterpret_cast<short*>(sBig + 57344);  // [64 o ][64]
    float* fSem = reinterpret_cast<float*>(sBig + 65536);  // [128][64]
    float* prm  = reinterpret_cast<float*>(sBig + 98304);  // 4 x 64
    // agg overlay: W7 [7][64][72] bf16 (64,512) + S double-buffer
    short* W7   = reinterpret_cast<short*>(sBig);          // 0 .. 64,512
    short* sSa0 = reinterpret_cast<short*>(sBig + 64512);  // [128][64] bf16
    short* sSa1 = reinterpret_cast<short*>(sBig + 80896);  // [128][64] bf16
    // op-proj overlay (after agg; W7/sSa dead)
    short* sWb  = reinterpret_cast<short*>(sBig);                       // 32,768
    short* sXT  = reinterpret_cast<short*>(sBig + 32768);               // 16,384
    float (*sT)[65] = reinterpret_cast<float(*)[65]>(sBig + 49152);     // 33,280

    float (*red1)[65] = reinterpret_cast<float(*)[65]>(sAux);
    float (*red2)[65] = reinterpret_cast<float(*)[65]>(sAux + 16 * 65 * 4);

    const int tid = threadIdx.x;
    const int l = tid & 63;
    const int q = tid >> 6;
    const int qu = __builtin_amdgcn_readfirstlane(q);
    // XCD-bijective swizzle (256 blocks, 8 XCDs): XCD k owns 32 consecutive rows.
    const int lbid = ((blockIdx.x & 7) << 5) | (blockIdx.x >> 3);
    const int b = lbid >> 6;
    const int h = lbid & 63;

    // ---- stage 7 reflected rows, bf16 [row][p][c] swz ----
    for (int idx = tid; idx < 7 * WW * 16; idx += 1024) {
        const int cchunk = idx & 15;
        const int p = (idx >> 4) & 63;
        const int row = idx >> 10;
        const int hp = reflect64(h + row - RR);
        const short8v v = *reinterpret_cast<const short8v*>(
            &pxt[((b * HH + hp) * WW + p) * CDIM + cchunk * 8]);
        *reinterpret_cast<short8v*>(
            &rows[(row * WW + p) * CDIM + ((cchunk * 8) ^ ((p & 7) << 3))]) = v;
    }

    // ---- T14: prefetch fixup weights + sem into registers (fly during Gram) ----
    float a1r[2][8];
    #pragma unroll
    for (int it = 0; it < 2; ++it) {
        const int idx = tid + it * 1024;
        const int o = idx / 24;
        const int ch0 = (idx % 24) * 8;
        #pragma unroll
        for (int j = 0; j < 8; ++j) {
            const int c = ch0 + j;
            float v = 0.f;
            if (idx < 64 * 24 && o < DSQ) {
                if (c < DSQ) v = fw1[o * 177 + c];
                else if (c >= 64) v = fw1[o * 177 + DSQ + (c - 64)];
            }
            a1r[it][j] = v;
        }
    }
    float a2r[8];
    {
        #pragma unroll
        for (int j = 0; j < 8; ++j) a2r[j] = 0.f;
        if (tid < 512) {
            const int o = tid >> 3;
            const int ch0 = (tid & 7) * 8;
            #pragma unroll
            for (int j = 0; j < 8; ++j) {
                const int c = ch0 + j;
                if (o < DSQ && c < DSQ) a2r[j] = fw2[o * DSQ + c];
            }
        }
    }
    float prmr = 0.f;
    if (tid < 256) {
        const int a = tid >> 6, i = tid & 63;
        if (i < DSQ) {
            if (a == 0) prmr = fb1[i];
            else if (a == 1) prmr = flnw[i];
            else if (a == 2) prmr = flnb[i];
            else prmr = fb2[i];
        }
    }
    float4 semr[2];
    {
        const float* srow = sem + (b * CDIM * HH + h) * WW;
        #pragma unroll
        for (int it = 0; it < 2; ++it) {
            const int idx = tid + it * 1024;     // CDIM*16 = 2048 total
            const int r = idx >> 4, pos = idx & 15;
            semr[it] = *reinterpret_cast<const float4*>(&srow[r * HH * WW + pos * 4]);
        }
    }
    __syncthreads();

    // ---- Gram MFMA: all 7 ki, accumulators live, NO internal barriers ----
    const int lm = l & 15, g = l >> 4;
    const int tm = q >> 2, tn = q & 3;
    const int pa = tm * 16 + lm;
    const int pxb = tn * 16 + lm;
    const int abase = (3 * WW + pa) * CDIM, as_ = (pa & 7) << 3;
    const int bs_ = (pxb & 7) << 3;

    short8v afr[4];
    #pragma unroll
    for (int kk = 0; kk < 4; ++kk)
        afr[kk] = *reinterpret_cast<const short8v*>(
            &rows[abase + ((kk * 32 + g * 8) ^ as_)]);

    float4v gacc[7];
    #pragma unroll
    for (int ki = 0; ki < 7; ++ki) {
        float4v acc = {0.f, 0.f, 0.f, 0.f};
        const int bbase = (ki * WW + pxb) * CDIM;
        #pragma unroll
        for (int kk = 0; kk < 4; ++kk) {
            const short8v bf = *reinterpret_cast<const short8v*>(
                &rows[bbase + ((kk * 32 + g * 8) ^ bs_)]);
            acc = __builtin_amdgcn_mfma_f32_16x16x32_bf16(afr[kk], bf, acc, 0, 0, 0);
        }
        gacc[ki] = acc;
    }
    __syncthreads();               // all rows reads done -> sP7 overlay safe

    #pragma unroll
    for (int ki = 0; ki < 7; ++ki) {
        #pragma unroll
        for (int r = 0; r < 4; ++r)
            sP7[ki * 4096 + (tm * 16 + g * 4 + r) * 64 + pxb] = gacc[ki][r];
    }
    __syncthreads();

    const float rscale = 0.088388347648318447f;  // 1/sqrt(128)
    for (int idx = tid; idx < 7 * 7 * 64; idx += 1024) {
        const int ki = idx / 448;
        const int rem = idx - ki * 448;
        const int kj = rem >> 6, p = rem & 63;
        sSimWts[ki * 7 + kj][p] =
            sP7[ki * 4096 + p * 64 + reflect64(p + kj - RR)] * rscale;
    }
    __syncthreads();
    // sP7 dead -> commit prefetched regs into fixup overlays

    #pragma unroll
    for (int it = 0; it < 2; ++it) {
        const int idx = tid + it * 1024;
        if (idx < 64 * 24) {
            const int o = idx / 24;
            const int ch0 = (idx % 24) * 8;
            short8v pk;
            #pragma unroll
            for (int j = 0; j < 8; ++j) pk[j] = f2bf(a1r[it][j]);
            *reinterpret_cast<short8v*>(&A1[o * 192 + (ch0 ^ ((o & 7) << 3))]) = pk;
        }
    }
    if (tid < 512) {
        const int o = tid >> 3;
        const int ch0 = (tid & 7) * 8;
        short8v pk;
        #pragma unroll
        for (int j = 0; j < 8; ++j) pk[j] = f2bf(a2r[j]);
        *reinterpret_cast<short8v*>(&A2[o * 64 + (ch0 ^ ((o & 7) << 3))]) = pk;
    }
    if (tid >= 512 && tid < 1024) {   // B2 zero-fill (distinct threads from A2 write)
        const short8v z = {0, 0, 0, 0, 0, 0, 0, 0};
        *reinterpret_cast<short8v*>(&B2[(tid - 512) * 8]) = z;
    }
    if (tid < 256) prm[tid] = prmr;
    #pragma unroll
    for (int it = 0; it < 2; ++it) {
        const int idx = tid + it * 1024;
        const int r = idx >> 4, pos = idx & 15;
        *reinterpret_cast<float4*>(&fSem[r * WW + pos * 4]) = semr[it];
    }
    // B1 pad cols [49..64) zero
    for (int idx = tid; idx < 64 * 15; idx += 1024) {
        const int p = idx / 15, c = DSQ + idx % 15;
        B1[p * 192 + (c ^ ((p & 7) << 3))] = 0;
    }
    // softmax * spatial kernel -> sCmb f32 + B1 cmb-cols bf16
    {
        float rv[DSQ];
        #pragma unroll
        for (int n = 0; n < DSQ; ++n) rv[n] = sSimWts[n][l];
        float m = -1e30f;
        #pragma unroll
        for (int n = 0; n < DSQ; ++n) m = fmaxf(m, rv[n]);
        float ssum = 0.f;
        #pragma unroll
        for (int n = 0; n < DSQ; ++n) ssum += __expf(rv[n] - m);
        const float inv = 1.0f / ssum;
        const float sigma = sigma_p[0];
        const float inv2s2 = 1.0f / (2.0f * sigma * sigma);
        const int swl = (l & 7) << 3;
        #pragma unroll
        for (int k = 0; k < 4; ++k) {
            const int n = q + 16 * k;
            if (n < DSQ) {
                const int ki = n / 7, kj = n % 7;
                const float dx = (float)(ki - 3) * (1.0f / 3.0f);
                const float dy = (float)(kj - 3) * (1.0f / 3.0f);
                const float sk = __expf(-(dx * dx + dy * dy) * inv2s2);
                const float cv = __expf(rv[n] - m) * inv * sk;
                sCmb[n][l] = cv;
                B1[l * 192 + (n ^ swl)] = f2bf(cv);
            }
        }
    }
    __syncthreads();
    // B1 sem-cols: transpose-pack from fSem
    {
        const int c0 = q * 8;
        short8v pk;
        #pragma unroll
        for (int j = 0; j < 8; ++j) pk[j] = f2bf(fSem[(c0 + j) * WW + l]);
        *reinterpret_cast<short8v*>(&B1[l * 192 + ((64 + c0) ^ ((l & 7) << 3))]) = pk;
    }
    __syncthreads();

    // ---- fixup conv1 MFMA ----
    const int oA = tm * 16 + lm;
    const int aswz = (oA & 7) << 3;
    const int p = tn * 16 + lm;
    const int bswz = (p & 7) << 3;

    float4v facc = {0.f, 0.f, 0.f, 0.f};
    #pragma unroll
    for (int kk = 0; kk < 6; ++kk) {
        const int ki = kk * 32 + g * 8;
        const short8v af = *reinterpret_cast<const short8v*>(&A1[oA * 192 + (ki ^ aswz)]);
        const short8v bf = *reinterpret_cast<const short8v*>(&B1[p * 192 + (ki ^ bswz)]);
        facc = __builtin_amdgcn_mfma_f32_16x16x32_bf16(af, bf, facc, 0, 0, 0);
    }
    float vals[4];
    float s1 = 0.f, s2 = 0.f;
    #pragma unroll
    for (int r = 0; r < 4; ++r) {
        const int o = tm * 16 + g * 4 + r;
        const float v = facc[r] + prm[o];
        vals[r] = v;
        if (o < DSQ) { s1 += v; s2 += v * v; }
    }
    red1[tm * 4 + g][p] = s1;
    red2[tm * 4 + g][p] = s2;
    __syncthreads();
    float t1 = 0.f, t2 = 0.f;
    #pragma unroll
    for (int j = 0; j < 16; ++j) { t1 += red1[j][p]; t2 += red2[j][p]; }
    const float mean = t1 * (1.0f / 49.0f);
    const float var  = t2 * (1.0f / 49.0f) - mean * mean;
    const float rstd = rsqrtf(var + 1e-6f);
    #pragma unroll
    for (int r = 0; r < 4; ++r) {
        const int o = tm * 16 + g * 4 + r;
        if (o < DSQ) {
            const float v = (vals[r] - mean) * rstd * prm[64 + o] + prm[128 + o];
            const float sv = v * sigm(v);
            B2[p * 64 + (o ^ bswz)] = f2bf(sv);
        }
    }
    __syncthreads();

    // ---- fixup conv2 MFMA + gate + normalize -> sWts (LDS) ----
    float4v facc2 = {0.f, 0.f, 0.f, 0.f};
    #pragma unroll
    for (int kk = 0; kk < 2; ++kk) {
        const int ki = kk * 32 + g * 8;
        const short8v af = *reinterpret_cast<const short8v*>(&A2[oA * 64 + (ki ^ aswz)]);
        const short8v bf = *reinterpret_cast<const short8v*>(&B2[p * 64 + (ki ^ bswz)]);
        facc2 = __builtin_amdgcn_mfma_f32_16x16x32_bf16(af, bf, facc2, 0, 0, 0);
    }
    float c2v[4];
    float ps = 0.f;
    #pragma unroll
    for (int r = 0; r < 4; ++r) {
        const int o = tm * 16 + g * 4 + r;
        if (o < DSQ) {
            const float f = facc2[r] + prm[192 + o];
            c2v[r] = sCmb[o][p] * (1.0f + sigm(f));
            ps += c2v[r];
        } else c2v[r] = 0.f;
    }
    red1[tm * 4 + g][p] = ps;
    __syncthreads();
    float tot = 0.f;
    #pragma unroll
    for (int j = 0; j < 16; ++j) tot += red1[j][p];
    const float invt = 1.0f / (tot + 1e-7f);
    #pragma unroll
    for (int r = 0; r < 4; ++r) {
        const int o = tm * 16 + g * 4 + r;
        if (o < DSQ) sSimWts[o][p] = c2v[r] * invt;   // sSim region reused as sWts
    }
    __syncthreads();   // wts ready; fixup buffers dead

    // ---- aggregate: build all 7 banded W in parallel; S rows double-buffered ----
    const float* sb = spatial + b * CDIM * HH * WW;
    float4 sreg[2];
    #define LD_SROW(KI)                                                          \
        { const int hp_ = reflect64(h + (KI) - RR);                              \
          _Pragma("unroll")                                                      \
          for (int j = 0; j < 2; ++j) {                                          \
              const int idx = tid * 2 + j;                                       \
              const int c = idx >> 4, pos = idx & 15;                            \
              sreg[j] = *reinterpret_cast<const float4*>(                        \
                  &sb[(c * HH + hp_) * WW + pos * 4]);                           \
          } }
    #define ST_SROW(DST)                                                         \
        { _Pragma("unroll")                                                      \
          for (int j = 0; j < 2; ++j) {                                          \
              const int idx = tid * 2 + j;                                       \
              const int c = idx >> 4, pos = idx & 15;                            \
              const int sw_ = (c & 7) << 3;                                      \
              short4v pk;                                                        \
              _Pragma("unroll")                                                  \
              for (int m = 0; m < 4; ++m) pk[m] = f2bf(((const float*)&sreg[j])[m]); \
              *reinterpret_cast<short4v*>(&(DST)[c * 64 + ((pos * 4) ^ sw_)]) = pk;  \
          } }

    LD_SROW(0);
    if (tid < 448) {   // 7 waves: wave k builds W7[k]; each thread owns one 72-short row
        const int kin = tid >> 6, pp_ = tid & 63;
        const int s_ = (pp_ > 3) ? (pp_ - 3) : 0;
        float col[7] = {0.f, 0.f, 0.f, 0.f, 0.f, 0.f, 0.f};
        #pragma unroll
        for (int kj = 0; kj < 7; ++kj) {
            const int pr = reflect64(pp_ + kj - RR);
            const float wv_ = sSimWts[kin * 7 + kj][pp_];
            const int id_ = pr - s_;
            #pragma unroll
            for (int jj = 0; jj < 7; ++jj) if (id_ == jj) col[jj] += wv_;
        }
        short* wrow = &W7[(kin * 64 + pp_) * 72];
        const short8v z8 = {0, 0, 0, 0, 0, 0, 0, 0};
        #pragma unroll
        for (int j8 = 0; j8 < 9; ++j8)
            *reinterpret_cast<short8v*>(&wrow[j8 * 8]) = z8;
        #pragma unroll
        for (int jj = 0; jj < 7; ++jj) {
            const int pr = s_ + jj;
            if (pr < 64) wrow[pr] = f2bf(col[jj]);
        }
    }
    ST_SROW(sSa0);
    __syncthreads();

    // agg GEMM: M=128 (c), N=64 (p). wave q: tmA=q>>1, N-tiles (q&1)*2 +{0,1}
    const int tmA = q >> 1;
    const int oaA = tmA * 16 + lm;
    const int arA = oaA * 64, aswA = (oaA & 7) << 3;
    const int pA0 = ((q & 1) * 2) * 16 + lm, pA1 = ((q & 1) * 2 + 1) * 16 + lm;

    float4v ag0 = {0.f, 0.f, 0.f, 0.f}, ag1 = {0.f, 0.f, 0.f, 0.f};
    for (int ki = 0; ki < 7; ++ki) {
        if (ki < 6) LD_SROW(ki + 1);
        const short* Sc = (ki & 1) ? sSa1 : sSa0;
        const short* Wc = &W7[ki * 64 * 72];
        #pragma unroll
        for (int kk = 0; kk < 2; ++kk) {
            const int k0 = kk * 32 + g * 8;
            const short8v a8 = *reinterpret_cast<const short8v*>(&Sc[arA + (k0 ^ aswA)]);
            const short8v b80 = *reinterpret_cast<const short8v*>(&Wc[pA0 * 72 + k0]);
            const short8v b81 = *reinterpret_cast<const short8v*>(&Wc[pA1 * 72 + k0]);
            ag0 = __builtin_amdgcn_mfma_f32_16x16x32_bf16(a8, b80, ag0, 0, 0, 0);
            ag1 = __builtin_amdgcn_mfma_f32_16x16x32_bf16(a8, b81, ag1, 0, 0, 0);
        }
        if (ki < 6) { ST_SROW(((ki & 1) ? sSa0 : sSa1)); }   // write next buffer
        __syncthreads();
    }
    #undef LD_SROW
    #undef ST_SROW

    // write agg result as bf16 op-proj B operand sXT[p][c]; stage op_w1 -> sWb
    {
        #pragma unroll
        for (int r = 0; r < 4; ++r) {
            const int c = tmA * 16 + g * 4 + r;
            sXT[pA0 * 128 + (c ^ ((pA0 & 7) << 3))] = f2bf(ag0[r]);
            sXT[pA1 * 128 + (c ^ ((pA1 & 7) << 3))] = f2bf(ag1[r]);
        }
    }
    {
        const int o = tid >> 3;
        const int i0 = (tid & 7) * 16;
        const int sw = (o & 7) << 3;
        const float* src = ow1 + o * CDIM + i0;
        short8v pk0, pk1;
        #pragma unroll
        for (int j = 0; j < 8; ++j) pk0[j] = f2bf(src[j]);
        #pragma unroll
        for (int j = 0; j < 8; ++j) pk1[j] = f2bf(src[8 + j]);
        *reinterpret_cast<short8v*>(&sWb[o * 128 + (i0 ^ sw)]) = pk0;
        *reinterpret_cast<short8v*>(&sWb[o * 128 + ((i0 + 8) ^ sw)]) = pk1;
    }
    __syncthreads();

    // ---- output_proj conv1 MFMA ----
    const int tmo = q >> 1;
    const int tn0 = (q & 1) * 2;
    const int oaop = tmo * 16 + lm;
    const int arow = oaop * 128, asw = (oaop & 7) << 3;
    const int p0 = tn0 * 16 + lm, p1 = (tn0 + 1) * 16 + lm;
    const int bsw0 = (p0 & 7) << 3, bsw1 = (p1 & 7) << 3;

    {
        float4v a0 = {0.f, 0.f, 0.f, 0.f}, a1 = {0.f, 0.f, 0.f, 0.f};
        #pragma unroll
        for (int kk = 0; kk < 4; ++kk) {
            const int ki = kk * 32 + g * 8;
            const short8v af = *reinterpret_cast<const short8v*>(&sWb[arow + (ki ^ asw)]);
            const short8v bf0 = *reinterpret_cast<const short8v*>(&sXT[p0 * 128 + (ki ^ bsw0)]);
            const short8v bf1 = *reinterpret_cast<const short8v*>(&sXT[p1 * 128 + (ki ^ bsw1)]);
            a0 = __builtin_amdgcn_mfma_f32_16x16x32_bf16(af, bf0, a0, 0, 0, 0);
            a1 = __builtin_amdgcn_mfma_f32_16x16x32_bf16(af, bf1, a1, 0, 0, 0);
        }
        __syncthreads();      // sSa region free for sT; conv1 reads complete
        #pragma unroll
        for (int r = 0; r < 4; ++r) sT[tmo * 16 + g * 4 + r][p0] = a0[r];
        #pragma unroll
        for (int r = 0; r < 4; ++r) sT[tmo * 16 + g * 4 + r][p1] = a1[r];
    }
    __syncthreads();

    // restage sWb = op_w2; bias + LN(128) -> sXT (reused as conv2 B operand)
    {
        const int o = tid >> 3;
        const int i0 = (tid & 7) * 16;
        const int sw = (o & 7) << 3;
        const float* src = ow2 + o * CDIM + i0;
        short8v pk0, pk1;
        #pragma unroll
        for (int j = 0; j < 8; ++j) pk0[j] = f2bf(src[j]);
        #pragma unroll
        for (int j = 0; j < 8; ++j) pk1[j] = f2bf(src[8 + j]);
        *reinterpret_cast<short8v*>(&sWb[o * 128 + (i0 ^ sw)]) = pk0;
        *reinterpret_cast<short8v*>(&sWb[o * 128 + ((i0 + 8) ^ sw)]) = pk1;
    }
    {
        float vals2[8];
        float u1 = 0.f, u2 = 0.f;
        #pragma unroll
        for (int j = 0; j < 8; ++j) {
            const float v = sT[qu * 8 + j][l] + ob1[qu * 8 + j];
            vals2[j] = v; u1 += v; u2 += v * v;
        }
        red1[q][l] = u1; red2[q][l] = u2;
        __syncthreads();
        float v1 = 0.f, v2 = 0.f;
        #pragma unroll
        for (int j = 0; j < 16; ++j) { v1 += red1[j][l]; v2 += red2[j][l]; }
        const float mn = v1 * (1.0f / 128.0f);
        const float vr = v2 * (1.0f / 128.0f) - mn * mn;
        const float rs = rsqrtf(vr + 1e-6f);
        short8v pk;
        #pragma unroll
        for (int j = 0; j < 8; ++j) {
            const float v = (vals2[j] - mn) * rs * olnw[qu * 8 + j] + olnb[qu * 8 + j];
            pk[j] = f2bf(v);
        }
        *reinterpret_cast<short8v*>(&sXT[l * 128 + ((qu * 8) ^ ((l & 7) << 3))]) = pk;
    }
    __syncthreads();

    // ---- output_proj conv2 MFMA + bias -> out ----
    {
        float4v a0 = {0.f, 0.f, 0.f, 0.f}, a1 = {0.f, 0.f, 0.f, 0.f};
        #pragma unroll
        for (int kk = 0; kk < 4; ++kk) {
            const int ki = kk * 32 + g * 8;
            const short8v af = *reinterpret_cast<const short8v*>(&sWb[arow + (ki ^ asw)]);
            const short8v bf0 = *reinterpret_cast<const short8v*>(&sXT[p0 * 128 + (ki ^ bsw0)]);
            const short8v bf1 = *reinterpret_cast<const short8v*>(&sXT[p1 * 128 + (ki ^ bsw1)]);
            a0 = __builtin_amdgcn_mfma_f32_16x16x32_bf16(af, bf0, a0, 0, 0, 0);
            a1 = __builtin_amdgcn_mfma_f32_16x16x32_bf16(af, bf1, a1, 0, 0, 0);
        }
        const float4 bv = *reinterpret_cast<const float4*>(&ob2[tmo * 16 + g * 4]);
        float* obase = out + (b * CDIM * HH + h) * WW;
        #pragma unroll
        for (int r = 0; r < 4; ++r) {
            const float bias = ((const float*)&bv)[r];
            obase[(tmo * 16 + g * 4 + r) * HH * WW + p0] = a0[r] + bias;
            obase[(tmo * 16 + g * 4 + r) * HH * WW + p1] = a1[r] + bias;
        }
    }
}

extern "C" void kernel_launch(void* const* d_in, const int* in_sizes, int n_in,
                              void* d_out, int out_size, void* d_ws, size_t ws_size,
                              hipStream_t stream) {
    (void)in_sizes; (void)n_in; (void)out_size; (void)ws_size;
    const float* spatial  = (const float*)d_in[0];
    const float* semantic = (const float*)d_in[1];
    const float* rp_w1 = (const float*)d_in[2];
    const float* rp_b1 = (const float*)d_in[3];
    const float* rp_lnw = (const float*)d_in[4];
    const float* rp_lnb = (const float*)d_in[5];
    const float* rp_w2 = (const float*)d_in[6];
    const float* rp_b2 = (const float*)d_in[7];
    const float* fx_w1 = (const float*)d_in[8];
    const float* fx_b1 = (const float*)d_in[9];
    const float* fx_lnw = (const float*)d_in[10];
    const float* fx_lnb = (const float*)d_in[11];
    const float* fx_w2 = (const float*)d_in[12];
    const float* fx_b2 = (const float*)d_in[13];
    const float* sigma = (const float*)d_in[14];
    const float* op_w1 = (const float*)d_in[15];
    const float* op_b1 = (const float*)d_in[16];
    const float* op_lnw = (const float*)d_in[17];
    const float* op_lnb = (const float*)d_in[18];
    const float* op_w2 = (const float*)d_in[19];
    const float* op_b2 = (const float*)d_in[20];

    char* wsb = (char*)d_ws;
    short* pxt  = (short*)wsb;                   // 4 MB bf16 [b][h][p][c]
    float* outp = (float*)d_out;

    dim3 grid(BB * HH), blk(1024);
    proj_kernel<true><<<grid, blk, 0, stream>>>(semantic, rp_w1, rp_b1, rp_lnw, rp_lnb,
                                                rp_w2, rp_b2, pxt);
    simfixagg_kernel<<<grid, blk, 0, stream>>>(pxt, sigma, semantic,
                                               fx_w1, fx_b1, fx_lnw, fx_lnb, fx_w2, fx_b2,
                                               spatial,
                                               op_w1, op_b1, op_lnw, op_lnb, op_w2, op_b2,
                                               outp);
}

// Round 21
// 47.670 us; speedup vs baseline: 1.4584x; 1.0119x over previous
//
#include <hip/hip_runtime.h>
#include <cstdint>

#define BB 4
#define CDIM 128
#define HH 64
#define WW 64
#define RR 3
#define DD 7
#define DSQ 49

typedef __attribute__((ext_vector_type(8))) short short8v;   // 8 bf16 = 4 VGPR
typedef __attribute__((ext_vector_type(4))) short short4v;   // 4 bf16 = 2 VGPR
typedef __attribute__((ext_vector_type(4))) float float4v;

__device__ __forceinline__ int reflect64(int p) {
    p = (p < 0) ? -p : p;
    return (p > 63) ? (126 - p) : p;
}
__device__ __forceinline__ float sigm(float x) { return 1.0f / (1.0f + __expf(-x)); }
__device__ __forceinline__ short f2bf(float f) {     // f32 -> bf16 RNE
    uint32_t u = __float_as_uint(f);
    u += 0x7FFF + ((u >> 16) & 1);
    return (short)(u >> 16);
}

// ---- range_proj: conv1x1 -> LN -> SiLU -> conv1x1 via bf16 MFMA.
// Output: bf16 TRANSPOSED [b][h][p][c].
template<bool SILU>
__global__ __launch_bounds__(1024) void proj_kernel(
    const float* __restrict__ x, const float* __restrict__ w1,
    const float* __restrict__ b1, const float* __restrict__ lnw,
    const float* __restrict__ lnb, const float* __restrict__ w2,
    const float* __restrict__ b2, short* __restrict__ outT)
{
    __shared__ short sW1[CDIM * CDIM];
    __shared__ short sW2[CDIM * CDIM];
    __shared__ short sXT[WW * CDIM];
    __shared__ short sXT2[WW * CDIM];
    __shared__ float sT[CDIM][65];
    __shared__ float red1[16][WW];
    __shared__ float red2[16][WW];

    const int tid = threadIdx.x;
    const int l = tid & 63;
    const int q = tid >> 6;
    const int qu = __builtin_amdgcn_readfirstlane(q);
    const int b = blockIdx.x >> 6;
    const int h = blockIdx.x & 63;

    {
        const int o = tid >> 3;
        const int i0 = (tid & 7) * 16;
        const int sw = (o & 7) << 3;
        const float* wsrc[2] = {w1, w2};
        short* wdst[2] = {sW1, sW2};
        #pragma unroll
        for (int m = 0; m < 2; ++m) {
            const float* src = wsrc[m] + o * CDIM + i0;
            short8v pk0, pk1;
            #pragma unroll
            for (int j = 0; j < 8; ++j) pk0[j] = f2bf(src[j]);
            #pragma unroll
            for (int j = 0; j < 8; ++j) pk1[j] = f2bf(src[8 + j]);
            *reinterpret_cast<short8v*>(&wdst[m][o * 128 + (i0 ^ sw)]) = pk0;
            *reinterpret_cast<short8v*>(&wdst[m][o * 128 + ((i0 + 8) ^ sw)]) = pk1;
        }
    }
    {
        const int pos = tid & 15;
        const int c0 = tid >> 4;
        const float* xrow = x + (b * CDIM * HH + h) * WW;
        #pragma unroll
        for (int rr = 0; rr < 2; ++rr) {
            const int c = c0 + rr * 64;
            const float4 v = *reinterpret_cast<const float4*>(&xrow[c * HH * WW + pos * 4]);
            #pragma unroll
            for (int m = 0; m < 4; ++m) {
                const int p = pos * 4 + m;
                sXT[p * 128 + (c ^ ((p & 7) << 3))] = f2bf(((const float*)&v)[m]);
            }
        }
    }
    __syncthreads();

    const int lm = l & 15, g = l >> 4;
    const int tm = q >> 1;
    const int tn0 = (q & 1) * 2;
    const int oa = tm * 16 + lm;
    const int arow = oa * 128, asw = (oa & 7) << 3;
    const int p0 = tn0 * 16 + lm, p1 = (tn0 + 1) * 16 + lm;
    const int bsw0 = (p0 & 7) << 3, bsw1 = (p1 & 7) << 3;

    float4v acc0 = {0.f, 0.f, 0.f, 0.f}, acc1 = {0.f, 0.f, 0.f, 0.f};
    #pragma unroll
    for (int kk = 0; kk < 4; ++kk) {
        const int ki = kk * 32 + g * 8;
        const short8v af = *reinterpret_cast<const short8v*>(&sW1[arow + (ki ^ asw)]);
        const short8v bf0 = *reinterpret_cast<const short8v*>(&sXT[p0 * 128 + (ki ^ bsw0)]);
        const short8v bf1 = *reinterpret_cast<const short8v*>(&sXT[p1 * 128 + (ki ^ bsw1)]);
        acc0 = __builtin_amdgcn_mfma_f32_16x16x32_bf16(af, bf0, acc0, 0, 0, 0);
        acc1 = __builtin_amdgcn_mfma_f32_16x16x32_bf16(af, bf1, acc1, 0, 0, 0);
    }
    #pragma unroll
    for (int r = 0; r < 4; ++r) sT[tm * 16 + g * 4 + r][p0] = acc0[r];
    #pragma unroll
    for (int r = 0; r < 4; ++r) sT[tm * 16 + g * 4 + r][p1] = acc1[r];
    __syncthreads();

    {
        const int p = l;
        float vals[8];
        float s1 = 0.f, s2 = 0.f;
        #pragma unroll
        for (int j = 0; j < 8; ++j) {
            const float v = sT[qu * 8 + j][p] + b1[qu * 8 + j];
            vals[j] = v; s1 += v; s2 += v * v;
        }
        red1[q][p] = s1; red2[q][p] = s2;
        __syncthreads();
        float t1 = 0.f, t2 = 0.f;
        #pragma unroll
        for (int j = 0; j < 16; ++j) { t1 += red1[j][p]; t2 += red2[j][p]; }
        const float mean = t1 * (1.0f / 128.0f);
        const float var  = t2 * (1.0f / 128.0f) - mean * mean;
        const float rstd = rsqrtf(var + 1e-6f);
        short8v pk;
        #pragma unroll
        for (int j = 0; j < 8; ++j) {
            float v = (vals[j] - mean) * rstd * lnw[qu * 8 + j] + lnb[qu * 8 + j];
            if (SILU) v = v * sigm(v);
            pk[j] = f2bf(v);
        }
        *reinterpret_cast<short8v*>(&sXT2[p * 128 + ((qu * 8) ^ ((p & 7) << 3))]) = pk;
    }
    __syncthreads();

    {
        float4v a0 = {0.f, 0.f, 0.f, 0.f}, a1 = {0.f, 0.f, 0.f, 0.f};
        #pragma unroll
        for (int kk = 0; kk < 4; ++kk) {
            const int ki = kk * 32 + g * 8;
            const short8v af = *reinterpret_cast<const short8v*>(&sW2[arow + (ki ^ asw)]);
            const short8v bf0 = *reinterpret_cast<const short8v*>(&sXT2[p0 * 128 + (ki ^ bsw0)]);
            const short8v bf1 = *reinterpret_cast<const short8v*>(&sXT2[p1 * 128 + (ki ^ bsw1)]);
            a0 = __builtin_amdgcn_mfma_f32_16x16x32_bf16(af, bf0, a0, 0, 0, 0);
            a1 = __builtin_amdgcn_mfma_f32_16x16x32_bf16(af, bf1, a1, 0, 0, 0);
        }
        const float4 bv = *reinterpret_cast<const float4*>(&b2[tm * 16 + g * 4]);
        #pragma unroll
        for (int r = 0; r < 4; ++r) {
            const float bias = ((const float*)&bv)[r];
            sT[tm * 16 + g * 4 + r][p0] = a0[r] + bias;
            sT[tm * 16 + g * 4 + r][p1] = a1[r] + bias;
        }
    }
    __syncthreads();
    {
        const int p = tid >> 4;
        const int c0 = (tid & 15) * 8;
        short8v pk;
        #pragma unroll
        for (int j = 0; j < 8; ++j) pk[j] = f2bf(sT[c0 + j][p]);
        *reinterpret_cast<short8v*>(&outT[((b * HH + h) * WW + p) * CDIM + c0]) = pk;
    }
}

// ---- fully fused: Gram-MFMA sim (T14 weight prefetch in flight) -> softmax*spatial
//      -> MFMA fixup -> banded-W7 MFMA aggregate -> output_proj MFMA -> d_out
__global__ __launch_bounds__(1024) void simfixagg_kernel(
    const short* __restrict__ pxt, const float* __restrict__ sigma_p,
    const float* __restrict__ sem,
    const float* __restrict__ fw1, const float* __restrict__ fb1,
    const float* __restrict__ flnw, const float* __restrict__ flnb,
    const float* __restrict__ fw2, const float* __restrict__ fb2,
    const float* __restrict__ spatial,
    const float* __restrict__ ow1, const float* __restrict__ ob1,
    const float* __restrict__ olnw, const float* __restrict__ olnb,
    const float* __restrict__ ow2, const float* __restrict__ ob2,
    float* __restrict__ out)
{
    __shared__ alignas(16) char sBig[7 * WW * CDIM * 2];   // 114,688 B
    __shared__ alignas(16) char sAux[64 * 66 * 4];         //  16,896 B
    __shared__ alignas(16) float sSimWts[DSQ][64];         //  12,544 B: sSim then sWts
    __shared__ alignas(16) float sCmb[DSQ][66];            //  12,936 B

    // Gram phase
    short* rows = reinterpret_cast<short*>(sBig);
    float* sP7  = reinterpret_cast<float*>(sBig);          // [7][64][64] f32 = 114,688
    // fixup overlay
    short* B1   = reinterpret_cast<short*>(sBig);          // [64 px][192]
    short* A1   = reinterpret_cast<short*>(sBig + 24576);  // [64 o ][192]
    short* B2   = reinterpret_cast<short*>(sBig + 49152);  // [64 px][64]
    short* A2   = reinterpret_cast<short*>(sBig + 57344);  // [64 o ][64]
    float* fSem = reinterpret_cast<float*>(sBig + 65536);  // [128][64]
    float* prm  = reinterpret_cast<float*>(sBig + 98304);  // 4 x 64
    // agg overlay: W7 [7][64][72] bf16 (64,512) + S double-buffer
    short* W7   = reinterpret_cast<short*>(sBig);          // 0 .. 64,512
    short* sSa0 = reinterpret_cast<short*>(sBig + 64512);  // [128][64] bf16
    short* sSa1 = reinterpret_cast<short*>(sBig + 80896);  // [128][64] bf16
    // op-proj overlay (after agg; W7/sSa dead)
    short* sWb  = reinterpret_cast<short*>(sBig);                       // 32,768
    short* sXT  = reinterpret_cast<short*>(sBig + 32768);               // 16,384
    float (*sT)[65] = reinterpret_cast<float(*)[65]>(sBig + 49152);     // 33,280

    float (*red1)[65] = reinterpret_cast<float(*)[65]>(sAux);
    float (*red2)[65] = reinterpret_cast<float(*)[65]>(sAux + 16 * 65 * 4);

    const int tid = threadIdx.x;
    const int l = tid & 63;
    const int q = tid >> 6;
    const int qu = __builtin_amdgcn_readfirstlane(q);
    // XCD-bijective swizzle (256 blocks, 8 XCDs): XCD k owns 32 consecutive rows.
    const int lbid = ((blockIdx.x & 7) << 5) | (blockIdx.x >> 3);
    const int b = lbid >> 6;
    const int h = lbid & 63;

    // ---- stage 7 reflected rows, bf16 [row][p][c] swz ----
    for (int idx = tid; idx < 7 * WW * 16; idx += 1024) {
        const int cchunk = idx & 15;
        const int p = (idx >> 4) & 63;
        const int row = idx >> 10;
        const int hp = reflect64(h + row - RR);
        const short8v v = *reinterpret_cast<const short8v*>(
            &pxt[((b * HH + hp) * WW + p) * CDIM + cchunk * 8]);
        *reinterpret_cast<short8v*>(
            &rows[(row * WW + p) * CDIM + ((cchunk * 8) ^ ((p & 7) << 3))]) = v;
    }

    // ---- T14: prefetch fixup weights + sem into registers (fly during Gram) ----
    float a1r[2][8];
    #pragma unroll
    for (int it = 0; it < 2; ++it) {
        const int idx = tid + it * 1024;
        const int o = idx / 24;
        const int ch0 = (idx % 24) * 8;
        #pragma unroll
        for (int j = 0; j < 8; ++j) {
            const int c = ch0 + j;
            float v = 0.f;
            if (idx < 64 * 24 && o < DSQ) {
                if (c < DSQ) v = fw1[o * 177 + c];
                else if (c >= 64) v = fw1[o * 177 + DSQ + (c - 64)];
            }
            a1r[it][j] = v;
        }
    }
    float a2r[8];
    {
        #pragma unroll
        for (int j = 0; j < 8; ++j) a2r[j] = 0.f;
        if (tid < 512) {
            const int o = tid >> 3;
            const int ch0 = (tid & 7) * 8;
            #pragma unroll
            for (int j = 0; j < 8; ++j) {
                const int c = ch0 + j;
                if (o < DSQ && c < DSQ) a2r[j] = fw2[o * DSQ + c];
            }
        }
    }
    float prmr = 0.f;
    if (tid < 256) {
        const int a = tid >> 6, i = tid & 63;
        if (i < DSQ) {
            if (a == 0) prmr = fb1[i];
            else if (a == 1) prmr = flnw[i];
            else if (a == 2) prmr = flnb[i];
            else prmr = fb2[i];
        }
    }
    float4 semr[2];
    {
        const float* srow = sem + (b * CDIM * HH + h) * WW;
        #pragma unroll
        for (int it = 0; it < 2; ++it) {
            const int idx = tid + it * 1024;     // CDIM*16 = 2048 total
            const int r = idx >> 4, pos = idx & 15;
            semr[it] = *reinterpret_cast<const float4*>(&srow[r * HH * WW + pos * 4]);
        }
    }
    __syncthreads();

    // ---- Gram MFMA: all 7 ki, accumulators live, NO internal barriers ----
    const int lm = l & 15, g = l >> 4;
    const int tm = q >> 2, tn = q & 3;
    const int pa = tm * 16 + lm;
    const int pxb = tn * 16 + lm;
    const int abase = (3 * WW + pa) * CDIM, as_ = (pa & 7) << 3;
    const int bs_ = (pxb & 7) << 3;

    short8v afr[4];
    #pragma unroll
    for (int kk = 0; kk < 4; ++kk)
        afr[kk] = *reinterpret_cast<const short8v*>(
            &rows[abase + ((kk * 32 + g * 8) ^ as_)]);

    float4v gacc[7];
    #pragma unroll
    for (int ki = 0; ki < 7; ++ki) {
        float4v acc = {0.f, 0.f, 0.f, 0.f};
        const int bbase = (ki * WW + pxb) * CDIM;
        #pragma unroll
        for (int kk = 0; kk < 4; ++kk) {
            const short8v bf = *reinterpret_cast<const short8v*>(
                &rows[bbase + ((kk * 32 + g * 8) ^ bs_)]);
            acc = __builtin_amdgcn_mfma_f32_16x16x32_bf16(afr[kk], bf, acc, 0, 0, 0);
        }
        gacc[ki] = acc;
    }
    __syncthreads();               // all rows reads done -> sP7 overlay safe

    #pragma unroll
    for (int ki = 0; ki < 7; ++ki) {
        #pragma unroll
        for (int r = 0; r < 4; ++r)
            sP7[ki * 4096 + (tm * 16 + g * 4 + r) * 64 + pxb] = gacc[ki][r];
    }
    __syncthreads();

    const float rscale = 0.088388347648318447f;  // 1/sqrt(128)
    for (int idx = tid; idx < 7 * 7 * 64; idx += 1024) {
        const int ki = idx / 448;
        const int rem = idx - ki * 448;
        const int kj = rem >> 6, p = rem & 63;
        sSimWts[ki * 7 + kj][p] =
            sP7[ki * 4096 + p * 64 + reflect64(p + kj - RR)] * rscale;
    }
    __syncthreads();
    // sP7 dead -> commit prefetched regs into fixup overlays

    #pragma unroll
    for (int it = 0; it < 2; ++it) {
        const int idx = tid + it * 1024;
        if (idx < 64 * 24) {
            const int o = idx / 24;
            const int ch0 = (idx % 24) * 8;
            short8v pk;
            #pragma unroll
            for (int j = 0; j < 8; ++j) pk[j] = f2bf(a1r[it][j]);
            *reinterpret_cast<short8v*>(&A1[o * 192 + (ch0 ^ ((o & 7) << 3))]) = pk;
        }
    }
    if (tid < 512) {
        const int o = tid >> 3;
        const int ch0 = (tid & 7) * 8;
        short8v pk;
        #pragma unroll
        for (int j = 0; j < 8; ++j) pk[j] = f2bf(a2r[j]);
        *reinterpret_cast<short8v*>(&A2[o * 64 + (ch0 ^ ((o & 7) << 3))]) = pk;
    }
    if (tid >= 512 && tid < 1024) {   // B2 zero-fill (distinct threads from A2 write)
        const short8v z = {0, 0, 0, 0, 0, 0, 0, 0};
        *reinterpret_cast<short8v*>(&B2[(tid - 512) * 8]) = z;
    }
    if (tid < 256) prm[tid] = prmr;
    #pragma unroll
    for (int it = 0; it < 2; ++it) {
        const int idx = tid + it * 1024;
        const int r = idx >> 4, pos = idx & 15;
        *reinterpret_cast<float4*>(&fSem[r * WW + pos * 4]) = semr[it];
    }
    // B1 pad cols [49..64) zero
    for (int idx = tid; idx < 64 * 15; idx += 1024) {
        const int p = idx / 15, c = DSQ + idx % 15;
        B1[p * 192 + (c ^ ((p & 7) << 3))] = 0;
    }
    // softmax * spatial kernel -> sCmb f32 + B1 cmb-cols bf16
    {
        float rv[DSQ];
        #pragma unroll
        for (int n = 0; n < DSQ; ++n) rv[n] = sSimWts[n][l];
        float m = -1e30f;
        #pragma unroll
        for (int n = 0; n < DSQ; ++n) m = fmaxf(m, rv[n]);
        float ssum = 0.f;
        #pragma unroll
        for (int n = 0; n < DSQ; ++n) ssum += __expf(rv[n] - m);
        const float inv = 1.0f / ssum;
        const float sigma = sigma_p[0];
        const float inv2s2 = 1.0f / (2.0f * sigma * sigma);
        const int swl = (l & 7) << 3;
        #pragma unroll
        for (int k = 0; k < 4; ++k) {
            const int n = q + 16 * k;
            if (n < DSQ) {
                const int ki = n / 7, kj = n % 7;
                const float dx = (float)(ki - 3) * (1.0f / 3.0f);
                const float dy = (float)(kj - 3) * (1.0f / 3.0f);
                const float sk = __expf(-(dx * dx + dy * dy) * inv2s2);
                const float cv = __expf(rv[n] - m) * inv * sk;
                sCmb[n][l] = cv;
                B1[l * 192 + (n ^ swl)] = f2bf(cv);
            }
        }
    }
    __syncthreads();
    // B1 sem-cols: transpose-pack from fSem
    {
        const int c0 = q * 8;
        short8v pk;
        #pragma unroll
        for (int j = 0; j < 8; ++j) pk[j] = f2bf(fSem[(c0 + j) * WW + l]);
        *reinterpret_cast<short8v*>(&B1[l * 192 + ((64 + c0) ^ ((l & 7) << 3))]) = pk;
    }
    __syncthreads();

    // ---- fixup conv1 MFMA ----
    const int oA = tm * 16 + lm;
    const int aswz = (oA & 7) << 3;
    const int p = tn * 16 + lm;
    const int bswz = (p & 7) << 3;

    float4v facc = {0.f, 0.f, 0.f, 0.f};
    #pragma unroll
    for (int kk = 0; kk < 6; ++kk) {
        const int ki = kk * 32 + g * 8;
        const short8v af = *reinterpret_cast<const short8v*>(&A1[oA * 192 + (ki ^ aswz)]);
        const short8v bf = *reinterpret_cast<const short8v*>(&B1[p * 192 + (ki ^ bswz)]);
        facc = __builtin_amdgcn_mfma_f32_16x16x32_bf16(af, bf, facc, 0, 0, 0);
    }
    float vals[4];
    float s1 = 0.f, s2 = 0.f;
    #pragma unroll
    for (int r = 0; r < 4; ++r) {
        const int o = tm * 16 + g * 4 + r;
        const float v = facc[r] + prm[o];
        vals[r] = v;
        if (o < DSQ) { s1 += v; s2 += v * v; }
    }
    red1[tm * 4 + g][p] = s1;
    red2[tm * 4 + g][p] = s2;
    __syncthreads();
    float t1 = 0.f, t2 = 0.f;
    #pragma unroll
    for (int j = 0; j < 16; ++j) { t1 += red1[j][p]; t2 += red2[j][p]; }
    const float mean = t1 * (1.0f / 49.0f);
    const float var  = t2 * (1.0f / 49.0f) - mean * mean;
    const float rstd = rsqrtf(var + 1e-6f);
    #pragma unroll
    for (int r = 0; r < 4; ++r) {
        const int o = tm * 16 + g * 4 + r;
        if (o < DSQ) {
            const float v = (vals[r] - mean) * rstd * prm[64 + o] + prm[128 + o];
            const float sv = v * sigm(v);
            B2[p * 64 + (o ^ bswz)] = f2bf(sv);
        }
    }
    __syncthreads();

    // ---- fixup conv2 MFMA + gate + normalize -> sWts (LDS) ----
    float4v facc2 = {0.f, 0.f, 0.f, 0.f};
    #pragma unroll
    for (int kk = 0; kk < 2; ++kk) {
        const int ki = kk * 32 + g * 8;
        const short8v af = *reinterpret_cast<const short8v*>(&A2[oA * 64 + (ki ^ aswz)]);
        const short8v bf = *reinterpret_cast<const short8v*>(&B2[p * 64 + (ki ^ bswz)]);
        facc2 = __builtin_amdgcn_mfma_f32_16x16x32_bf16(af, bf, facc2, 0, 0, 0);
    }
    float c2v[4];
    float ps = 0.f;
    #pragma unroll
    for (int r = 0; r < 4; ++r) {
        const int o = tm * 16 + g * 4 + r;
        if (o < DSQ) {
            const float f = facc2[r] + prm[192 + o];
            c2v[r] = sCmb[o][p] * (1.0f + sigm(f));
            ps += c2v[r];
        } else c2v[r] = 0.f;
    }
    red1[tm * 4 + g][p] = ps;
    __syncthreads();
    float tot = 0.f;
    #pragma unroll
    for (int j = 0; j < 16; ++j) tot += red1[j][p];
    const float invt = 1.0f / (tot + 1e-7f);
    #pragma unroll
    for (int r = 0; r < 4; ++r) {
        const int o = tm * 16 + g * 4 + r;
        if (o < DSQ) sSimWts[o][p] = c2v[r] * invt;   // sSim region reused as sWts
    }
    __syncthreads();   // wts ready; fixup buffers dead

    // ---- aggregate: build all 7 banded W in parallel; S rows double-buffered ----
    const float* sb = spatial + b * CDIM * HH * WW;
    float4 sreg[2];
    #define LD_SROW(KI)                                                          \
        { const int hp_ = reflect64(h + (KI) - RR);                              \
          _Pragma("unroll")                                                      \
          for (int j = 0; j < 2; ++j) {                                          \
              const int idx = tid * 2 + j;                                       \
              const int c = idx >> 4, pos = idx & 15;                            \
              sreg[j] = *reinterpret_cast<const float4*>(                        \
                  &sb[(c * HH + hp_) * WW + pos * 4]);                           \
          } }
    #define ST_SROW(DST)                                                         \
        { _Pragma("unroll")                                                      \
          for (int j = 0; j < 2; ++j) {                                          \
              const int idx = tid * 2 + j;                                       \
              const int c = idx >> 4, pos = idx & 15;                            \
              const int sw_ = (c & 7) << 3;                                      \
              short4v pk;                                                        \
              _Pragma("unroll")                                                  \
              for (int m = 0; m < 4; ++m) pk[m] = f2bf(((const float*)&sreg[j])[m]); \
              *reinterpret_cast<short4v*>(&(DST)[c * 64 + ((pos * 4) ^ sw_)]) = pk;  \
          } }

    LD_SROW(0);
    if (tid < 448) {   // 7 waves: wave k builds W7[k]; each thread owns one 72-short row
        const int kin = tid >> 6, pp_ = tid & 63;
        const int s_ = (pp_ > 3) ? (pp_ - 3) : 0;
        float col[7] = {0.f, 0.f, 0.f, 0.f, 0.f, 0.f, 0.f};
        #pragma unroll
        for (int kj = 0; kj < 7; ++kj) {
            const int pr = reflect64(pp_ + kj - RR);
            const float wv_ = sSimWts[kin * 7 + kj][pp_];
            const int id_ = pr - s_;
            #pragma unroll
            for (int jj = 0; jj < 7; ++jj) if (id_ == jj) col[jj] += wv_;
        }
        short* wrow = &W7[(kin * 64 + pp_) * 72];
        const short8v z8 = {0, 0, 0, 0, 0, 0, 0, 0};
        #pragma unroll
        for (int j8 = 0; j8 < 9; ++j8)
            *reinterpret_cast<short8v*>(&wrow[j8 * 8]) = z8;
        #pragma unroll
        for (int jj = 0; jj < 7; ++jj) {
            const int pr = s_ + jj;
            if (pr < 64) wrow[pr] = f2bf(col[jj]);
        }
    }
    ST_SROW(sSa0);
    __syncthreads();

    // agg GEMM: M=128 (c), N=64 (p). wave q: tmA=q>>1, N-tiles (q&1)*2 +{0,1}
    const int tmA = q >> 1;
    const int oaA = tmA * 16 + lm;
    const int arA = oaA * 64, aswA = (oaA & 7) << 3;
    const int pA0 = ((q & 1) * 2) * 16 + lm, pA1 = ((q & 1) * 2 + 1) * 16 + lm;

    float4v ag0 = {0.f, 0.f, 0.f, 0.f}, ag1 = {0.f, 0.f, 0.f, 0.f};
    for (int ki = 0; ki < 7; ++ki) {
        if (ki < 6) LD_SROW(ki + 1);
        const short* Sc = (ki & 1) ? sSa1 : sSa0;
        const short* Wc = &W7[ki * 64 * 72];
        #pragma unroll
        for (int kk = 0; kk < 2; ++kk) {
            const int k0 = kk * 32 + g * 8;
            const short8v a8 = *reinterpret_cast<const short8v*>(&Sc[arA + (k0 ^ aswA)]);
            const short8v b80 = *reinterpret_cast<const short8v*>(&Wc[pA0 * 72 + k0]);
            const short8v b81 = *reinterpret_cast<const short8v*>(&Wc[pA1 * 72 + k0]);
            ag0 = __builtin_amdgcn_mfma_f32_16x16x32_bf16(a8, b80, ag0, 0, 0, 0);
            ag1 = __builtin_amdgcn_mfma_f32_16x16x32_bf16(a8, b81, ag1, 0, 0, 0);
        }
        if (ki < 6) { ST_SROW(((ki & 1) ? sSa0 : sSa1)); }   // write next buffer
        __syncthreads();
    }
    #undef LD_SROW
    #undef ST_SROW

    // write agg result as bf16 op-proj B operand sXT[p][c]; stage op_w1 -> sWb
    {
        #pragma unroll
        for (int r = 0; r < 4; ++r) {
            const int c = tmA * 16 + g * 4 + r;
            sXT[pA0 * 128 + (c ^ ((pA0 & 7) << 3))] = f2bf(ag0[r]);
            sXT[pA1 * 128 + (c ^ ((pA1 & 7) << 3))] = f2bf(ag1[r]);
        }
    }
    {
        const int o = tid >> 3;
        const int i0 = (tid & 7) * 16;
        const int sw = (o & 7) << 3;
        const float* src = ow1 + o * CDIM + i0;
        short8v pk0, pk1;
        #pragma unroll
        for (int j = 0; j < 8; ++j) pk0[j] = f2bf(src[j]);
        #pragma unroll
        for (int j = 0; j < 8; ++j) pk1[j] = f2bf(src[8 + j]);
        *reinterpret_cast<short8v*>(&sWb[o * 128 + (i0 ^ sw)]) = pk0;
        *reinterpret_cast<short8v*>(&sWb[o * 128 + ((i0 + 8) ^ sw)]) = pk1;
    }
    __syncthreads();

    // ---- output_proj conv1 MFMA ----
    const int tmo = q >> 1;
    const int tn0 = (q & 1) * 2;
    const int oaop = tmo * 16 + lm;
    const int arow = oaop * 128, asw = (oaop & 7) << 3;
    const int p0 = tn0 * 16 + lm, p1 = (tn0 + 1) * 16 + lm;
    const int bsw0 = (p0 & 7) << 3, bsw1 = (p1 & 7) << 3;

    {
        float4v a0 = {0.f, 0.f, 0.f, 0.f}, a1 = {0.f, 0.f, 0.f, 0.f};
        #pragma unroll
        for (int kk = 0; kk < 4; ++kk) {
            const int ki = kk * 32 + g * 8;
            const short8v af = *reinterpret_cast<const short8v*>(&sWb[arow + (ki ^ asw)]);
            const short8v bf0 = *reinterpret_cast<const short8v*>(&sXT[p0 * 128 + (ki ^ bsw0)]);
            const short8v bf1 = *reinterpret_cast<const short8v*>(&sXT[p1 * 128 + (ki ^ bsw1)]);
            a0 = __builtin_amdgcn_mfma_f32_16x16x32_bf16(af, bf0, a0, 0, 0, 0);
            a1 = __builtin_amdgcn_mfma_f32_16x16x32_bf16(af, bf1, a1, 0, 0, 0);
        }
        __syncthreads();      // sSa region free for sT; conv1 reads complete
        #pragma unroll
        for (int r = 0; r < 4; ++r) sT[tmo * 16 + g * 4 + r][p0] = a0[r];
        #pragma unroll
        for (int r = 0; r < 4; ++r) sT[tmo * 16 + g * 4 + r][p1] = a1[r];
    }
    __syncthreads();

    // restage sWb = op_w2; bias + LN(128) -> sXT (reused as conv2 B operand)
    {
        const int o = tid >> 3;
        const int i0 = (tid & 7) * 16;
        const int sw = (o & 7) << 3;
        const float* src = ow2 + o * CDIM + i0;
        short8v pk0, pk1;
        #pragma unroll
        for (int j = 0; j < 8; ++j) pk0[j] = f2bf(src[j]);
        #pragma unroll
        for (int j = 0; j < 8; ++j) pk1[j] = f2bf(src[8 + j]);
        *reinterpret_cast<short8v*>(&sWb[o * 128 + (i0 ^ sw)]) = pk0;
        *reinterpret_cast<short8v*>(&sWb[o * 128 + ((i0 + 8) ^ sw)]) = pk1;
    }
    {
        float vals2[8];
        float u1 = 0.f, u2 = 0.f;
        #pragma unroll
        for (int j = 0; j < 8; ++j) {
            const float v = sT[qu * 8 + j][l] + ob1[qu * 8 + j];
            vals2[j] = v; u1 += v; u2 += v * v;
        }
        red1[q][l] = u1; red2[q][l] = u2;
        __syncthreads();
        float v1 = 0.f, v2 = 0.f;
        #pragma unroll
        for (int j = 0; j < 16; ++j) { v1 += red1[j][l]; v2 += red2[j][l]; }
        const float mn = v1 * (1.0f / 128.0f);
        const float vr = v2 * (1.0f / 128.0f) - mn * mn;
        const float rs = rsqrtf(vr + 1e-6f);
        short8v pk;
        #pragma unroll
        for (int j = 0; j < 8; ++j) {
            const float v = (vals2[j] - mn) * rs * olnw[qu * 8 + j] + olnb[qu * 8 + j];
            pk[j] = f2bf(v);
        }
        *reinterpret_cast<short8v*>(&sXT[l * 128 + ((qu * 8) ^ ((l & 7) << 3))]) = pk;
    }
    __syncthreads();

    // ---- output_proj conv2 MFMA + bias -> out ----
    {
        float4v a0 = {0.f, 0.f, 0.f, 0.f}, a1 = {0.f, 0.f, 0.f, 0.f};
        #pragma unroll
        for (int kk = 0; kk < 4; ++kk) {
            const int ki = kk * 32 + g * 8;
            const short8v af = *reinterpret_cast<const short8v*>(&sWb[arow + (ki ^ asw)]);
            const short8v bf0 = *reinterpret_cast<const short8v*>(&sXT[p0 * 128 + (ki ^ bsw0)]);
            const short8v bf1 = *reinterpret_cast<const short8v*>(&sXT[p1 * 128 + (ki ^ bsw1)]);
            a0 = __builtin_amdgcn_mfma_f32_16x16x32_bf16(af, bf0, a0, 0, 0, 0);
            a1 = __builtin_amdgcn_mfma_f32_16x16x32_bf16(af, bf1, a1, 0, 0, 0);
        }
        const float4 bv = *reinterpret_cast<const float4*>(&ob2[tmo * 16 + g * 4]);
        float* obase = out + (b * CDIM * HH + h) * WW;
        #pragma unroll
        for (int r = 0; r < 4; ++r) {
            const float bias = ((const float*)&bv)[r];
            obase[(tmo * 16 + g * 4 + r) * HH * WW + p0] = a0[r] + bias;
            obase[(tmo * 16 + g * 4 + r) * HH * WW + p1] = a1[r] + bias;
        }
    }
}

extern "C" void kernel_launch(void* const* d_in, const int* in_sizes, int n_in,
                              void* d_out, int out_size, void* d_ws, size_t ws_size,
                              hipStream_t stream) {
    (void)in_sizes; (void)n_in; (void)out_size; (void)ws_size;
    const float* spatial  = (const float*)d_in[0];
    const float* semantic = (const float*)d_in[1];
    const float* rp_w1 = (const float*)d_in[2];
    const float* rp_b1 = (const float*)d_in[3];
    const float* rp_lnw = (const float*)d_in[4];
    const float* rp_lnb = (const float*)d_in[5];
    const float* rp_w2 = (const float*)d_in[6];
    const float* rp_b2 = (const float*)d_in[7];
    const float* fx_w1 = (const float*)d_in[8];
    const float* fx_b1 = (const float*)d_in[9];
    const float* fx_lnw = (const float*)d_in[10];
    const float* fx_lnb = (const float*)d_in[11];
    const float* fx_w2 = (const float*)d_in[12];
    const float* fx_b2 = (const float*)d_in[13];
    const float* sigma = (const float*)d_in[14];
    const float* op_w1 = (const float*)d_in[15];
    const float* op_b1 = (const float*)d_in[16];
    const float* op_lnw = (const float*)d_in[17];
    const float* op_lnb = (const float*)d_in[18];
    const float* op_w2 = (const float*)d_in[19];
    const float* op_b2 = (const float*)d_in[20];

    char* wsb = (char*)d_ws;
    short* pxt  = (short*)wsb;                   // 4 MB bf16 [b][h][p][c]
    float* outp = (float*)d_out;

    dim3 grid(BB * HH), blk(1024);
    proj_kernel<true><<<grid, blk, 0, stream>>>(semantic, rp_w1, rp_b1, rp_lnw, rp_lnb,
                                                rp_w2, rp_b2, pxt);
    simfixagg_kernel<<<grid, blk, 0, stream>>>(pxt, sigma, semantic,
                                               fx_w1, fx_b1, fx_lnw, fx_lnb, fx_w2, fx_b2,
                                               spatial,
                                               op_w1, op_b1, op_lnw, op_lnb, op_w2, op_b2,
                                               outp);
}